// Round 2
// baseline (672.538 us; speedup 1.0000x reference)
//
#include <hip/hip_runtime.h>
#include <cmath>

#define NN 50000
#define C_IN 256
#define C_HID 128
#define C_OUT 40

// ---------------- CSR build ----------------

__global__ void count_kernel(const int* __restrict__ dst, int E, int* __restrict__ cnt) {
  int e = blockIdx.x * 256 + threadIdx.x;
  if (e < E) atomicAdd(&cnt[dst[e]], 1);
}

__global__ void dinv_kernel(const int* __restrict__ cnt, float* __restrict__ dinv, int n) {
  int i = blockIdx.x * 256 + threadIdx.x;
  if (i < n) dinv[i] = rsqrtf((float)(cnt[i] + 1));  // +1 self loop; deg>0 always
}

// single-block exclusive scan over n counts -> off[0..n], cur[i]=off[i]
__global__ void scan_kernel(const int* __restrict__ cnt, int* __restrict__ off,
                            int* __restrict__ cur, int n) {
  __shared__ int tmp[1024];
  __shared__ int carry_s;
  int tid = threadIdx.x;
  if (tid == 0) carry_s = 0;
  __syncthreads();
  for (int base = 0; base < n; base += 1024) {
    int i = base + tid;
    int v = (i < n) ? cnt[i] : 0;
    tmp[tid] = v;
    __syncthreads();
    for (int d = 1; d < 1024; d <<= 1) {
      int t = (tid >= d) ? tmp[tid - d] : 0;
      __syncthreads();
      tmp[tid] += t;
      __syncthreads();
    }
    int incl = tmp[tid];
    int carry = carry_s;
    if (i < n) { int e0 = carry + incl - v; off[i] = e0; cur[i] = e0; }
    __syncthreads();
    if (tid == 1023) carry_s = carry + incl;
    __syncthreads();
  }
  if (tid == 0) off[n] = carry_s;
}

__global__ void fill_kernel(const int* __restrict__ src, const int* __restrict__ dst,
                            int E, int* __restrict__ cur, int* __restrict__ esrc) {
  int e = blockIdx.x * 256 + threadIdx.x;
  if (e < E) {
    int d = dst[e];
    int p = atomicAdd(&cur[d], 1);
    esrc[p] = src[e];
  }
}

// ---------------- GEMMs (fp32 vector) ----------------

// h1[50000,128] = x[50000,256] @ W1[256,128].  block=128 (one lane per col), 8 rows/block.
__global__ void gemm1_kernel(const float* __restrict__ x, const float* __restrict__ W,
                             float* __restrict__ h) {
  int c = threadIdx.x;
  int row0 = blockIdx.x * 8;
  float acc[8] = {0.f, 0.f, 0.f, 0.f, 0.f, 0.f, 0.f, 0.f};
  const float* xr = x + (size_t)row0 * C_IN;
  #pragma unroll 4
  for (int k = 0; k < C_IN; ++k) {
    float w = W[k * C_HID + c];
    #pragma unroll
    for (int r = 0; r < 8; ++r) acc[r] += xr[r * C_IN + k] * w;
  }
  #pragma unroll
  for (int r = 0; r < 8; ++r) h[(size_t)(row0 + r) * C_HID + c] = acc[r];
}

// h2[50000,40] = agg1[50000,128] @ W2[128,40].  block=256: 6 rows x 40 cols active.
__global__ void gemm2_kernel(const float* __restrict__ a, const float* __restrict__ W,
                             float* __restrict__ h, int nrows) {
  int tid = threadIdx.x;
  int rl = tid / 40, c = tid - rl * 40;
  int row = blockIdx.x * 6 + rl;
  if (rl >= 6 || row >= nrows) return;
  float acc = 0.f;
  const float* ar = a + (size_t)row * C_HID;
  #pragma unroll 4
  for (int k = 0; k < C_HID; ++k) acc += ar[k] * W[k * C_OUT + c];
  h[(size_t)row * C_OUT + c] = acc;
}

// ---------------- Aggregation ----------------

// out[i,c] = relu( sum_{j->i} h[j,c]*dinv[j]*dinv[i] + h[i,c]*dinv[i]^2 + b[c] )
__global__ void agg1_kernel(const float* __restrict__ h, const int* __restrict__ off,
                            const int* __restrict__ esrc, const float* __restrict__ dinv,
                            const float* __restrict__ b, float* __restrict__ out) {
  int i = blockIdx.x;
  int c = threadIdx.x;  // 128
  float di = dinv[i];
  float acc = h[(size_t)i * C_HID + c] * di * di;
  int p0 = off[i], p1 = off[i + 1];
  int p = p0;
  for (; p + 3 < p1; p += 4) {
    int s0 = esrc[p], s1 = esrc[p + 1], s2 = esrc[p + 2], s3 = esrc[p + 3];
    float n0 = dinv[s0] * di, n1 = dinv[s1] * di, n2 = dinv[s2] * di, n3 = dinv[s3] * di;
    acc += h[(size_t)s0 * C_HID + c] * n0;
    acc += h[(size_t)s1 * C_HID + c] * n1;
    acc += h[(size_t)s2 * C_HID + c] * n2;
    acc += h[(size_t)s3 * C_HID + c] * n3;
  }
  for (; p < p1; ++p) {
    int s = esrc[p];
    acc += h[(size_t)s * C_HID + c] * (dinv[s] * di);
  }
  acc += b[c];
  out[(size_t)i * C_HID + c] = fmaxf(acc, 0.0f);
}

// layer-2 aggregation + bias + log_softmax.  block=256 -> 4 waves, wave per node.
__global__ void agg2_kernel(const float* __restrict__ h, const int* __restrict__ off,
                            const int* __restrict__ esrc, const float* __restrict__ dinv,
                            const float* __restrict__ b, float* __restrict__ out, int n) {
  int wv = threadIdx.x >> 6, lane = threadIdx.x & 63;
  int i = blockIdx.x * 4 + wv;
  if (i >= n) return;
  bool act = lane < C_OUT;
  float di = dinv[i];
  float acc = act ? h[(size_t)i * C_OUT + lane] * di * di : 0.f;
  int p0 = off[i], p1 = off[i + 1];
  int p = p0;
  for (; p + 3 < p1; p += 4) {
    int s0 = esrc[p], s1 = esrc[p + 1], s2 = esrc[p + 2], s3 = esrc[p + 3];
    float n0 = dinv[s0] * di, n1 = dinv[s1] * di, n2 = dinv[s2] * di, n3 = dinv[s3] * di;
    if (act) {
      acc += h[(size_t)s0 * C_OUT + lane] * n0;
      acc += h[(size_t)s1 * C_OUT + lane] * n1;
      acc += h[(size_t)s2 * C_OUT + lane] * n2;
      acc += h[(size_t)s3 * C_OUT + lane] * n3;
    }
  }
  for (; p < p1; ++p) {
    int s = esrc[p];
    float nr = dinv[s] * di;
    if (act) acc += h[(size_t)s * C_OUT + lane] * nr;
  }
  float v = act ? acc + b[lane] : -INFINITY;
  float m = v;
  #pragma unroll
  for (int d = 32; d > 0; d >>= 1) m = fmaxf(m, __shfl_xor(m, d));
  float e = act ? expf(v - m) : 0.f;
  float ssum = e;
  #pragma unroll
  for (int d = 32; d > 0; d >>= 1) ssum += __shfl_xor(ssum, d);
  if (act) out[(size_t)i * C_OUT + lane] = v - m - logf(ssum);
}

// ---------------- launch ----------------

extern "C" void kernel_launch(void* const* d_in, const int* in_sizes, int n_in,
                              void* d_out, int out_size, void* d_ws, size_t ws_size,
                              hipStream_t stream) {
  const float* x  = (const float*)d_in[0];
  const int*   ei = (const int*)d_in[1];   // harness passes integer inputs as int32
  const float* W1 = (const float*)d_in[2];
  const float* b1 = (const float*)d_in[3];
  const float* W2 = (const float*)d_in[4];
  const float* b2 = (const float*)d_in[5];
  int E = in_sizes[1] / 2;
  const int* src = ei;
  const int* dst = ei + E;

  char* ws = (char*)d_ws;
  size_t o = 0;
  auto alloc = [&](size_t bytes) {
    char* p = ws + o;
    o += (bytes + 255) & ~(size_t)255;
    return p;
  };
  int*   off  = (int*)alloc((NN + 1) * sizeof(int));
  int*   cnt  = (int*)alloc(NN * sizeof(int));
  int*   cur  = (int*)alloc(NN * sizeof(int));
  float* dinv = (float*)alloc(NN * sizeof(float));
  int*   esrc = (int*)alloc((size_t)E * sizeof(int));
  float* h1   = (float*)alloc((size_t)NN * C_HID * sizeof(float));
  float* ag1  = (float*)alloc((size_t)NN * C_HID * sizeof(float));
  float* h2   = h1;  // h1 is dead after agg1; reuse its space for h2

  hipMemsetAsync(cnt, 0, NN * sizeof(int), stream);
  count_kernel<<<(E + 255) / 256, 256, 0, stream>>>(dst, E, cnt);
  dinv_kernel<<<(NN + 255) / 256, 256, 0, stream>>>(cnt, dinv, NN);
  scan_kernel<<<1, 1024, 0, stream>>>(cnt, off, cur, NN);
  fill_kernel<<<(E + 255) / 256, 256, 0, stream>>>(src, dst, E, cur, esrc);

  gemm1_kernel<<<NN / 8, 128, 0, stream>>>(x, W1, h1);
  agg1_kernel<<<NN, 128, 0, stream>>>(h1, off, esrc, dinv, b1, ag1);
  gemm2_kernel<<<(NN + 5) / 6, 256, 0, stream>>>(ag1, W2, h2, NN);
  agg2_kernel<<<(NN + 3) / 4, 256, 0, stream>>>(h2, off, esrc, dinv, b2, (float*)d_out, NN);
}

// Round 3
// 527.029 us; speedup vs baseline: 1.2761x; 1.2761x over previous
//
#include <hip/hip_runtime.h>
#include <cmath>

#define NN 50000
#define C_IN 256
#define C_HID 128
#define C_OUT 40
#define BM 64
#define BK 32

// ---------------- CSR build ----------------

__global__ void count_kernel(const int* __restrict__ dst, int E, int* __restrict__ cnt) {
  int e = blockIdx.x * 256 + threadIdx.x;
  if (e < E) atomicAdd(&cnt[dst[e]], 1);
}

// hierarchical scan, stage 1: per-block (1024 elems) local exclusive scan + block sum
__global__ void scan_blocks_kernel(const int* __restrict__ cnt, int* __restrict__ off,
                                   int* __restrict__ bsum, int n) {
  __shared__ int ts[256];
  int tid = threadIdx.x;
  int base = blockIdx.x * 1024 + tid * 4;
  int v0 = (base + 0 < n) ? cnt[base + 0] : 0;
  int v1 = (base + 1 < n) ? cnt[base + 1] : 0;
  int v2 = (base + 2 < n) ? cnt[base + 2] : 0;
  int v3 = (base + 3 < n) ? cnt[base + 3] : 0;
  int s0 = v0, s1 = s0 + v1, s2 = s1 + v2, s3 = s2 + v3;
  ts[tid] = s3;
  __syncthreads();
  for (int d = 1; d < 256; d <<= 1) {
    int t = (tid >= d) ? ts[tid - d] : 0;
    __syncthreads();
    ts[tid] += t;
    __syncthreads();
  }
  int excl = ts[tid] - s3;  // exclusive prefix of this thread's 4-group
  if (base + 0 < n) off[base + 0] = excl;
  if (base + 1 < n) off[base + 1] = excl + s0;
  if (base + 2 < n) off[base + 2] = excl + s1;
  if (base + 3 < n) off[base + 3] = excl + s2;
  if (tid == 255) bsum[blockIdx.x] = ts[255];
}

// stage 2: single-wave scan of block sums (NB <= 64)
__global__ void scan_carry_kernel(const int* __restrict__ bsum, int* __restrict__ carry,
                                  int* __restrict__ off, int nb, int n) {
  int l = threadIdx.x;
  int v = (l < nb) ? bsum[l] : 0;
  int x = v;
  #pragma unroll
  for (int d = 1; d < 64; d <<= 1) {
    int t = __shfl_up(x, d);
    if (l >= d) x += t;
  }
  if (l < nb) carry[l] = x - v;       // exclusive
  if (l == nb - 1) off[n] = x;        // grand total
}

// stage 3: add carries; also cur[] and dinv[]
__global__ void scan_add_kernel(int* __restrict__ off, const int* __restrict__ carry,
                                int* __restrict__ cur, const int* __restrict__ cnt,
                                float* __restrict__ dinv, int n) {
  int i = blockIdx.x * 256 + threadIdx.x;
  if (i < n) {
    int o = off[i] + carry[i >> 10];
    off[i] = o;
    cur[i] = o;
    dinv[i] = rsqrtf((float)(cnt[i] + 1));  // +1 self loop
  }
}

__global__ void fill_kernel(const int* __restrict__ src, const int* __restrict__ dst,
                            int E, int* __restrict__ cur, int* __restrict__ esrc) {
  int e = blockIdx.x * 256 + threadIdx.x;
  if (e < E) {
    int d = dst[e];
    int p = atomicAdd(&cur[d], 1);
    esrc[p] = src[e];
  }
}

// ---------------- GEMM 1: h1[50000,128] = x[50000,256] @ W1[256,128] ----------------
// LDS-tiled: 64x128 tile, BK=32, 256 threads, 8x4 micro-tile/thread.
__global__ __launch_bounds__(256) void gemm1_kernel(const float* __restrict__ x,
                                                    const float* __restrict__ W,
                                                    float* __restrict__ h) {
  __shared__ float xsT[BK][BM + 4];   // transposed: xsT[k][r], pad to 68 (16B-aligned rows)
  __shared__ float ws[BK][C_HID];
  int tid = threadIdx.x;
  int tx = tid & 31, ty = tid >> 5;   // tx: col group (4 cols), ty: row group (8 rows)
  int row0 = blockIdx.x * BM;
  float acc[8][4] = {};

  int r = tid & 63, kq = tid >> 6;    // x staging: 64 rows x (4 k-chunks of 8)
  int xrow = min(row0 + r, NN - 1);
  const float* xp = x + (size_t)xrow * C_IN + kq * 8;

  for (int k0 = 0; k0 < C_IN; k0 += BK) {
    float4 a0 = *(const float4*)(xp + k0);
    float4 a1 = *(const float4*)(xp + k0 + 4);
    float4 wv[4];
    #pragma unroll
    for (int j = 0; j < 4; ++j) {
      int slot = tid + j * 256;
      int kk = slot >> 5, cc = (slot & 31) * 4;
      wv[j] = *(const float4*)(W + (size_t)(k0 + kk) * C_HID + cc);
    }
    __syncthreads();  // previous compute done reading LDS
    int kb = kq * 8;
    xsT[kb + 0][r] = a0.x; xsT[kb + 1][r] = a0.y; xsT[kb + 2][r] = a0.z; xsT[kb + 3][r] = a0.w;
    xsT[kb + 4][r] = a1.x; xsT[kb + 5][r] = a1.y; xsT[kb + 6][r] = a1.z; xsT[kb + 7][r] = a1.w;
    #pragma unroll
    for (int j = 0; j < 4; ++j) {
      int slot = tid + j * 256;
      int kk = slot >> 5, cc = (slot & 31) * 4;
      *(float4*)&ws[kk][cc] = wv[j];
    }
    __syncthreads();
    #pragma unroll
    for (int kk = 0; kk < BK; ++kk) {
      float4 af0 = *(const float4*)&xsT[kk][ty * 8];
      float4 af1 = *(const float4*)&xsT[kk][ty * 8 + 4];
      float4 bf  = *(const float4*)&ws[kk][tx * 4];
      float a[8] = {af0.x, af0.y, af0.z, af0.w, af1.x, af1.y, af1.z, af1.w};
      #pragma unroll
      for (int rr = 0; rr < 8; ++rr) {
        acc[rr][0] += a[rr] * bf.x;
        acc[rr][1] += a[rr] * bf.y;
        acc[rr][2] += a[rr] * bf.z;
        acc[rr][3] += a[rr] * bf.w;
      }
    }
  }
  #pragma unroll
  for (int rr = 0; rr < 8; ++rr) {
    int row = row0 + ty * 8 + rr;
    if (row < NN) {
      float4 v = {acc[rr][0], acc[rr][1], acc[rr][2], acc[rr][3]};
      *(float4*)&h[(size_t)row * C_HID + tx * 4] = v;
    }
  }
}

// ---------------- GEMM 2: h2[50000,40] = ag1[50000,128] @ W2[128,40] ----------------
__global__ void gemm2_kernel(const float* __restrict__ a, const float* __restrict__ W,
                             float* __restrict__ h, int nrows) {
  int tid = threadIdx.x;
  int rl = tid / 40, c = tid - rl * 40;
  int row = blockIdx.x * 6 + rl;
  if (rl >= 6 || row >= nrows) return;
  float acc = 0.f;
  const float* ar = a + (size_t)row * C_HID;
  #pragma unroll 4
  for (int k = 0; k < C_HID; ++k) acc += ar[k] * W[k * C_OUT + c];
  h[(size_t)row * C_OUT + c] = acc;
}

// ---------------- Aggregation ----------------

// 1 wave per node, float2 per lane (128 channels).
__global__ void agg1_kernel(const float* __restrict__ h, const int* __restrict__ off,
                            const int* __restrict__ esrc, const float* __restrict__ dinv,
                            const float* __restrict__ b, float* __restrict__ out) {
  int i = blockIdx.x;
  int l = threadIdx.x;  // 64
  float di = dinv[i];
  const float2* hp = (const float2*)h;
  float2 self = hp[(size_t)i * 64 + l];
  float ax = self.x * di * di, ay = self.y * di * di;
  int p0 = off[i], p1 = off[i + 1];
  int p = p0;
  for (; p + 3 < p1; p += 4) {
    int s0 = esrc[p], s1 = esrc[p + 1], s2 = esrc[p + 2], s3 = esrc[p + 3];
    float n0 = dinv[s0] * di, n1 = dinv[s1] * di, n2 = dinv[s2] * di, n3 = dinv[s3] * di;
    float2 v0 = hp[(size_t)s0 * 64 + l];
    float2 v1 = hp[(size_t)s1 * 64 + l];
    float2 v2 = hp[(size_t)s2 * 64 + l];
    float2 v3 = hp[(size_t)s3 * 64 + l];
    ax += v0.x * n0; ay += v0.y * n0;
    ax += v1.x * n1; ay += v1.y * n1;
    ax += v2.x * n2; ay += v2.y * n2;
    ax += v3.x * n3; ay += v3.y * n3;
  }
  for (; p < p1; ++p) {
    int s = esrc[p];
    float nr = dinv[s] * di;
    float2 v = hp[(size_t)s * 64 + l];
    ax += v.x * nr; ay += v.y * nr;
  }
  float2 bb = ((const float2*)b)[l];
  float2 res;
  res.x = fmaxf(ax + bb.x, 0.f);
  res.y = fmaxf(ay + bb.y, 0.f);
  ((float2*)out)[(size_t)i * 64 + l] = res;
}

// layer-2 aggregation + bias + log_softmax.  wave per node, 4 waves/block.
__global__ void agg2_kernel(const float* __restrict__ h, const int* __restrict__ off,
                            const int* __restrict__ esrc, const float* __restrict__ dinv,
                            const float* __restrict__ b, float* __restrict__ out, int n) {
  int wv = threadIdx.x >> 6, lane = threadIdx.x & 63;
  int i = blockIdx.x * 4 + wv;
  if (i >= n) return;
  bool act = lane < C_OUT;
  float di = dinv[i];
  float acc = act ? h[(size_t)i * C_OUT + lane] * di * di : 0.f;
  int p0 = off[i], p1 = off[i + 1];
  int p = p0;
  for (; p + 3 < p1; p += 4) {
    int s0 = esrc[p], s1 = esrc[p + 1], s2 = esrc[p + 2], s3 = esrc[p + 3];
    float n0 = dinv[s0] * di, n1 = dinv[s1] * di, n2 = dinv[s2] * di, n3 = dinv[s3] * di;
    if (act) {
      acc += h[(size_t)s0 * C_OUT + lane] * n0;
      acc += h[(size_t)s1 * C_OUT + lane] * n1;
      acc += h[(size_t)s2 * C_OUT + lane] * n2;
      acc += h[(size_t)s3 * C_OUT + lane] * n3;
    }
  }
  for (; p < p1; ++p) {
    int s = esrc[p];
    float nr = dinv[s] * di;
    if (act) acc += h[(size_t)s * C_OUT + lane] * nr;
  }
  float v = act ? acc + b[lane] : -INFINITY;
  float m = v;
  #pragma unroll
  for (int d = 32; d > 0; d >>= 1) m = fmaxf(m, __shfl_xor(m, d));
  float e = act ? expf(v - m) : 0.f;
  float ssum = e;
  #pragma unroll
  for (int d = 32; d > 0; d >>= 1) ssum += __shfl_xor(ssum, d);
  if (act) out[(size_t)i * C_OUT + lane] = v - m - logf(ssum);
}

// ---------------- launch ----------------

extern "C" void kernel_launch(void* const* d_in, const int* in_sizes, int n_in,
                              void* d_out, int out_size, void* d_ws, size_t ws_size,
                              hipStream_t stream) {
  const float* x  = (const float*)d_in[0];
  const int*   ei = (const int*)d_in[1];   // harness passes integer inputs as int32
  const float* W1 = (const float*)d_in[2];
  const float* b1 = (const float*)d_in[3];
  const float* W2 = (const float*)d_in[4];
  const float* b2 = (const float*)d_in[5];
  int E = in_sizes[1] / 2;
  const int* src = ei;
  const int* dst = ei + E;

  char* ws = (char*)d_ws;
  size_t o = 0;
  auto alloc = [&](size_t bytes) {
    char* p = ws + o;
    o += (bytes + 255) & ~(size_t)255;
    return p;
  };
  int*   off   = (int*)alloc((NN + 1) * sizeof(int));
  int*   cnt   = (int*)alloc(NN * sizeof(int));
  int*   cur   = (int*)alloc(NN * sizeof(int));
  float* dinv  = (float*)alloc(NN * sizeof(float));
  int*   esrc  = (int*)alloc((size_t)E * sizeof(int));
  int*   bsum  = (int*)alloc(64 * sizeof(int));
  int*   carry = (int*)alloc(64 * sizeof(int));
  float* h1    = (float*)alloc((size_t)NN * C_HID * sizeof(float));
  float* ag1   = (float*)alloc((size_t)NN * C_HID * sizeof(float));
  float* h2    = h1;  // h1 dead after agg1; reuse for h2

  int NB = (NN + 1023) >> 10;  // 49

  hipMemsetAsync(cnt, 0, NN * sizeof(int), stream);
  count_kernel<<<(E + 255) / 256, 256, 0, stream>>>(dst, E, cnt);
  scan_blocks_kernel<<<NB, 256, 0, stream>>>(cnt, off, bsum, NN);
  scan_carry_kernel<<<1, 64, 0, stream>>>(bsum, carry, off, NB, NN);
  scan_add_kernel<<<(NN + 255) / 256, 256, 0, stream>>>(off, carry, cur, cnt, dinv, NN);
  fill_kernel<<<(E + 255) / 256, 256, 0, stream>>>(src, dst, E, cur, esrc);

  gemm1_kernel<<<(NN + BM - 1) / BM, 256, 0, stream>>>(x, W1, h1);
  agg1_kernel<<<NN, 64, 0, stream>>>(h1, off, esrc, dinv, b1, ag1);
  gemm2_kernel<<<(NN + 5) / 6, 256, 0, stream>>>(ag1, W2, h2, NN);
  agg2_kernel<<<(NN + 3) / 4, 256, 0, stream>>>(h2, off, esrc, dinv, b2, (float*)d_out, NN);
}

// Round 4
// 298.954 us; speedup vs baseline: 2.2496x; 1.7629x over previous
//
#include <hip/hip_runtime.h>
#include <cmath>

#define NN 50000
#define C_IN 256
#define C_HID 128
#define C_OUT 40
#define BM 64
#define BK 32

#define BSZ 512                          // nodes per bucket
#define NBUCK ((NN + BSZ - 1) / BSZ)     // 98
#define CAP 19456                        // max edges per bucket region (mean 16384, std 127)
#define EPB 4096                         // edges per passA block

__device__ __forceinline__ float bf2f(unsigned int u16) {
  unsigned int b = (u16 & 0xFFFFu) << 16;
  return __builtin_bit_cast(float, b);
}
__device__ __forceinline__ unsigned short f2bf(float f) {
  unsigned int b = __builtin_bit_cast(unsigned int, f);
  unsigned int r = (b + 0x7FFF + ((b >> 16) & 1)) >> 16;  // RNE
  return (unsigned short)r;
}

// ---------------- CSR build: pass A — LDS-binned partition into NBUCK regions ------------

__global__ __launch_bounds__(256) void passA_kernel(const int* __restrict__ src,
    const int* __restrict__ dst, int E, unsigned int* __restrict__ gedge,
    int* __restrict__ bcur) {
  __shared__ unsigned int pk[EPB];
  __shared__ unsigned char bof[EPB];
  __shared__ int bcnt[NBUCK], bstart[NBUCK], bpos[NBUCK], gbase[NBUCK];
  int tid = threadIdx.x;
  int e0 = blockIdx.x * EPB;
  int cnt = min(EPB, E - e0);
  for (int b = tid; b < NBUCK; b += 256) bcnt[b] = 0;
  int ds_[16], ss_[16];
  __syncthreads();
  #pragma unroll
  for (int k = 0; k < 16; ++k) {
    int i = tid + k * 256;
    if (i < cnt) {
      ds_[k] = dst[e0 + i];
      ss_[k] = src[e0 + i];
      atomicAdd(&bcnt[ds_[k] >> 9], 1);
    }
  }
  __syncthreads();
  if (tid == 0) {  // serial exclusive scan of 98 bins (cheap vs rest of block)
    int acc = 0;
    for (int b = 0; b < NBUCK; ++b) { bstart[b] = acc; bpos[b] = acc; acc += bcnt[b]; }
  }
  __syncthreads();
  #pragma unroll
  for (int k = 0; k < 16; ++k) {
    int i = tid + k * 256;
    if (i < cnt) {
      int b = ds_[k] >> 9;
      int p = atomicAdd(&bpos[b], 1);
      pk[p] = ((unsigned int)ss_[k] << 9) | (unsigned int)(ds_[k] & 511);  // src<16b, dloc 9b
      bof[p] = (unsigned char)b;
    }
  }
  __syncthreads();
  for (int b = tid; b < NBUCK; b += 256)
    gbase[b] = atomicAdd(&bcur[b], bcnt[b]);  // reserve contiguous chunk per bucket
  __syncthreads();
  for (int i = tid; i < cnt; i += 256) {      // bin-ordered -> coalesced global writes
    int b = bof[i];
    int p = gbase[b] + (i - bstart[b]);
    gedge[(size_t)b * CAP + p] = pk[i];
  }
}

// exclusive scan of the 98 bucket totals
__global__ void bscan_kernel(const int* __restrict__ bcur, int* __restrict__ goff,
                             int* __restrict__ off, int E) {
  __shared__ int t[128];
  int tid = threadIdx.x;
  int v = (tid < NBUCK) ? bcur[tid] : 0;
  t[tid] = v;
  __syncthreads();
  for (int d = 1; d < 128; d <<= 1) {
    int x = (tid >= d) ? t[tid - d] : 0;
    __syncthreads();
    t[tid] += x;
    __syncthreads();
  }
  if (tid < NBUCK) goff[tid] = t[tid] - v;
  if (tid == 0) { goff[NBUCK] = E; off[NN] = E; }
}

// pass B — per-bucket counting sort; emits esrc, off, dinv
__global__ __launch_bounds__(512) void passB_kernel(const unsigned int* __restrict__ gedge,
    const int* __restrict__ bcur, const int* __restrict__ goff,
    int* __restrict__ esrc, int* __restrict__ off, float* __restrict__ dinv) {
  __shared__ int dcnt[512];
  __shared__ int dsc[512];
  __shared__ int dcur[512];
  int b = blockIdx.x, tid = threadIdx.x;
  int nE = bcur[b];
  int base = goff[b];
  const unsigned int* reg = gedge + (size_t)b * CAP;
  dcnt[tid] = 0;
  __syncthreads();
  for (int i = tid; i < nE; i += 512)
    atomicAdd(&dcnt[reg[i] & 511], 1);
  __syncthreads();
  int own = dcnt[tid];
  dsc[tid] = own;
  __syncthreads();
  for (int d = 1; d < 512; d <<= 1) {  // Hillis-Steele inclusive
    int x = (tid >= d) ? dsc[tid - d] : 0;
    __syncthreads();
    dsc[tid] += x;
    __syncthreads();
  }
  int excl = dsc[tid] - own;
  dcur[tid] = excl;
  int node = b * BSZ + tid;
  if (node < NN) {
    off[node]  = base + excl;
    dinv[node] = rsqrtf((float)(own + 1));  // +1 self loop
  }
  __syncthreads();
  for (int i = tid; i < nE; i += 512) {
    unsigned int p = reg[i];
    int pos = atomicAdd(&dcur[p & 511], 1);
    esrc[base + pos] = (int)(p >> 9);
  }
}

// precompute dinv[src] per edge so aggs do zero random dinv gathers
__global__ void expand_kernel(const int* __restrict__ esrc, const float* __restrict__ dinv,
                              float* __restrict__ dinvs, int E) {
  int e = blockIdx.x * 256 + threadIdx.x;
  if (e < E) dinvs[e] = dinv[esrc[e]];
}

// ---------------- GEMM 1: h1[50000,128](bf16) = x[50000,256] @ W1[256,128] --------------

__global__ __launch_bounds__(256) void gemm1_kernel(const float* __restrict__ x,
                                                    const float* __restrict__ W,
                                                    unsigned short* __restrict__ h) {
  __shared__ float xsT[BK][BM + 4];
  __shared__ float ws[BK][C_HID];
  int tid = threadIdx.x;
  int tx = tid & 31, ty = tid >> 5;
  int row0 = blockIdx.x * BM;
  float acc[8][4] = {};

  int r = tid & 63, kq = tid >> 6;
  int xrow = min(row0 + r, NN - 1);
  const float* xp = x + (size_t)xrow * C_IN + kq * 8;

  for (int k0 = 0; k0 < C_IN; k0 += BK) {
    float4 a0 = *(const float4*)(xp + k0);
    float4 a1 = *(const float4*)(xp + k0 + 4);
    float4 wv[4];
    #pragma unroll
    for (int j = 0; j < 4; ++j) {
      int slot = tid + j * 256;
      int kk = slot >> 5, cc = (slot & 31) * 4;
      wv[j] = *(const float4*)(W + (size_t)(k0 + kk) * C_HID + cc);
    }
    __syncthreads();
    int kb = kq * 8;
    xsT[kb + 0][r] = a0.x; xsT[kb + 1][r] = a0.y; xsT[kb + 2][r] = a0.z; xsT[kb + 3][r] = a0.w;
    xsT[kb + 4][r] = a1.x; xsT[kb + 5][r] = a1.y; xsT[kb + 6][r] = a1.z; xsT[kb + 7][r] = a1.w;
    #pragma unroll
    for (int j = 0; j < 4; ++j) {
      int slot = tid + j * 256;
      int kk = slot >> 5, cc = (slot & 31) * 4;
      *(float4*)&ws[kk][cc] = wv[j];
    }
    __syncthreads();
    #pragma unroll
    for (int kk = 0; kk < BK; ++kk) {
      float4 af0 = *(const float4*)&xsT[kk][ty * 8];
      float4 af1 = *(const float4*)&xsT[kk][ty * 8 + 4];
      float4 bf  = *(const float4*)&ws[kk][tx * 4];
      float a[8] = {af0.x, af0.y, af0.z, af0.w, af1.x, af1.y, af1.z, af1.w};
      #pragma unroll
      for (int rr = 0; rr < 8; ++rr) {
        acc[rr][0] += a[rr] * bf.x;
        acc[rr][1] += a[rr] * bf.y;
        acc[rr][2] += a[rr] * bf.z;
        acc[rr][3] += a[rr] * bf.w;
      }
    }
  }
  #pragma unroll
  for (int rr = 0; rr < 8; ++rr) {
    int row = row0 + ty * 8 + rr;
    if (row < NN) {
      ushort4 v;
      v.x = f2bf(acc[rr][0]); v.y = f2bf(acc[rr][1]);
      v.z = f2bf(acc[rr][2]); v.w = f2bf(acc[rr][3]);
      *(ushort4*)&h[(size_t)row * C_HID + tx * 4] = v;
    }
  }
}

// ---------------- GEMM 2: h2[50000,40](bf16) = ag1[50000,128] @ W2[128,40] --------------

__global__ void gemm2_kernel(const float* __restrict__ a, const float* __restrict__ W,
                             unsigned short* __restrict__ h, int nrows) {
  int tid = threadIdx.x;
  int rl = tid / 40, c = tid - rl * 40;
  int row = blockIdx.x * 6 + rl;
  if (rl >= 6 || row >= nrows) return;
  float acc = 0.f;
  const float* ar = a + (size_t)row * C_HID;
  #pragma unroll 4
  for (int k = 0; k < C_HID; ++k) acc += ar[k] * W[k * C_OUT + c];
  h[(size_t)row * C_OUT + c] = f2bf(acc);
}

// ---------------- Aggregation ----------------

// 1 wave per node; h1 is bf16 (uint = 2 channels per lane).
__global__ void agg1_kernel(const unsigned short* __restrict__ h, const int* __restrict__ off,
                            const int* __restrict__ esrc, const float* __restrict__ dinvs,
                            const float* __restrict__ dinv, const float* __restrict__ b,
                            float* __restrict__ out) {
  int i = blockIdx.x;
  int l = threadIdx.x;  // 64
  float di = dinv[i];
  const unsigned int* hp = (const unsigned int*)h;
  unsigned int su = hp[(size_t)i * 64 + l];
  float ax = bf2f(su) * di * di, ay = bf2f(su >> 16) * di * di;
  int p0 = off[i], p1 = off[i + 1];
  int p = p0;
  for (; p + 3 < p1; p += 4) {
    int s0 = esrc[p], s1 = esrc[p + 1], s2 = esrc[p + 2], s3 = esrc[p + 3];
    float n0 = dinvs[p] * di, n1 = dinvs[p + 1] * di, n2 = dinvs[p + 2] * di,
          n3 = dinvs[p + 3] * di;
    unsigned int v0 = hp[(size_t)s0 * 64 + l];
    unsigned int v1 = hp[(size_t)s1 * 64 + l];
    unsigned int v2 = hp[(size_t)s2 * 64 + l];
    unsigned int v3 = hp[(size_t)s3 * 64 + l];
    ax += bf2f(v0) * n0; ay += bf2f(v0 >> 16) * n0;
    ax += bf2f(v1) * n1; ay += bf2f(v1 >> 16) * n1;
    ax += bf2f(v2) * n2; ay += bf2f(v2 >> 16) * n2;
    ax += bf2f(v3) * n3; ay += bf2f(v3 >> 16) * n3;
  }
  for (; p < p1; ++p) {
    int s = esrc[p];
    float nr = dinvs[p] * di;
    unsigned int v = hp[(size_t)s * 64 + l];
    ax += bf2f(v) * nr; ay += bf2f(v >> 16) * nr;
  }
  float2 bb = ((const float2*)b)[l];
  float2 res;
  res.x = fmaxf(ax + bb.x, 0.f);
  res.y = fmaxf(ay + bb.y, 0.f);
  ((float2*)out)[(size_t)i * 64 + l] = res;
}

// layer-2 aggregation + bias + log_softmax; h2 bf16; wave per node.
__global__ void agg2_kernel(const unsigned short* __restrict__ h, const int* __restrict__ off,
                            const int* __restrict__ esrc, const float* __restrict__ dinvs,
                            const float* __restrict__ dinv, const float* __restrict__ b,
                            float* __restrict__ out, int n) {
  int wv = threadIdx.x >> 6, lane = threadIdx.x & 63;
  int i = blockIdx.x * 4 + wv;
  if (i >= n) return;
  bool act = lane < C_OUT;
  float di = dinv[i];
  float acc = act ? bf2f(h[(size_t)i * C_OUT + lane]) * di * di : 0.f;
  int p0 = off[i], p1 = off[i + 1];
  int p = p0;
  for (; p + 3 < p1; p += 4) {
    int s0 = esrc[p], s1 = esrc[p + 1], s2 = esrc[p + 2], s3 = esrc[p + 3];
    float n0 = dinvs[p] * di, n1 = dinvs[p + 1] * di, n2 = dinvs[p + 2] * di,
          n3 = dinvs[p + 3] * di;
    if (act) {
      acc += bf2f(h[(size_t)s0 * C_OUT + lane]) * n0;
      acc += bf2f(h[(size_t)s1 * C_OUT + lane]) * n1;
      acc += bf2f(h[(size_t)s2 * C_OUT + lane]) * n2;
      acc += bf2f(h[(size_t)s3 * C_OUT + lane]) * n3;
    }
  }
  for (; p < p1; ++p) {
    int s = esrc[p];
    float nr = dinvs[p] * di;
    if (act) acc += bf2f(h[(size_t)s * C_OUT + lane]) * nr;
  }
  float v = act ? acc + b[lane] : -INFINITY;
  float m = v;
  #pragma unroll
  for (int d = 32; d > 0; d >>= 1) m = fmaxf(m, __shfl_xor(m, d));
  float e = act ? expf(v - m) : 0.f;
  float ssum = e;
  #pragma unroll
  for (int d = 32; d > 0; d >>= 1) ssum += __shfl_xor(ssum, d);
  if (act) out[(size_t)i * C_OUT + lane] = v - m - logf(ssum);
}

// ---------------- launch ----------------

extern "C" void kernel_launch(void* const* d_in, const int* in_sizes, int n_in,
                              void* d_out, int out_size, void* d_ws, size_t ws_size,
                              hipStream_t stream) {
  const float* x  = (const float*)d_in[0];
  const int*   ei = (const int*)d_in[1];   // integer inputs arrive as int32
  const float* W1 = (const float*)d_in[2];
  const float* b1 = (const float*)d_in[3];
  const float* W2 = (const float*)d_in[4];
  const float* b2 = (const float*)d_in[5];
  int E = in_sizes[1] / 2;
  const int* src = ei;
  const int* dst = ei + E;

  char* ws = (char*)d_ws;
  size_t o = 0;
  auto alloc = [&](size_t bytes) {
    char* p = ws + o;
    o += (bytes + 255) & ~(size_t)255;
    return p;
  };
  unsigned int* gedge = (unsigned int*)alloc((size_t)NBUCK * CAP * sizeof(unsigned int));
  int*   bcur  = (int*)alloc(NBUCK * sizeof(int));
  int*   goff  = (int*)alloc((NBUCK + 1) * sizeof(int));
  int*   off   = (int*)alloc((NN + 1) * sizeof(int));
  float* dinv  = (float*)alloc(NN * sizeof(float));
  int*   esrc  = (int*)alloc((size_t)E * sizeof(int));
  float* dinvs = (float*)alloc((size_t)E * sizeof(float));
  unsigned short* h1b = (unsigned short*)alloc((size_t)NN * C_HID * sizeof(unsigned short));
  float* ag1   = (float*)alloc((size_t)NN * C_HID * sizeof(float));
  unsigned short* h2b = (unsigned short*)alloc((size_t)NN * C_OUT * sizeof(unsigned short));

  hipMemsetAsync(bcur, 0, NBUCK * sizeof(int), stream);
  passA_kernel<<<(E + EPB - 1) / EPB, 256, 0, stream>>>(src, dst, E, gedge, bcur);
  bscan_kernel<<<1, 128, 0, stream>>>(bcur, goff, off, E);
  passB_kernel<<<NBUCK, 512, 0, stream>>>(gedge, bcur, goff, esrc, off, dinv);
  expand_kernel<<<(E + 255) / 256, 256, 0, stream>>>(esrc, dinv, dinvs, E);

  gemm1_kernel<<<(NN + BM - 1) / BM, 256, 0, stream>>>(x, W1, h1b);
  agg1_kernel<<<NN, 64, 0, stream>>>(h1b, off, esrc, dinvs, dinv, b1, ag1);
  gemm2_kernel<<<(NN + 5) / 6, 256, 0, stream>>>(ag1, W2, h2b, NN);
  agg2_kernel<<<(NN + 3) / 4, 256, 0, stream>>>(h2b, off, esrc, dinvs, dinv, b2,
                                                (float*)d_out, NN);
}

// Round 5
// 236.780 us; speedup vs baseline: 2.8404x; 1.2626x over previous
//
#include <hip/hip_runtime.h>
#include <cmath>

#define NN 50000
#define C_IN 256
#define C_HID 128
#define C_OUT 40
#define BM 64
#define BK 32

#define BSZ 512                          // nodes per bucket
#define NBUCK ((NN + BSZ - 1) / BSZ)     // 98
#define CAP 19456                        // max edges per bucket region
#define EPB 4096                         // edges per passA block

typedef __attribute__((ext_vector_type(8))) short bf16x8;
typedef __attribute__((ext_vector_type(4))) float f32x4;

__device__ __forceinline__ float bf2f(unsigned int u16) {
  unsigned int b = (u16 & 0xFFFFu) << 16;
  return __builtin_bit_cast(float, b);
}
__device__ __forceinline__ unsigned short f2bf(float f) {
  unsigned int b = __builtin_bit_cast(unsigned int, f);
  unsigned int r = (b + 0x7FFF + ((b >> 16) & 1)) >> 16;  // RNE
  return (unsigned short)r;
}

// ---------------- CSR build: pass A — LDS-binned partition into NBUCK regions ------------

__global__ __launch_bounds__(256) void passA_kernel(const int* __restrict__ src,
    const int* __restrict__ dst, int E, unsigned int* __restrict__ gedge,
    int* __restrict__ bcur) {
  __shared__ unsigned int pk[EPB];
  __shared__ unsigned char bof[EPB];
  __shared__ int bcnt[NBUCK], bstart[NBUCK], bpos[NBUCK], gbase[NBUCK];
  int tid = threadIdx.x;
  int e0 = blockIdx.x * EPB;
  int cnt = min(EPB, E - e0);
  for (int b = tid; b < NBUCK; b += 256) bcnt[b] = 0;
  int ds_[16], ss_[16];
  __syncthreads();
  #pragma unroll
  for (int k = 0; k < 16; ++k) {
    int i = tid + k * 256;
    if (i < cnt) {
      ds_[k] = dst[e0 + i];
      ss_[k] = src[e0 + i];
      atomicAdd(&bcnt[ds_[k] >> 9], 1);
    }
  }
  __syncthreads();
  if (tid == 0) {
    int acc = 0;
    for (int b = 0; b < NBUCK; ++b) { bstart[b] = acc; bpos[b] = acc; acc += bcnt[b]; }
  }
  __syncthreads();
  #pragma unroll
  for (int k = 0; k < 16; ++k) {
    int i = tid + k * 256;
    if (i < cnt) {
      int b = ds_[k] >> 9;
      int p = atomicAdd(&bpos[b], 1);
      pk[p] = ((unsigned int)ss_[k] << 9) | (unsigned int)(ds_[k] & 511);
      bof[p] = (unsigned char)b;
    }
  }
  __syncthreads();
  for (int b = tid; b < NBUCK; b += 256)
    gbase[b] = atomicAdd(&bcur[b], bcnt[b]);
  __syncthreads();
  for (int i = tid; i < cnt; i += 256) {
    int b = bof[i];
    int p = gbase[b] + (i - bstart[b]);
    gedge[(size_t)b * CAP + p] = pk[i];
  }
}

__global__ void bscan_kernel(const int* __restrict__ bcur, int* __restrict__ goff,
                             int* __restrict__ off, int E) {
  __shared__ int t[128];
  int tid = threadIdx.x;
  int v = (tid < NBUCK) ? bcur[tid] : 0;
  t[tid] = v;
  __syncthreads();
  for (int d = 1; d < 128; d <<= 1) {
    int x = (tid >= d) ? t[tid - d] : 0;
    __syncthreads();
    t[tid] += x;
    __syncthreads();
  }
  if (tid < NBUCK) goff[tid] = t[tid] - v;
  if (tid == 0) { goff[NBUCK] = E; off[NN] = E; }
}

__global__ __launch_bounds__(512) void passB_kernel(const unsigned int* __restrict__ gedge,
    const int* __restrict__ bcur, const int* __restrict__ goff,
    int* __restrict__ esrc, int* __restrict__ off, float* __restrict__ dinv) {
  __shared__ int dcnt[512];
  __shared__ int dsc[512];
  __shared__ int dcur[512];
  int b = blockIdx.x, tid = threadIdx.x;
  int nE = bcur[b];
  int base = goff[b];
  const unsigned int* reg = gedge + (size_t)b * CAP;
  dcnt[tid] = 0;
  __syncthreads();
  for (int i = tid; i < nE; i += 512)
    atomicAdd(&dcnt[reg[i] & 511], 1);
  __syncthreads();
  int own = dcnt[tid];
  dsc[tid] = own;
  __syncthreads();
  for (int d = 1; d < 512; d <<= 1) {
    int x = (tid >= d) ? dsc[tid - d] : 0;
    __syncthreads();
    dsc[tid] += x;
    __syncthreads();
  }
  int excl = dsc[tid] - own;
  dcur[tid] = excl;
  int node = b * BSZ + tid;
  if (node < NN) {
    off[node]  = base + excl;
    dinv[node] = rsqrtf((float)(own + 1));
  }
  __syncthreads();
  for (int i = tid; i < nE; i += 512) {
    unsigned int p = reg[i];
    int pos = atomicAdd(&dcur[p & 511], 1);
    esrc[base + pos] = (int)(p >> 9);
  }
}

__global__ void expand_kernel(const int* __restrict__ esrc, const float* __restrict__ dinv,
                              float* __restrict__ dinvs, int E) {
  int e = blockIdx.x * 256 + threadIdx.x;
  if (e < E) dinvs[e] = dinv[esrc[e]];
}

// ---------------- GEMM 1: h1[50000,128](bf16) = x[50000,256] @ W1[256,128] --------------

__global__ __launch_bounds__(256) void gemm1_kernel(const float* __restrict__ x,
                                                    const float* __restrict__ W,
                                                    unsigned short* __restrict__ h) {
  __shared__ float xsT[BK][BM + 4];
  __shared__ float ws[BK][C_HID];
  int tid = threadIdx.x;
  int tx = tid & 31, ty = tid >> 5;
  int row0 = blockIdx.x * BM;
  float acc[8][4] = {};

  int r = tid & 63, kq = tid >> 6;
  int xrow = min(row0 + r, NN - 1);
  const float* xp = x + (size_t)xrow * C_IN + kq * 8;

  for (int k0 = 0; k0 < C_IN; k0 += BK) {
    float4 a0 = *(const float4*)(xp + k0);
    float4 a1 = *(const float4*)(xp + k0 + 4);
    float4 wv[4];
    #pragma unroll
    for (int j = 0; j < 4; ++j) {
      int slot = tid + j * 256;
      int kk = slot >> 5, cc = (slot & 31) * 4;
      wv[j] = *(const float4*)(W + (size_t)(k0 + kk) * C_HID + cc);
    }
    __syncthreads();
    int kb = kq * 8;
    xsT[kb + 0][r] = a0.x; xsT[kb + 1][r] = a0.y; xsT[kb + 2][r] = a0.z; xsT[kb + 3][r] = a0.w;
    xsT[kb + 4][r] = a1.x; xsT[kb + 5][r] = a1.y; xsT[kb + 6][r] = a1.z; xsT[kb + 7][r] = a1.w;
    #pragma unroll
    for (int j = 0; j < 4; ++j) {
      int slot = tid + j * 256;
      int kk = slot >> 5, cc = (slot & 31) * 4;
      *(float4*)&ws[kk][cc] = wv[j];
    }
    __syncthreads();
    #pragma unroll
    for (int kk = 0; kk < BK; ++kk) {
      float4 af0 = *(const float4*)&xsT[kk][ty * 8];
      float4 af1 = *(const float4*)&xsT[kk][ty * 8 + 4];
      float4 bf  = *(const float4*)&ws[kk][tx * 4];
      float a[8] = {af0.x, af0.y, af0.z, af0.w, af1.x, af1.y, af1.z, af1.w};
      #pragma unroll
      for (int rr = 0; rr < 8; ++rr) {
        acc[rr][0] += a[rr] * bf.x;
        acc[rr][1] += a[rr] * bf.y;
        acc[rr][2] += a[rr] * bf.z;
        acc[rr][3] += a[rr] * bf.w;
      }
    }
  }
  #pragma unroll
  for (int rr = 0; rr < 8; ++rr) {
    int row = row0 + ty * 8 + rr;
    if (row < NN) {
      ushort4 v;
      v.x = f2bf(acc[rr][0]); v.y = f2bf(acc[rr][1]);
      v.z = f2bf(acc[rr][2]); v.w = f2bf(acc[rr][3]);
      *(ushort4*)&h[(size_t)row * C_HID + tx * 4] = v;
    }
  }
}

// ---------------- W2 prep: pack W2[128][40] fp32 -> bf16 B-fragments, 48 cols ------------
// Layout: pbuf[(t*4+ks)*64 + lane] = uint4 of 8 bf16, elem j = B[k=ks*32+(lane>>4)*8+j][c=t*16+(lane&15)]
__global__ void w2prep_kernel(const float* __restrict__ W2, uint4* __restrict__ pbuf) {
  int tid = threadIdx.x;  // 768
  int lane = tid & 63, idx = tid >> 6;  // idx = t*4+ks
  int ks = idx & 3;
  int t  = idx >> 2;
  int c = t * 16 + (lane & 15);
  int kbase = ks * 32 + (lane >> 4) * 8;
  unsigned int u[4];
  #pragma unroll
  for (int jp = 0; jp < 4; ++jp) {
    float v0 = (c < C_OUT) ? W2[(size_t)(kbase + 2 * jp) * C_OUT + c] : 0.f;
    float v1 = (c < C_OUT) ? W2[(size_t)(kbase + 2 * jp + 1) * C_OUT + c] : 0.f;
    u[jp] = (unsigned int)f2bf(v0) | ((unsigned int)f2bf(v1) << 16);
  }
  pbuf[idx * 64 + lane] = make_uint4(u[0], u[1], u[2], u[3]);
}

// ---------------- GEMM 2 (MFMA): h2[50000,40](bf16) = ag1(bf16) @ W2 --------------------
__global__ __launch_bounds__(256) void gemm2_kernel(const unsigned short* __restrict__ ag1b,
    const uint4* __restrict__ pbuf, unsigned short* __restrict__ h2) {
  int l = threadIdx.x & 63, w = threadIdx.x >> 6;
  int row0 = blockIdx.x * 64 + w * 16;
  int arow = min(row0 + (l & 15), NN - 1);
  const uint4* ap = (const uint4*)(ag1b + (size_t)arow * C_HID + (l >> 4) * 8);
  bf16x8 a[4];
  #pragma unroll
  for (int ks = 0; ks < 4; ++ks) a[ks] = __builtin_bit_cast(bf16x8, ap[ks * 4]);
  f32x4 acc[3] = {};
  #pragma unroll
  for (int t = 0; t < 3; ++t) {
    #pragma unroll
    for (int ks = 0; ks < 4; ++ks) {
      bf16x8 b = __builtin_bit_cast(bf16x8, pbuf[(t * 4 + ks) * 64 + l]);
      acc[t] = __builtin_amdgcn_mfma_f32_16x16x32_bf16(a[ks], b, acc[t], 0, 0, 0);
    }
  }
  int rbase = row0 + (l >> 4) * 4;
  int c0 = l & 15;
  #pragma unroll
  for (int t = 0; t < 3; ++t) {
    int col = t * 16 + c0;
    if (col < C_OUT) {
      #pragma unroll
      for (int r = 0; r < 4; ++r) {
        int row = rbase + r;
        if (row < NN) h2[(size_t)row * C_OUT + col] = f2bf(acc[t][r]);
      }
    }
  }
}

// ---------------- Aggregation ----------------

// 1 wave per node; h1 bf16 in, ag1 bf16 out.
__global__ void agg1_kernel(const unsigned short* __restrict__ h, const int* __restrict__ off,
                            const int* __restrict__ esrc, const float* __restrict__ dinvs,
                            const float* __restrict__ dinv, const float* __restrict__ b,
                            unsigned int* __restrict__ outb) {
  int i = blockIdx.x;
  int l = threadIdx.x;  // 64
  float di = dinv[i];
  const unsigned int* hp = (const unsigned int*)h;
  unsigned int su = hp[(size_t)i * 64 + l];
  float ax = bf2f(su) * di * di, ay = bf2f(su >> 16) * di * di;
  int p0 = off[i], p1 = off[i + 1];
  int p = p0;
  for (; p + 3 < p1; p += 4) {
    int s0 = esrc[p], s1 = esrc[p + 1], s2 = esrc[p + 2], s3 = esrc[p + 3];
    float n0 = dinvs[p] * di, n1 = dinvs[p + 1] * di, n2 = dinvs[p + 2] * di,
          n3 = dinvs[p + 3] * di;
    unsigned int v0 = hp[(size_t)s0 * 64 + l];
    unsigned int v1 = hp[(size_t)s1 * 64 + l];
    unsigned int v2 = hp[(size_t)s2 * 64 + l];
    unsigned int v3 = hp[(size_t)s3 * 64 + l];
    ax += bf2f(v0) * n0; ay += bf2f(v0 >> 16) * n0;
    ax += bf2f(v1) * n1; ay += bf2f(v1 >> 16) * n1;
    ax += bf2f(v2) * n2; ay += bf2f(v2 >> 16) * n2;
    ax += bf2f(v3) * n3; ay += bf2f(v3 >> 16) * n3;
  }
  for (; p < p1; ++p) {
    int s = esrc[p];
    float nr = dinvs[p] * di;
    unsigned int v = hp[(size_t)s * 64 + l];
    ax += bf2f(v) * nr; ay += bf2f(v >> 16) * nr;
  }
  float2 bb = ((const float2*)b)[l];
  float rx = fmaxf(ax + bb.x, 0.f);
  float ry = fmaxf(ay + bb.y, 0.f);
  outb[(size_t)i * 64 + l] = (unsigned int)f2bf(rx) | ((unsigned int)f2bf(ry) << 16);
}

// layer-2 aggregation + bias + log_softmax; h2 bf16; wave per node.
__global__ void agg2_kernel(const unsigned short* __restrict__ h, const int* __restrict__ off,
                            const int* __restrict__ esrc, const float* __restrict__ dinvs,
                            const float* __restrict__ dinv, const float* __restrict__ b,
                            float* __restrict__ out, int n) {
  int wv = threadIdx.x >> 6, lane = threadIdx.x & 63;
  int i = blockIdx.x * 4 + wv;
  if (i >= n) return;
  bool act = lane < C_OUT;
  float di = dinv[i];
  float acc = act ? bf2f(h[(size_t)i * C_OUT + lane]) * di * di : 0.f;
  int p0 = off[i], p1 = off[i + 1];
  int p = p0;
  for (; p + 3 < p1; p += 4) {
    int s0 = esrc[p], s1 = esrc[p + 1], s2 = esrc[p + 2], s3 = esrc[p + 3];
    float n0 = dinvs[p] * di, n1 = dinvs[p + 1] * di, n2 = dinvs[p + 2] * di,
          n3 = dinvs[p + 3] * di;
    if (act) {
      acc += bf2f(h[(size_t)s0 * C_OUT + lane]) * n0;
      acc += bf2f(h[(size_t)s1 * C_OUT + lane]) * n1;
      acc += bf2f(h[(size_t)s2 * C_OUT + lane]) * n2;
      acc += bf2f(h[(size_t)s3 * C_OUT + lane]) * n3;
    }
  }
  for (; p < p1; ++p) {
    int s = esrc[p];
    float nr = dinvs[p] * di;
    if (act) acc += bf2f(h[(size_t)s * C_OUT + lane]) * nr;
  }
  float v = act ? acc + b[lane] : -INFINITY;
  float m = v;
  #pragma unroll
  for (int d = 32; d > 0; d >>= 1) m = fmaxf(m, __shfl_xor(m, d));
  float e = act ? expf(v - m) : 0.f;
  float ssum = e;
  #pragma unroll
  for (int d = 32; d > 0; d >>= 1) ssum += __shfl_xor(ssum, d);
  if (act) out[(size_t)i * C_OUT + lane] = v - m - logf(ssum);
}

// ---------------- launch ----------------

extern "C" void kernel_launch(void* const* d_in, const int* in_sizes, int n_in,
                              void* d_out, int out_size, void* d_ws, size_t ws_size,
                              hipStream_t stream) {
  const float* x  = (const float*)d_in[0];
  const int*   ei = (const int*)d_in[1];
  const float* W1 = (const float*)d_in[2];
  const float* b1 = (const float*)d_in[3];
  const float* W2 = (const float*)d_in[4];
  const float* b2 = (const float*)d_in[5];
  int E = in_sizes[1] / 2;
  const int* src = ei;
  const int* dst = ei + E;

  char* ws = (char*)d_ws;
  size_t o = 0;
  auto alloc = [&](size_t bytes) {
    char* p = ws + o;
    o += (bytes + 255) & ~(size_t)255;
    return p;
  };
  unsigned int* gedge = (unsigned int*)alloc((size_t)NBUCK * CAP * sizeof(unsigned int));
  int*   bcur  = (int*)alloc(NBUCK * sizeof(int));
  int*   goff  = (int*)alloc((NBUCK + 1) * sizeof(int));
  int*   off   = (int*)alloc((NN + 1) * sizeof(int));
  float* dinv  = (float*)alloc(NN * sizeof(float));
  int*   esrc  = (int*)alloc((size_t)E * sizeof(int));
  float* dinvs = (float*)alloc((size_t)E * sizeof(float));
  unsigned short* h1b = (unsigned short*)alloc((size_t)NN * C_HID * sizeof(unsigned short));
  unsigned int*   ag1b = (unsigned int*)alloc((size_t)NN * (C_HID / 2) * sizeof(unsigned int));
  unsigned short* h2b = (unsigned short*)alloc((size_t)NN * C_OUT * sizeof(unsigned short));
  uint4* pbuf  = (uint4*)alloc(12 * 64 * sizeof(uint4));

  hipMemsetAsync(bcur, 0, NBUCK * sizeof(int), stream);
  passA_kernel<<<(E + EPB - 1) / EPB, 256, 0, stream>>>(src, dst, E, gedge, bcur);
  bscan_kernel<<<1, 128, 0, stream>>>(bcur, goff, off, E);
  passB_kernel<<<NBUCK, 512, 0, stream>>>(gedge, bcur, goff, esrc, off, dinv);
  expand_kernel<<<(E + 255) / 256, 256, 0, stream>>>(esrc, dinv, dinvs, E);
  w2prep_kernel<<<1, 768, 0, stream>>>(W2, pbuf);

  gemm1_kernel<<<(NN + BM - 1) / BM, 256, 0, stream>>>(x, W1, h1b);
  agg1_kernel<<<NN, 64, 0, stream>>>(h1b, off, esrc, dinvs, dinv, b1, ag1b);
  gemm2_kernel<<<(NN + 63) / 64, 256, 0, stream>>>((const unsigned short*)ag1b, pbuf, h2b);
  agg2_kernel<<<(NN + 3) / 4, 256, 0, stream>>>(h2b, off, esrc, dinvs, dinv, b2,
                                                (float*)d_out, NN);
}

// Round 6
// 200.819 us; speedup vs baseline: 3.3490x; 1.1791x over previous
//
#include <hip/hip_runtime.h>
#include <cmath>

#define NN 50000
#define C_IN 256
#define C_HID 128
#define C_OUT 40

#define BSZ 512                          // nodes per bucket
#define NBUCK ((NN + BSZ - 1) / BSZ)     // 98
#define CAP 19456                        // max edges per bucket region
#define EPB 4096                         // edges per passA block

typedef __attribute__((ext_vector_type(8))) short bf16x8;
typedef __attribute__((ext_vector_type(4))) float f32x4;

__device__ __forceinline__ float bf2f(unsigned int u16) {
  unsigned int b = (u16 & 0xFFFFu) << 16;
  return __builtin_bit_cast(float, b);
}
__device__ __forceinline__ unsigned short f2bf(float f) {
  unsigned int b = __builtin_bit_cast(unsigned int, f);
  unsigned int r = (b + 0x7FFF + ((b >> 16) & 1)) >> 16;  // RNE
  return (unsigned short)r;
}

// ---------------- CSR build: pass A — LDS-binned partition into NBUCK regions ------------

__global__ __launch_bounds__(256) void passA_kernel(const int* __restrict__ src,
    const int* __restrict__ dst, int E, unsigned int* __restrict__ gedge,
    int* __restrict__ bcur) {
  __shared__ unsigned int pk[EPB];
  __shared__ unsigned char bof[EPB];
  __shared__ int bcnt[NBUCK], bstart[NBUCK], bpos[NBUCK], gbase[NBUCK];
  int tid = threadIdx.x;
  int e0 = blockIdx.x * EPB;
  int cnt = min(EPB, E - e0);
  for (int b = tid; b < NBUCK; b += 256) bcnt[b] = 0;
  int ds_[16], ss_[16];
  __syncthreads();
  #pragma unroll
  for (int k = 0; k < 16; ++k) {
    int i = tid + k * 256;
    if (i < cnt) {
      ds_[k] = dst[e0 + i];
      ss_[k] = src[e0 + i];
      atomicAdd(&bcnt[ds_[k] >> 9], 1);
    }
  }
  __syncthreads();
  if (tid == 0) {
    int acc = 0;
    for (int b = 0; b < NBUCK; ++b) { bstart[b] = acc; bpos[b] = acc; acc += bcnt[b]; }
  }
  __syncthreads();
  #pragma unroll
  for (int k = 0; k < 16; ++k) {
    int i = tid + k * 256;
    if (i < cnt) {
      int b = ds_[k] >> 9;
      int p = atomicAdd(&bpos[b], 1);
      pk[p] = ((unsigned int)ss_[k] << 9) | (unsigned int)(ds_[k] & 511);
      bof[p] = (unsigned char)b;
    }
  }
  __syncthreads();
  for (int b = tid; b < NBUCK; b += 256)
    gbase[b] = atomicAdd(&bcur[b], bcnt[b]);
  __syncthreads();
  for (int i = tid; i < cnt; i += 256) {
    int b = bof[i];
    int p = gbase[b] + (i - bstart[b]);
    gedge[(size_t)b * CAP + p] = pk[i];
  }
}

__global__ void bscan_kernel(const int* __restrict__ bcur, int* __restrict__ goff,
                             int* __restrict__ off, int E) {
  __shared__ int t[128];
  int tid = threadIdx.x;
  int v = (tid < NBUCK) ? bcur[tid] : 0;
  t[tid] = v;
  __syncthreads();
  for (int d = 1; d < 128; d <<= 1) {
    int x = (tid >= d) ? t[tid - d] : 0;
    __syncthreads();
    t[tid] += x;
    __syncthreads();
  }
  if (tid < NBUCK) goff[tid] = t[tid] - v;
  if (tid == 0) { goff[NBUCK] = E; off[NN] = E; }
}

__global__ __launch_bounds__(512) void passB_kernel(const unsigned int* __restrict__ gedge,
    const int* __restrict__ bcur, const int* __restrict__ goff,
    int* __restrict__ esrc, int* __restrict__ off, float* __restrict__ dinv) {
  __shared__ int dcnt[512];
  __shared__ int dsc[512];
  __shared__ int dcur[512];
  int b = blockIdx.x, tid = threadIdx.x;
  int nE = bcur[b];
  int base = goff[b];
  const unsigned int* reg = gedge + (size_t)b * CAP;
  dcnt[tid] = 0;
  __syncthreads();
  for (int i = tid; i < nE; i += 512)
    atomicAdd(&dcnt[reg[i] & 511], 1);
  __syncthreads();
  int own = dcnt[tid];
  dsc[tid] = own;
  __syncthreads();
  for (int d = 1; d < 512; d <<= 1) {
    int x = (tid >= d) ? dsc[tid - d] : 0;
    __syncthreads();
    dsc[tid] += x;
    __syncthreads();
  }
  int excl = dsc[tid] - own;
  dcur[tid] = excl;
  int node = b * BSZ + tid;
  if (node < NN) {
    off[node]  = base + excl;
    dinv[node] = rsqrtf((float)(own + 1));
  }
  __syncthreads();
  for (int i = tid; i < nE; i += 512) {
    unsigned int p = reg[i];
    int pos = atomicAdd(&dcur[p & 511], 1);
    esrc[base + pos] = (int)(p >> 9);
  }
}

__global__ void expand_kernel(const int* __restrict__ esrc, const float* __restrict__ dinv,
                              float* __restrict__ dinvs, int E) {
  int e = blockIdx.x * 256 + threadIdx.x;
  if (e < E) dinvs[e] = dinv[esrc[e]];
}

// ---------------- W1 prep: W1[256][128] fp32 -> bf16 B-frags (8 col-tiles x 8 k-steps) ---
// pbuf1[(t*8+ks)*64 + lane]: elem j = W1[k=ks*32+(lane>>4)*8+j][c=t*16+(lane&15)]
__global__ void w1prep_kernel(const float* __restrict__ W1, uint4* __restrict__ pbuf1) {
  int gid = blockIdx.x * 256 + threadIdx.x;  // 4096 total
  int l = gid & 63, idx = gid >> 6;          // idx = t*8+ks
  int ks = idx & 7, t = idx >> 3;
  int c = t * 16 + (l & 15);
  int kbase = ks * 32 + (l >> 4) * 8;
  unsigned int u[4];
  #pragma unroll
  for (int jp = 0; jp < 4; ++jp) {
    float v0 = W1[(size_t)(kbase + 2 * jp) * C_HID + c];
    float v1 = W1[(size_t)(kbase + 2 * jp + 1) * C_HID + c];
    u[jp] = (unsigned int)f2bf(v0) | ((unsigned int)f2bf(v1) << 16);
  }
  pbuf1[idx * 64 + l] = make_uint4(u[0], u[1], u[2], u[3]);
}

// ---------------- GEMM 1 (MFMA): h1[50000,128](bf16) = x(->bf16) @ W1 -------------------
// Wave computes 16 rows x 128 cols. A-frags direct from global fp32 x (convert in-reg),
// B-frags from pbuf1 (L2-hot). No LDS.
__global__ __launch_bounds__(256) void gemm1_kernel(const float* __restrict__ x,
    const uint4* __restrict__ pb, unsigned short* __restrict__ h) {
  int l = threadIdx.x & 63, w = threadIdx.x >> 6;
  int row0 = blockIdx.x * 64 + w * 16;
  int arow = min(row0 + (l & 15), NN - 1);
  const float* xp = x + (size_t)arow * C_IN + (l >> 4) * 8;
  bf16x8 a[8];
  #pragma unroll
  for (int ks = 0; ks < 8; ++ks) {
    float4 a0 = *(const float4*)(xp + ks * 32);
    float4 a1 = *(const float4*)(xp + ks * 32 + 4);
    union { bf16x8 v; unsigned short s[8]; } pa;
    pa.s[0] = f2bf(a0.x); pa.s[1] = f2bf(a0.y); pa.s[2] = f2bf(a0.z); pa.s[3] = f2bf(a0.w);
    pa.s[4] = f2bf(a1.x); pa.s[5] = f2bf(a1.y); pa.s[6] = f2bf(a1.z); pa.s[7] = f2bf(a1.w);
    a[ks] = pa.v;
  }
  f32x4 acc[8] = {};
  #pragma unroll
  for (int t = 0; t < 8; ++t) {
    #pragma unroll
    for (int ks = 0; ks < 8; ++ks) {
      bf16x8 b = __builtin_bit_cast(bf16x8, pb[(t * 8 + ks) * 64 + l]);
      acc[t] = __builtin_amdgcn_mfma_f32_16x16x32_bf16(a[ks], b, acc[t], 0, 0, 0);
    }
  }
  int c0 = l & 15, rb = (l >> 4) * 4;
  #pragma unroll
  for (int t = 0; t < 8; ++t) {
    #pragma unroll
    for (int r = 0; r < 4; ++r) {
      int row = row0 + rb + r;
      if (row < NN) h[(size_t)row * C_HID + t * 16 + c0] = f2bf(acc[t][r]);
    }
  }
}

// ---------------- W2 prep: pack W2[128][40] fp32 -> bf16 B-fragments, 48 cols ------------
__global__ void w2prep_kernel(const float* __restrict__ W2, uint4* __restrict__ pbuf) {
  int tid = threadIdx.x;  // 768
  int lane = tid & 63, idx = tid >> 6;  // idx = t*4+ks
  int ks = idx & 3;
  int t  = idx >> 2;
  int c = t * 16 + (lane & 15);
  int kbase = ks * 32 + (lane >> 4) * 8;
  unsigned int u[4];
  #pragma unroll
  for (int jp = 0; jp < 4; ++jp) {
    float v0 = (c < C_OUT) ? W2[(size_t)(kbase + 2 * jp) * C_OUT + c] : 0.f;
    float v1 = (c < C_OUT) ? W2[(size_t)(kbase + 2 * jp + 1) * C_OUT + c] : 0.f;
    u[jp] = (unsigned int)f2bf(v0) | ((unsigned int)f2bf(v1) << 16);
  }
  pbuf[idx * 64 + lane] = make_uint4(u[0], u[1], u[2], u[3]);
}

// ---------------- GEMM 2 (MFMA): h2[50000,40](bf16) = ag1(bf16) @ W2 --------------------
__global__ __launch_bounds__(256) void gemm2_kernel(const unsigned short* __restrict__ ag1b,
    const uint4* __restrict__ pbuf, unsigned short* __restrict__ h2) {
  int l = threadIdx.x & 63, w = threadIdx.x >> 6;
  int row0 = blockIdx.x * 64 + w * 16;
  int arow = min(row0 + (l & 15), NN - 1);
  const uint4* ap = (const uint4*)(ag1b + (size_t)arow * C_HID + (l >> 4) * 8);
  bf16x8 a[4];
  #pragma unroll
  for (int ks = 0; ks < 4; ++ks) a[ks] = __builtin_bit_cast(bf16x8, ap[ks * 4]);
  f32x4 acc[3] = {};
  #pragma unroll
  for (int t = 0; t < 3; ++t) {
    #pragma unroll
    for (int ks = 0; ks < 4; ++ks) {
      bf16x8 b = __builtin_bit_cast(bf16x8, pbuf[(t * 4 + ks) * 64 + l]);
      acc[t] = __builtin_amdgcn_mfma_f32_16x16x32_bf16(a[ks], b, acc[t], 0, 0, 0);
    }
  }
  int rbase = row0 + (l >> 4) * 4;
  int c0 = l & 15;
  #pragma unroll
  for (int t = 0; t < 3; ++t) {
    int col = t * 16 + c0;
    if (col < C_OUT) {
      #pragma unroll
      for (int r = 0; r < 4; ++r) {
        int row = rbase + r;
        if (row < NN) h2[(size_t)row * C_OUT + col] = f2bf(acc[t][r]);
      }
    }
  }
}

// ---------------- Aggregation ----------------

// 1 wave per node; h1 bf16 in, ag1 bf16 out.
__global__ void agg1_kernel(const unsigned short* __restrict__ h, const int* __restrict__ off,
                            const int* __restrict__ esrc, const float* __restrict__ dinvs,
                            const float* __restrict__ dinv, const float* __restrict__ b,
                            unsigned int* __restrict__ outb) {
  int i = blockIdx.x;
  int l = threadIdx.x;  // 64
  float di = dinv[i];
  const unsigned int* hp = (const unsigned int*)h;
  unsigned int su = hp[(size_t)i * 64 + l];
  float ax = bf2f(su) * di * di, ay = bf2f(su >> 16) * di * di;
  int p0 = off[i], p1 = off[i + 1];
  int p = p0;
  for (; p + 3 < p1; p += 4) {
    int s0 = esrc[p], s1 = esrc[p + 1], s2 = esrc[p + 2], s3 = esrc[p + 3];
    float n0 = dinvs[p] * di, n1 = dinvs[p + 1] * di, n2 = dinvs[p + 2] * di,
          n3 = dinvs[p + 3] * di;
    unsigned int v0 = hp[(size_t)s0 * 64 + l];
    unsigned int v1 = hp[(size_t)s1 * 64 + l];
    unsigned int v2 = hp[(size_t)s2 * 64 + l];
    unsigned int v3 = hp[(size_t)s3 * 64 + l];
    ax += bf2f(v0) * n0; ay += bf2f(v0 >> 16) * n0;
    ax += bf2f(v1) * n1; ay += bf2f(v1 >> 16) * n1;
    ax += bf2f(v2) * n2; ay += bf2f(v2 >> 16) * n2;
    ax += bf2f(v3) * n3; ay += bf2f(v3 >> 16) * n3;
  }
  for (; p < p1; ++p) {
    int s = esrc[p];
    float nr = dinvs[p] * di;
    unsigned int v = hp[(size_t)s * 64 + l];
    ax += bf2f(v) * nr; ay += bf2f(v >> 16) * nr;
  }
  float2 bb = ((const float2*)b)[l];
  float rx = fmaxf(ax + bb.x, 0.f);
  float ry = fmaxf(ay + bb.y, 0.f);
  outb[(size_t)i * 64 + l] = (unsigned int)f2bf(rx) | ((unsigned int)f2bf(ry) << 16);
}

// layer-2 aggregation + bias + log_softmax; h2 bf16; wave per node.
__global__ void agg2_kernel(const unsigned short* __restrict__ h, const int* __restrict__ off,
                            const int* __restrict__ esrc, const float* __restrict__ dinvs,
                            const float* __restrict__ dinv, const float* __restrict__ b,
                            float* __restrict__ out, int n) {
  int wv = threadIdx.x >> 6, lane = threadIdx.x & 63;
  int i = blockIdx.x * 4 + wv;
  if (i >= n) return;
  bool act = lane < C_OUT;
  float di = dinv[i];
  float acc = act ? bf2f(h[(size_t)i * C_OUT + lane]) * di * di : 0.f;
  int p0 = off[i], p1 = off[i + 1];
  int p = p0;
  for (; p + 3 < p1; p += 4) {
    int s0 = esrc[p], s1 = esrc[p + 1], s2 = esrc[p + 2], s3 = esrc[p + 3];
    float n0 = dinvs[p] * di, n1 = dinvs[p + 1] * di, n2 = dinvs[p + 2] * di,
          n3 = dinvs[p + 3] * di;
    if (act) {
      acc += bf2f(h[(size_t)s0 * C_OUT + lane]) * n0;
      acc += bf2f(h[(size_t)s1 * C_OUT + lane]) * n1;
      acc += bf2f(h[(size_t)s2 * C_OUT + lane]) * n2;
      acc += bf2f(h[(size_t)s3 * C_OUT + lane]) * n3;
    }
  }
  for (; p < p1; ++p) {
    int s = esrc[p];
    float nr = dinvs[p] * di;
    if (act) acc += bf2f(h[(size_t)s * C_OUT + lane]) * nr;
  }
  float v = act ? acc + b[lane] : -INFINITY;
  float m = v;
  #pragma unroll
  for (int d = 32; d > 0; d >>= 1) m = fmaxf(m, __shfl_xor(m, d));
  float e = act ? expf(v - m) : 0.f;
  float ssum = e;
  #pragma unroll
  for (int d = 32; d > 0; d >>= 1) ssum += __shfl_xor(ssum, d);
  if (act) out[(size_t)i * C_OUT + lane] = v - m - logf(ssum);
}

// ---------------- launch ----------------

extern "C" void kernel_launch(void* const* d_in, const int* in_sizes, int n_in,
                              void* d_out, int out_size, void* d_ws, size_t ws_size,
                              hipStream_t stream) {
  const float* x  = (const float*)d_in[0];
  const int*   ei = (const int*)d_in[1];
  const float* W1 = (const float*)d_in[2];
  const float* b1 = (const float*)d_in[3];
  const float* W2 = (const float*)d_in[4];
  const float* b2 = (const float*)d_in[5];
  int E = in_sizes[1] / 2;
  const int* src = ei;
  const int* dst = ei + E;

  char* ws = (char*)d_ws;
  size_t o = 0;
  auto alloc = [&](size_t bytes) {
    char* p = ws + o;
    o += (bytes + 255) & ~(size_t)255;
    return p;
  };
  unsigned int* gedge = (unsigned int*)alloc((size_t)NBUCK * CAP * sizeof(unsigned int));
  int*   bcur  = (int*)alloc(NBUCK * sizeof(int));
  int*   goff  = (int*)alloc((NBUCK + 1) * sizeof(int));
  int*   off   = (int*)alloc((NN + 1) * sizeof(int));
  float* dinv  = (float*)alloc(NN * sizeof(float));
  int*   esrc  = (int*)alloc((size_t)E * sizeof(int));
  float* dinvs = (float*)alloc((size_t)E * sizeof(float));
  unsigned short* h1b = (unsigned short*)alloc((size_t)NN * C_HID * sizeof(unsigned short));
  unsigned int*   ag1b = (unsigned int*)alloc((size_t)NN * (C_HID / 2) * sizeof(unsigned int));
  unsigned short* h2b = (unsigned short*)alloc((size_t)NN * C_OUT * sizeof(unsigned short));
  uint4* pbuf  = (uint4*)alloc(12 * 64 * sizeof(uint4));
  uint4* pbuf1 = (uint4*)alloc(64 * 64 * sizeof(uint4));

  hipMemsetAsync(bcur, 0, NBUCK * sizeof(int), stream);
  passA_kernel<<<(E + EPB - 1) / EPB, 256, 0, stream>>>(src, dst, E, gedge, bcur);
  bscan_kernel<<<1, 128, 0, stream>>>(bcur, goff, off, E);
  passB_kernel<<<NBUCK, 512, 0, stream>>>(gedge, bcur, goff, esrc, off, dinv);
  expand_kernel<<<(E + 255) / 256, 256, 0, stream>>>(esrc, dinv, dinvs, E);
  w1prep_kernel<<<16, 256, 0, stream>>>(W1, pbuf1);
  w2prep_kernel<<<1, 768, 0, stream>>>(W2, pbuf);

  gemm1_kernel<<<(NN + 63) / 64, 256, 0, stream>>>(x, pbuf1, h1b);
  agg1_kernel<<<NN, 64, 0, stream>>>(h1b, off, esrc, dinvs, dinv, b1, ag1b);
  gemm2_kernel<<<(NN + 63) / 64, 256, 0, stream>>>((const unsigned short*)ag1b, pbuf, h2b);
  agg2_kernel<<<(NN + 3) / 4, 256, 0, stream>>>(h2b, off, esrc, dinvs, dinv, b2,
                                                (float*)d_out, NN);
}

// Round 7
// 195.366 us; speedup vs baseline: 3.4424x; 1.0279x over previous
//
#include <hip/hip_runtime.h>
#include <cmath>

#define NN 50000
#define C_IN 256
#define C_HID 128
#define C_OUT 40

#define BSZ 512                          // nodes per bucket
#define NBUCK ((NN + BSZ - 1) / BSZ)     // 98
#define CAP 19456                        // max edges per bucket region
#define EPB 4096                         // edges per passA block

typedef __attribute__((ext_vector_type(8))) short bf16x8;
typedef __attribute__((ext_vector_type(4))) float f32x4;

__device__ __forceinline__ float bf2f(unsigned int u16) {
  unsigned int b = (u16 & 0xFFFFu) << 16;
  return __builtin_bit_cast(float, b);
}
__device__ __forceinline__ unsigned short f2bf(float f) {
  unsigned int b = __builtin_bit_cast(unsigned int, f);
  unsigned int r = (b + 0x7FFF + ((b >> 16) & 1)) >> 16;  // RNE
  return (unsigned short)r;
}

// ---------------- CSR build: pass A — LDS-binned partition into NBUCK regions ------------

__global__ __launch_bounds__(256) void passA_kernel(const int* __restrict__ src,
    const int* __restrict__ dst, int E, unsigned int* __restrict__ gedge,
    int* __restrict__ bcur) {
  __shared__ unsigned int pk[EPB];
  __shared__ unsigned char bof[EPB];
  __shared__ int bcnt[NBUCK], bstart[NBUCK], bpos[NBUCK], gbase[NBUCK];
  int tid = threadIdx.x;
  int e0 = blockIdx.x * EPB;
  int cnt = min(EPB, E - e0);
  for (int b = tid; b < NBUCK; b += 256) bcnt[b] = 0;
  int ds_[16], ss_[16];
  __syncthreads();
  #pragma unroll
  for (int k = 0; k < 16; ++k) {
    int i = tid + k * 256;
    if (i < cnt) {
      ds_[k] = dst[e0 + i];
      ss_[k] = src[e0 + i];
      atomicAdd(&bcnt[ds_[k] >> 9], 1);
    }
  }
  __syncthreads();
  if (tid == 0) {
    int acc = 0;
    for (int b = 0; b < NBUCK; ++b) { bstart[b] = acc; bpos[b] = acc; acc += bcnt[b]; }
  }
  __syncthreads();
  #pragma unroll
  for (int k = 0; k < 16; ++k) {
    int i = tid + k * 256;
    if (i < cnt) {
      int b = ds_[k] >> 9;
      int p = atomicAdd(&bpos[b], 1);
      pk[p] = ((unsigned int)ss_[k] << 9) | (unsigned int)(ds_[k] & 511);
      bof[p] = (unsigned char)b;
    }
  }
  __syncthreads();
  for (int b = tid; b < NBUCK; b += 256)
    gbase[b] = atomicAdd(&bcur[b], bcnt[b]);
  __syncthreads();
  for (int i = tid; i < cnt; i += 256) {
    int b = bof[i];
    int p = gbase[b] + (i - bstart[b]);
    gedge[(size_t)b * CAP + p] = pk[i];
  }
}

__global__ void bscan_kernel(const int* __restrict__ bcur, int* __restrict__ goff,
                             int* __restrict__ off, int E) {
  __shared__ int t[128];
  int tid = threadIdx.x;
  int v = (tid < NBUCK) ? bcur[tid] : 0;
  t[tid] = v;
  __syncthreads();
  for (int d = 1; d < 128; d <<= 1) {
    int x = (tid >= d) ? t[tid - d] : 0;
    __syncthreads();
    t[tid] += x;
    __syncthreads();
  }
  if (tid < NBUCK) goff[tid] = t[tid] - v;
  if (tid == 0) { goff[NBUCK] = E; off[NN] = E; }
}

__global__ __launch_bounds__(512) void passB_kernel(const unsigned int* __restrict__ gedge,
    const int* __restrict__ bcur, const int* __restrict__ goff,
    int* __restrict__ esrc, int* __restrict__ off, float* __restrict__ dinv) {
  __shared__ int dcnt[512];
  __shared__ int dsc[512];
  __shared__ int dcur[512];
  int b = blockIdx.x, tid = threadIdx.x;
  int nE = bcur[b];
  int base = goff[b];
  const unsigned int* reg = gedge + (size_t)b * CAP;
  dcnt[tid] = 0;
  __syncthreads();
  for (int i = tid; i < nE; i += 512)
    atomicAdd(&dcnt[reg[i] & 511], 1);
  __syncthreads();
  int own = dcnt[tid];
  dsc[tid] = own;
  __syncthreads();
  for (int d = 1; d < 512; d <<= 1) {
    int x = (tid >= d) ? dsc[tid - d] : 0;
    __syncthreads();
    dsc[tid] += x;
    __syncthreads();
  }
  int excl = dsc[tid] - own;
  dcur[tid] = excl;
  int node = b * BSZ + tid;
  if (node < NN) {
    off[node]  = base + excl;
    dinv[node] = rsqrtf((float)(own + 1));
  }
  __syncthreads();
  for (int i = tid; i < nE; i += 512) {
    unsigned int p = reg[i];
    int pos = atomicAdd(&dcur[p & 511], 1);
    esrc[base + pos] = (int)(p >> 9);
  }
}

__global__ void expand_kernel(const int* __restrict__ esrc, const float* __restrict__ dinv,
                              float* __restrict__ dinvs, int E) {
  int e = blockIdx.x * 256 + threadIdx.x;
  if (e < E) dinvs[e] = dinv[esrc[e]];
}

// ---------------- W1 prep: W1[256][128] fp32 -> bf16 B-frags (8 col-tiles x 8 k-steps) ---

__global__ void w1prep_kernel(const float* __restrict__ W1, uint4* __restrict__ pbuf1) {
  int gid = blockIdx.x * 256 + threadIdx.x;  // 4096 total
  int l = gid & 63, idx = gid >> 6;          // idx = t*8+ks
  int ks = idx & 7, t = idx >> 3;
  int c = t * 16 + (l & 15);
  int kbase = ks * 32 + (l >> 4) * 8;
  unsigned int u[4];
  #pragma unroll
  for (int jp = 0; jp < 4; ++jp) {
    float v0 = W1[(size_t)(kbase + 2 * jp) * C_HID + c];
    float v1 = W1[(size_t)(kbase + 2 * jp + 1) * C_HID + c];
    u[jp] = (unsigned int)f2bf(v0) | ((unsigned int)f2bf(v1) << 16);
  }
  pbuf1[idx * 64 + l] = make_uint4(u[0], u[1], u[2], u[3]);
}

// ---------------- GEMM 1 (MFMA): h1[50000,128](bf16) = x(->bf16) @ W1 -------------------

__global__ __launch_bounds__(256) void gemm1_kernel(const float* __restrict__ x,
    const uint4* __restrict__ pb, unsigned short* __restrict__ h) {
  int l = threadIdx.x & 63, w = threadIdx.x >> 6;
  int row0 = blockIdx.x * 64 + w * 16;
  int arow = min(row0 + (l & 15), NN - 1);
  const float* xp = x + (size_t)arow * C_IN + (l >> 4) * 8;
  bf16x8 a[8];
  #pragma unroll
  for (int ks = 0; ks < 8; ++ks) {
    float4 a0 = *(const float4*)(xp + ks * 32);
    float4 a1 = *(const float4*)(xp + ks * 32 + 4);
    union { bf16x8 v; unsigned short s[8]; } pa;
    pa.s[0] = f2bf(a0.x); pa.s[1] = f2bf(a0.y); pa.s[2] = f2bf(a0.z); pa.s[3] = f2bf(a0.w);
    pa.s[4] = f2bf(a1.x); pa.s[5] = f2bf(a1.y); pa.s[6] = f2bf(a1.z); pa.s[7] = f2bf(a1.w);
    a[ks] = pa.v;
  }
  f32x4 acc[8] = {};
  #pragma unroll
  for (int t = 0; t < 8; ++t) {
    #pragma unroll
    for (int ks = 0; ks < 8; ++ks) {
      bf16x8 b = __builtin_bit_cast(bf16x8, pb[(t * 8 + ks) * 64 + l]);
      acc[t] = __builtin_amdgcn_mfma_f32_16x16x32_bf16(a[ks], b, acc[t], 0, 0, 0);
    }
  }
  int c0 = l & 15, rb = (l >> 4) * 4;
  #pragma unroll
  for (int t = 0; t < 8; ++t) {
    #pragma unroll
    for (int r = 0; r < 4; ++r) {
      int row = row0 + rb + r;
      if (row < NN) h[(size_t)row * C_HID + t * 16 + c0] = f2bf(acc[t][r]);
    }
  }
}

// ---------------- W2 prep: pack W2[128][40] fp32 -> bf16 B-fragments, 48 cols ------------

__global__ void w2prep_kernel(const float* __restrict__ W2, uint4* __restrict__ pbuf) {
  int tid = threadIdx.x;  // 768
  int lane = tid & 63, idx = tid >> 6;  // idx = t*4+ks
  int ks = idx & 3;
  int t  = idx >> 2;
  int c = t * 16 + (lane & 15);
  int kbase = ks * 32 + (lane >> 4) * 8;
  unsigned int u[4];
  #pragma unroll
  for (int jp = 0; jp < 4; ++jp) {
    float v0 = (c < C_OUT) ? W2[(size_t)(kbase + 2 * jp) * C_OUT + c] : 0.f;
    float v1 = (c < C_OUT) ? W2[(size_t)(kbase + 2 * jp + 1) * C_OUT + c] : 0.f;
    u[jp] = (unsigned int)f2bf(v0) | ((unsigned int)f2bf(v1) << 16);
  }
  pbuf[idx * 64 + lane] = make_uint4(u[0], u[1], u[2], u[3]);
}

// ---------------- GEMM 2 (MFMA): h2[50000,40](bf16) = ag1(bf16) @ W2 --------------------

__global__ __launch_bounds__(256) void gemm2_kernel(const unsigned short* __restrict__ ag1b,
    const uint4* __restrict__ pbuf, unsigned short* __restrict__ h2) {
  int l = threadIdx.x & 63, w = threadIdx.x >> 6;
  int row0 = blockIdx.x * 64 + w * 16;
  int arow = min(row0 + (l & 15), NN - 1);
  const uint4* ap = (const uint4*)(ag1b + (size_t)arow * C_HID + (l >> 4) * 8);
  bf16x8 a[4];
  #pragma unroll
  for (int ks = 0; ks < 4; ++ks) a[ks] = __builtin_bit_cast(bf16x8, ap[ks * 4]);
  f32x4 acc[3] = {};
  #pragma unroll
  for (int t = 0; t < 3; ++t) {
    #pragma unroll
    for (int ks = 0; ks < 4; ++ks) {
      bf16x8 b = __builtin_bit_cast(bf16x8, pbuf[(t * 4 + ks) * 64 + l]);
      acc[t] = __builtin_amdgcn_mfma_f32_16x16x32_bf16(a[ks], b, acc[t], 0, 0, 0);
    }
  }
  int rbase = row0 + (l >> 4) * 4;
  int c0 = l & 15;
  #pragma unroll
  for (int t = 0; t < 3; ++t) {
    int col = t * 16 + c0;
    if (col < C_OUT) {
      #pragma unroll
      for (int r = 0; r < 4; ++r) {
        int row = rbase + r;
        if (row < NN) h2[(size_t)row * C_OUT + col] = f2bf(acc[t][r]);
      }
    }
  }
}

// ---------------- Aggregation ----------------

// Layer-1 agg: wave per node, 2 edges per gather instruction (uint2 = 4 ch per lane).
// lane l: group g=l>>5 (edge within pair), q=l&31 (channel quad).
__global__ void agg1_kernel(const unsigned short* __restrict__ h, const int* __restrict__ off,
                            const int* __restrict__ esrc, const float* __restrict__ dinvs,
                            const float* __restrict__ dinv, const float* __restrict__ b,
                            uint2* __restrict__ outb, int n) {
  int wv = threadIdx.x >> 6, l = threadIdx.x & 63;
  int i = blockIdx.x * 4 + wv;
  if (i >= n) return;
  int g = l >> 5, q = l & 31;
  float di = dinv[i];
  const uint2* hp = (const uint2*)h;  // row = 32 uint2 (128 ch)
  float a0 = 0.f, a1 = 0.f, a2 = 0.f, a3 = 0.f;
  int p0 = off[i], p1 = off[i + 1];
  int pb = p0;
  for (; pb + 3 < p1; pb += 4) {  // 4 edges = 2 gather instructions
    int pA = pb + g, pB = pb + 2 + g;
    int sA = esrc[pA], sB = esrc[pB];
    float nA = dinvs[pA] * di, nB = dinvs[pB] * di;
    uint2 vA = hp[(size_t)sA * 32 + q];
    uint2 vB = hp[(size_t)sB * 32 + q];
    a0 += bf2f(vA.x) * nA; a1 += bf2f(vA.x >> 16) * nA;
    a2 += bf2f(vA.y) * nA; a3 += bf2f(vA.y >> 16) * nA;
    a0 += bf2f(vB.x) * nB; a1 += bf2f(vB.x >> 16) * nB;
    a2 += bf2f(vB.y) * nB; a3 += bf2f(vB.y >> 16) * nB;
  }
  for (; pb < p1; pb += 2) {
    int p = pb + g;
    if (p < p1) {
      int s = esrc[p];
      float nr = dinvs[p] * di;
      uint2 v = hp[(size_t)s * 32 + q];
      a0 += bf2f(v.x) * nr; a1 += bf2f(v.x >> 16) * nr;
      a2 += bf2f(v.y) * nr; a3 += bf2f(v.y >> 16) * nr;
    }
  }
  a0 += __shfl_xor(a0, 32); a1 += __shfl_xor(a1, 32);
  a2 += __shfl_xor(a2, 32); a3 += __shfl_xor(a3, 32);
  if (g == 0) {
    uint2 sv = hp[(size_t)i * 32 + q];
    float dd = di * di;
    a0 += bf2f(sv.x) * dd; a1 += bf2f(sv.x >> 16) * dd;
    a2 += bf2f(sv.y) * dd; a3 += bf2f(sv.y >> 16) * dd;
    float4 bb = ((const float4*)b)[q];
    a0 = fmaxf(a0 + bb.x, 0.f); a1 = fmaxf(a1 + bb.y, 0.f);
    a2 = fmaxf(a2 + bb.z, 0.f); a3 = fmaxf(a3 + bb.w, 0.f);
    uint2 o;
    o.x = (unsigned int)f2bf(a0) | ((unsigned int)f2bf(a1) << 16);
    o.y = (unsigned int)f2bf(a2) | ((unsigned int)f2bf(a3) << 16);
    outb[(size_t)i * 32 + q] = o;
  }
}

// Layer-2 agg + bias + log_softmax: wave per node, 6 edges per gather instruction.
// lane l: group g=l/10 (edge), q=l%10 (uint2 = 4 channels). lanes 60-63 idle in loop.
__global__ void agg2_kernel(const unsigned short* __restrict__ h, const int* __restrict__ off,
                            const int* __restrict__ esrc, const float* __restrict__ dinvs,
                            const float* __restrict__ dinv, const float* __restrict__ b,
                            float* __restrict__ out, int n) {
  int wv = threadIdx.x >> 6, l = threadIdx.x & 63;
  int i = blockIdx.x * 4 + wv;
  if (i >= n) return;
  int g = l / 10, q = l - g * 10;
  bool lact = l < 60;
  float di = dinv[i];
  const uint2* hp = (const uint2*)h;  // row = 10 uint2 (40 ch)
  float a0 = 0.f, a1 = 0.f, a2 = 0.f, a3 = 0.f;
  int p0 = off[i], p1 = off[i + 1];
  int pb = p0;
  for (; pb + 5 < p1; pb += 6) {
    if (lact) {
      int p = pb + g;
      int s = esrc[p];
      float nr = dinvs[p] * di;
      uint2 v = hp[(size_t)s * 10 + q];
      a0 += bf2f(v.x) * nr; a1 += bf2f(v.x >> 16) * nr;
      a2 += bf2f(v.y) * nr; a3 += bf2f(v.y >> 16) * nr;
    }
  }
  if (pb < p1) {
    int p = pb + g;
    if (lact && p < p1) {
      int s = esrc[p];
      float nr = dinvs[p] * di;
      uint2 v = hp[(size_t)s * 10 + q];
      a0 += bf2f(v.x) * nr; a1 += bf2f(v.x >> 16) * nr;
      a2 += bf2f(v.y) * nr; a3 += bf2f(v.y >> 16) * nr;
    }
  }
  // reduce the 6 groups onto lanes 0..9
  float t0 = 0.f, t1 = 0.f, t2 = 0.f, t3 = 0.f;
  #pragma unroll
  for (int gg = 0; gg < 6; ++gg) {
    int sl = gg * 10 + q;
    t0 += __shfl(a0, sl); t1 += __shfl(a1, sl);
    t2 += __shfl(a2, sl); t3 += __shfl(a3, sl);
  }
  bool act = l < 10;
  float v0, v1, v2, v3;
  if (act) {
    uint2 sv = hp[(size_t)i * 10 + l];
    float dd = di * di;
    float4 bb = ((const float4*)b)[l];
    v0 = t0 + bf2f(sv.x) * dd + bb.x;
    v1 = t1 + bf2f(sv.x >> 16) * dd + bb.y;
    v2 = t2 + bf2f(sv.y) * dd + bb.z;
    v3 = t3 + bf2f(sv.y >> 16) * dd + bb.w;
  } else {
    v0 = v1 = v2 = v3 = -INFINITY;
  }
  float mm = fmaxf(fmaxf(v0, v1), fmaxf(v2, v3));
  #pragma unroll
  for (int d = 32; d > 0; d >>= 1) mm = fmaxf(mm, __shfl_xor(mm, d));
  float e = act ? (expf(v0 - mm) + expf(v1 - mm) + expf(v2 - mm) + expf(v3 - mm)) : 0.f;
  float ss = e;
  #pragma unroll
  for (int d = 32; d > 0; d >>= 1) ss += __shfl_xor(ss, d);
  if (act) {
    float lg = logf(ss);
    float4 o = {v0 - mm - lg, v1 - mm - lg, v2 - mm - lg, v3 - mm - lg};
    *(float4*)&out[(size_t)i * C_OUT + l * 4] = o;
  }
}

// ---------------- launch ----------------

extern "C" void kernel_launch(void* const* d_in, const int* in_sizes, int n_in,
                              void* d_out, int out_size, void* d_ws, size_t ws_size,
                              hipStream_t stream) {
  const float* x  = (const float*)d_in[0];
  const int*   ei = (const int*)d_in[1];
  const float* W1 = (const float*)d_in[2];
  const float* b1 = (const float*)d_in[3];
  const float* W2 = (const float*)d_in[4];
  const float* b2 = (const float*)d_in[5];
  int E = in_sizes[1] / 2;
  const int* src = ei;
  const int* dst = ei + E;

  char* ws = (char*)d_ws;
  size_t o = 0;
  auto alloc = [&](size_t bytes) {
    char* p = ws + o;
    o += (bytes + 255) & ~(size_t)255;
    return p;
  };
  unsigned int* gedge = (unsigned int*)alloc((size_t)NBUCK * CAP * sizeof(unsigned int));
  int*   bcur  = (int*)alloc(NBUCK * sizeof(int));
  int*   goff  = (int*)alloc((NBUCK + 1) * sizeof(int));
  int*   off   = (int*)alloc((NN + 1) * sizeof(int));
  float* dinv  = (float*)alloc(NN * sizeof(float));
  int*   esrc  = (int*)alloc((size_t)E * sizeof(int));
  float* dinvs = (float*)alloc((size_t)E * sizeof(float));
  unsigned short* h1b = (unsigned short*)alloc((size_t)NN * C_HID * sizeof(unsigned short));
  unsigned int*   ag1b = (unsigned int*)alloc((size_t)NN * (C_HID / 2) * sizeof(unsigned int));
  unsigned short* h2b = (unsigned short*)alloc((size_t)NN * C_OUT * sizeof(unsigned short));
  uint4* pbuf  = (uint4*)alloc(12 * 64 * sizeof(uint4));
  uint4* pbuf1 = (uint4*)alloc(64 * 64 * sizeof(uint4));

  hipMemsetAsync(bcur, 0, NBUCK * sizeof(int), stream);
  passA_kernel<<<(E + EPB - 1) / EPB, 256, 0, stream>>>(src, dst, E, gedge, bcur);
  bscan_kernel<<<1, 128, 0, stream>>>(bcur, goff, off, E);
  passB_kernel<<<NBUCK, 512, 0, stream>>>(gedge, bcur, goff, esrc, off, dinv);
  expand_kernel<<<(E + 255) / 256, 256, 0, stream>>>(esrc, dinv, dinvs, E);
  w1prep_kernel<<<16, 256, 0, stream>>>(W1, pbuf1);
  w2prep_kernel<<<1, 768, 0, stream>>>(W2, pbuf);

  gemm1_kernel<<<(NN + 63) / 64, 256, 0, stream>>>(x, pbuf1, h1b);
  agg1_kernel<<<(NN + 3) / 4, 256, 0, stream>>>(h1b, off, esrc, dinvs, dinv, b1,
                                                (uint2*)ag1b, NN);
  gemm2_kernel<<<(NN + 63) / 64, 256, 0, stream>>>((const unsigned short*)ag1b, pbuf, h2b);
  agg2_kernel<<<(NN + 3) / 4, 256, 0, stream>>>(h2b, off, esrc, dinvs, dinv, b2,
                                                (float*)d_out, NN);
}

// Round 8
// 183.999 us; speedup vs baseline: 3.6551x; 1.0618x over previous
//
#include <hip/hip_runtime.h>
#include <cmath>

#define NN 50000
#define C_IN 256
#define C_HID 128
#define C_OUT 40

#define BSZ 512                          // nodes per bucket
#define NBUCK ((NN + BSZ - 1) / BSZ)     // 98
#define CAP 19456                        // max edges per bucket region
#define EPB 4096                         // edges per passA block

typedef __attribute__((ext_vector_type(8))) short bf16x8;
typedef __attribute__((ext_vector_type(4))) float f32x4;

__device__ __forceinline__ float bf2f(unsigned int u16) {
  unsigned int b = (u16 & 0xFFFFu) << 16;
  return __builtin_bit_cast(float, b);
}
__device__ __forceinline__ unsigned short f2bf(float f) {
  unsigned int b = __builtin_bit_cast(unsigned int, f);
  unsigned int r = (b + 0x7FFF + ((b >> 16) & 1)) >> 16;  // RNE
  return (unsigned short)r;
}

// ---------------- CSR build: pass A — LDS-binned partition into NBUCK regions ------------

__global__ __launch_bounds__(256) void passA_kernel(const int* __restrict__ src,
    const int* __restrict__ dst, int E, unsigned int* __restrict__ gedge,
    int* __restrict__ bcur) {
  __shared__ unsigned int pk[EPB];
  __shared__ unsigned char bof[EPB];
  __shared__ int bcnt[NBUCK], bstart[NBUCK], bpos[NBUCK], gbase[NBUCK];
  int tid = threadIdx.x;
  int e0 = blockIdx.x * EPB;
  int cnt = min(EPB, E - e0);
  for (int b = tid; b < NBUCK; b += 256) bcnt[b] = 0;
  int ds_[16], ss_[16];
  __syncthreads();
  #pragma unroll
  for (int k = 0; k < 16; ++k) {
    int i = tid + k * 256;
    if (i < cnt) {
      ds_[k] = dst[e0 + i];
      ss_[k] = src[e0 + i];
      atomicAdd(&bcnt[ds_[k] >> 9], 1);
    }
  }
  __syncthreads();
  if (tid == 0) {
    int acc = 0;
    for (int b = 0; b < NBUCK; ++b) { bstart[b] = acc; bpos[b] = acc; acc += bcnt[b]; }
  }
  __syncthreads();
  #pragma unroll
  for (int k = 0; k < 16; ++k) {
    int i = tid + k * 256;
    if (i < cnt) {
      int b = ds_[k] >> 9;
      int p = atomicAdd(&bpos[b], 1);
      pk[p] = ((unsigned int)ss_[k] << 9) | (unsigned int)(ds_[k] & 511);
      bof[p] = (unsigned char)b;
    }
  }
  __syncthreads();
  for (int b = tid; b < NBUCK; b += 256)
    gbase[b] = atomicAdd(&bcur[b], bcnt[b]);
  __syncthreads();
  for (int i = tid; i < cnt; i += 256) {
    int b = bof[i];
    int p = gbase[b] + (i - bstart[b]);
    gedge[(size_t)b * CAP + p] = pk[i];
  }
}

__global__ void bscan_kernel(const int* __restrict__ bcur, int* __restrict__ goff,
                             int* __restrict__ off, int E) {
  __shared__ int t[128];
  int tid = threadIdx.x;
  int v = (tid < NBUCK) ? bcur[tid] : 0;
  t[tid] = v;
  __syncthreads();
  for (int d = 1; d < 128; d <<= 1) {
    int x = (tid >= d) ? t[tid - d] : 0;
    __syncthreads();
    t[tid] += x;
    __syncthreads();
  }
  if (tid < NBUCK) goff[tid] = t[tid] - v;
  if (tid == 0) { goff[NBUCK] = E; off[NN] = E; }
}

__global__ __launch_bounds__(512) void passB_kernel(const unsigned int* __restrict__ gedge,
    const int* __restrict__ bcur, const int* __restrict__ goff,
    int* __restrict__ esrc, int* __restrict__ off, float* __restrict__ dinv) {
  __shared__ int dcnt[512];
  __shared__ int dsc[512];
  __shared__ int dcur[512];
  int b = blockIdx.x, tid = threadIdx.x;
  int nE = bcur[b];
  int base = goff[b];
  const unsigned int* reg = gedge + (size_t)b * CAP;
  dcnt[tid] = 0;
  __syncthreads();
  for (int i = tid; i < nE; i += 512)
    atomicAdd(&dcnt[reg[i] & 511], 1);
  __syncthreads();
  int own = dcnt[tid];
  dsc[tid] = own;
  __syncthreads();
  for (int d = 1; d < 512; d <<= 1) {
    int x = (tid >= d) ? dsc[tid - d] : 0;
    __syncthreads();
    dsc[tid] += x;
    __syncthreads();
  }
  int excl = dsc[tid] - own;
  dcur[tid] = excl;
  int node = b * BSZ + tid;
  if (node < NN) {
    off[node]  = base + excl;
    dinv[node] = rsqrtf((float)(own + 1));
  }
  __syncthreads();
  for (int i = tid; i < nE; i += 512) {
    unsigned int p = reg[i];
    int pos = atomicAdd(&dcur[p & 511], 1);
    esrc[base + pos] = (int)(p >> 9);
  }
}

// ---------------- W prep (merged): W1 -> 64 frag-sets, W2 -> 12 frag-sets ---------------
// pbuf1[(t*8+ks)*64 + l]: elem j = W1[k=ks*32+(l>>4)*8+j][c=t*16+(l&15)]
// pbuf2[(t*4+ks)*64 + l]: elem j = W2[k=ks*32+(l>>4)*8+j][c=t*16+(l&15)], 0-pad c>=40
__global__ void wprep_kernel(const float* __restrict__ W1, const float* __restrict__ W2,
                             uint4* __restrict__ pbuf1, uint4* __restrict__ pbuf2) {
  int blk = blockIdx.x;
  int tid = threadIdx.x;
  if (blk < 16) {  // W1: 4096 lanes total
    int gid = blk * 256 + tid;
    int l = gid & 63, idx = gid >> 6;  // idx = t*8+ks
    int ks = idx & 7, t = idx >> 3;
    int c = t * 16 + (l & 15);
    int kbase = ks * 32 + (l >> 4) * 8;
    unsigned int u[4];
    #pragma unroll
    for (int jp = 0; jp < 4; ++jp) {
      float v0 = W1[(size_t)(kbase + 2 * jp) * C_HID + c];
      float v1 = W1[(size_t)(kbase + 2 * jp + 1) * C_HID + c];
      u[jp] = (unsigned int)f2bf(v0) | ((unsigned int)f2bf(v1) << 16);
    }
    pbuf1[idx * 64 + l] = make_uint4(u[0], u[1], u[2], u[3]);
  } else {  // W2: 768 lanes total over 3 blocks (16,17,18)
    int gid = (blk - 16) * 256 + tid;
    int l = gid & 63, idx = gid >> 6;  // idx = t*4+ks
    int ks = idx & 3, t = idx >> 2;
    int c = t * 16 + (l & 15);
    int kbase = ks * 32 + (l >> 4) * 8;
    unsigned int u[4];
    #pragma unroll
    for (int jp = 0; jp < 4; ++jp) {
      float v0 = (c < C_OUT) ? W2[(size_t)(kbase + 2 * jp) * C_OUT + c] : 0.f;
      float v1 = (c < C_OUT) ? W2[(size_t)(kbase + 2 * jp + 1) * C_OUT + c] : 0.f;
      u[jp] = (unsigned int)f2bf(v0) | ((unsigned int)f2bf(v1) << 16);
    }
    pbuf2[idx * 64 + l] = make_uint4(u[0], u[1], u[2], u[3]);
  }
}

// ---------------- GEMM 1 (MFMA): h1[50000,128](bf16) = x(->bf16) @ W1 -------------------

__global__ __launch_bounds__(256) void gemm1_kernel(const float* __restrict__ x,
    const uint4* __restrict__ pb, unsigned short* __restrict__ h) {
  int l = threadIdx.x & 63, w = threadIdx.x >> 6;
  int row0 = blockIdx.x * 64 + w * 16;
  int arow = min(row0 + (l & 15), NN - 1);
  const float* xp = x + (size_t)arow * C_IN + (l >> 4) * 8;
  bf16x8 a[8];
  #pragma unroll
  for (int ks = 0; ks < 8; ++ks) {
    float4 a0 = *(const float4*)(xp + ks * 32);
    float4 a1 = *(const float4*)(xp + ks * 32 + 4);
    union { bf16x8 v; unsigned short s[8]; } pa;
    pa.s[0] = f2bf(a0.x); pa.s[1] = f2bf(a0.y); pa.s[2] = f2bf(a0.z); pa.s[3] = f2bf(a0.w);
    pa.s[4] = f2bf(a1.x); pa.s[5] = f2bf(a1.y); pa.s[6] = f2bf(a1.z); pa.s[7] = f2bf(a1.w);
    a[ks] = pa.v;
  }
  f32x4 acc[8] = {};
  #pragma unroll
  for (int t = 0; t < 8; ++t) {
    #pragma unroll
    for (int ks = 0; ks < 8; ++ks) {
      bf16x8 b = __builtin_bit_cast(bf16x8, pb[(t * 8 + ks) * 64 + l]);
      acc[t] = __builtin_amdgcn_mfma_f32_16x16x32_bf16(a[ks], b, acc[t], 0, 0, 0);
    }
  }
  int c0 = l & 15, rb = (l >> 4) * 4;
  #pragma unroll
  for (int t = 0; t < 8; ++t) {
    #pragma unroll
    for (int r = 0; r < 4; ++r) {
      int row = row0 + rb + r;
      if (row < NN) h[(size_t)row * C_HID + t * 16 + c0] = f2bf(acc[t][r]);
    }
  }
}

// ---------------- GEMM 2 (MFMA): h2[50000,40](bf16) = ag1(bf16) @ W2 --------------------

__global__ __launch_bounds__(256) void gemm2_kernel(const unsigned short* __restrict__ ag1b,
    const uint4* __restrict__ pbuf, unsigned short* __restrict__ h2) {
  int l = threadIdx.x & 63, w = threadIdx.x >> 6;
  int row0 = blockIdx.x * 64 + w * 16;
  int arow = min(row0 + (l & 15), NN - 1);
  const uint4* ap = (const uint4*)(ag1b + (size_t)arow * C_HID + (l >> 4) * 8);
  bf16x8 a[4];
  #pragma unroll
  for (int ks = 0; ks < 4; ++ks) a[ks] = __builtin_bit_cast(bf16x8, ap[ks * 4]);
  f32x4 acc[3] = {};
  #pragma unroll
  for (int t = 0; t < 3; ++t) {
    #pragma unroll
    for (int ks = 0; ks < 4; ++ks) {
      bf16x8 b = __builtin_bit_cast(bf16x8, pbuf[(t * 4 + ks) * 64 + l]);
      acc[t] = __builtin_amdgcn_mfma_f32_16x16x32_bf16(a[ks], b, acc[t], 0, 0, 0);
    }
  }
  int rbase = row0 + (l >> 4) * 4;
  int c0 = l & 15;
  #pragma unroll
  for (int t = 0; t < 3; ++t) {
    int col = t * 16 + c0;
    if (col < C_OUT) {
      #pragma unroll
      for (int r = 0; r < 4; ++r) {
        int row = rbase + r;
        if (row < NN) h2[(size_t)row * C_OUT + col] = f2bf(acc[t][r]);
      }
    }
  }
}

// ---------------- Aggregation ----------------

// Layer-1 agg: wave per node, 16 lanes/edge (uint4 = 8 ch), 4 edges per gather instr,
// x2 unrolled -> 8 edges / 2 independent gathers in flight per iter.
__global__ void agg1_kernel(const unsigned short* __restrict__ h, const int* __restrict__ off,
                            const int* __restrict__ esrc, const float* __restrict__ dinv,
                            const float* __restrict__ b, uint4* __restrict__ outb, int n) {
  int wv = threadIdx.x >> 6, l = threadIdx.x & 63;
  int i = blockIdx.x * 4 + wv;
  if (i >= n) return;
  int g = l >> 4, q = l & 15;
  float di = dinv[i];
  const uint4* hp = (const uint4*)h;  // row = 16 uint4 (128 ch)
  float a0 = 0.f, a1 = 0.f, a2 = 0.f, a3 = 0.f, a4 = 0.f, a5 = 0.f, a6 = 0.f, a7 = 0.f;
  int p0 = off[i], p1 = off[i + 1];
  int pb = p0;
  for (; pb + 7 < p1; pb += 8) {
    int pA = pb + g, pB = pb + 4 + g;
    int sA = esrc[pA], sB = esrc[pB];
    float nA = dinv[sA] * di, nB = dinv[sB] * di;
    uint4 vA = hp[(size_t)sA * 16 + q];
    uint4 vB = hp[(size_t)sB * 16 + q];
    a0 += bf2f(vA.x) * nA; a1 += bf2f(vA.x >> 16) * nA;
    a2 += bf2f(vA.y) * nA; a3 += bf2f(vA.y >> 16) * nA;
    a4 += bf2f(vA.z) * nA; a5 += bf2f(vA.z >> 16) * nA;
    a6 += bf2f(vA.w) * nA; a7 += bf2f(vA.w >> 16) * nA;
    a0 += bf2f(vB.x) * nB; a1 += bf2f(vB.x >> 16) * nB;
    a2 += bf2f(vB.y) * nB; a3 += bf2f(vB.y >> 16) * nB;
    a4 += bf2f(vB.z) * nB; a5 += bf2f(vB.z >> 16) * nB;
    a6 += bf2f(vB.w) * nB; a7 += bf2f(vB.w >> 16) * nB;
  }
  for (; pb < p1; pb += 4) {
    int p = pb + g;
    if (p < p1) {
      int s = esrc[p];
      float nr = dinv[s] * di;
      uint4 v = hp[(size_t)s * 16 + q];
      a0 += bf2f(v.x) * nr; a1 += bf2f(v.x >> 16) * nr;
      a2 += bf2f(v.y) * nr; a3 += bf2f(v.y >> 16) * nr;
      a4 += bf2f(v.z) * nr; a5 += bf2f(v.z >> 16) * nr;
      a6 += bf2f(v.w) * nr; a7 += bf2f(v.w >> 16) * nr;
    }
  }
  a0 += __shfl_xor(a0, 16); a1 += __shfl_xor(a1, 16);
  a2 += __shfl_xor(a2, 16); a3 += __shfl_xor(a3, 16);
  a4 += __shfl_xor(a4, 16); a5 += __shfl_xor(a5, 16);
  a6 += __shfl_xor(a6, 16); a7 += __shfl_xor(a7, 16);
  a0 += __shfl_xor(a0, 32); a1 += __shfl_xor(a1, 32);
  a2 += __shfl_xor(a2, 32); a3 += __shfl_xor(a3, 32);
  a4 += __shfl_xor(a4, 32); a5 += __shfl_xor(a5, 32);
  a6 += __shfl_xor(a6, 32); a7 += __shfl_xor(a7, 32);
  if (g == 0) {
    uint4 sv = hp[(size_t)i * 16 + q];
    float dd = di * di;
    a0 += bf2f(sv.x) * dd; a1 += bf2f(sv.x >> 16) * dd;
    a2 += bf2f(sv.y) * dd; a3 += bf2f(sv.y >> 16) * dd;
    a4 += bf2f(sv.z) * dd; a5 += bf2f(sv.z >> 16) * dd;
    a6 += bf2f(sv.w) * dd; a7 += bf2f(sv.w >> 16) * dd;
    float4 b0 = ((const float4*)b)[q * 2];
    float4 b1v = ((const float4*)b)[q * 2 + 1];
    a0 = fmaxf(a0 + b0.x, 0.f); a1 = fmaxf(a1 + b0.y, 0.f);
    a2 = fmaxf(a2 + b0.z, 0.f); a3 = fmaxf(a3 + b0.w, 0.f);
    a4 = fmaxf(a4 + b1v.x, 0.f); a5 = fmaxf(a5 + b1v.y, 0.f);
    a6 = fmaxf(a6 + b1v.z, 0.f); a7 = fmaxf(a7 + b1v.w, 0.f);
    uint4 o;
    o.x = (unsigned int)f2bf(a0) | ((unsigned int)f2bf(a1) << 16);
    o.y = (unsigned int)f2bf(a2) | ((unsigned int)f2bf(a3) << 16);
    o.z = (unsigned int)f2bf(a4) | ((unsigned int)f2bf(a5) << 16);
    o.w = (unsigned int)f2bf(a6) | ((unsigned int)f2bf(a7) << 16);
    outb[(size_t)i * 16 + q] = o;
  }
}

// Layer-2 agg + bias + log_softmax: wave per node, 6 edges per gather instruction.
__global__ void agg2_kernel(const unsigned short* __restrict__ h, const int* __restrict__ off,
                            const int* __restrict__ esrc, const float* __restrict__ dinv,
                            const float* __restrict__ b, float* __restrict__ out, int n) {
  int wv = threadIdx.x >> 6, l = threadIdx.x & 63;
  int i = blockIdx.x * 4 + wv;
  if (i >= n) return;
  int g = l / 10, q = l - g * 10;
  bool lact = l < 60;
  float di = dinv[i];
  const uint2* hp = (const uint2*)h;  // row = 10 uint2 (40 ch)
  float a0 = 0.f, a1 = 0.f, a2 = 0.f, a3 = 0.f;
  int p0 = off[i], p1 = off[i + 1];
  int pb = p0;
  for (; pb + 5 < p1; pb += 6) {
    if (lact) {
      int p = pb + g;
      int s = esrc[p];
      float nr = dinv[s] * di;
      uint2 v = hp[(size_t)s * 10 + q];
      a0 += bf2f(v.x) * nr; a1 += bf2f(v.x >> 16) * nr;
      a2 += bf2f(v.y) * nr; a3 += bf2f(v.y >> 16) * nr;
    }
  }
  if (pb < p1) {
    int p = pb + g;
    if (lact && p < p1) {
      int s = esrc[p];
      float nr = dinv[s] * di;
      uint2 v = hp[(size_t)s * 10 + q];
      a0 += bf2f(v.x) * nr; a1 += bf2f(v.x >> 16) * nr;
      a2 += bf2f(v.y) * nr; a3 += bf2f(v.y >> 16) * nr;
    }
  }
  float t0 = 0.f, t1 = 0.f, t2 = 0.f, t3 = 0.f;
  #pragma unroll
  for (int gg = 0; gg < 6; ++gg) {
    int sl = gg * 10 + q;
    t0 += __shfl(a0, sl); t1 += __shfl(a1, sl);
    t2 += __shfl(a2, sl); t3 += __shfl(a3, sl);
  }
  bool act = l < 10;
  float v0, v1, v2, v3;
  if (act) {
    uint2 sv = hp[(size_t)i * 10 + l];
    float dd = di * di;
    float4 bb = ((const float4*)b)[l];
    v0 = t0 + bf2f(sv.x) * dd + bb.x;
    v1 = t1 + bf2f(sv.x >> 16) * dd + bb.y;
    v2 = t2 + bf2f(sv.y) * dd + bb.z;
    v3 = t3 + bf2f(sv.y >> 16) * dd + bb.w;
  } else {
    v0 = v1 = v2 = v3 = -INFINITY;
  }
  float mm = fmaxf(fmaxf(v0, v1), fmaxf(v2, v3));
  #pragma unroll
  for (int d = 32; d > 0; d >>= 1) mm = fmaxf(mm, __shfl_xor(mm, d));
  float e = act ? (expf(v0 - mm) + expf(v1 - mm) + expf(v2 - mm) + expf(v3 - mm)) : 0.f;
  float ss = e;
  #pragma unroll
  for (int d = 32; d > 0; d >>= 1) ss += __shfl_xor(ss, d);
  if (act) {
    float lg = logf(ss);
    float4 o = {v0 - mm - lg, v1 - mm - lg, v2 - mm - lg, v3 - mm - lg};
    *(float4*)&out[(size_t)i * C_OUT + l * 4] = o;
  }
}

// ---------------- launch ----------------

extern "C" void kernel_launch(void* const* d_in, const int* in_sizes, int n_in,
                              void* d_out, int out_size, void* d_ws, size_t ws_size,
                              hipStream_t stream) {
  const float* x  = (const float*)d_in[0];
  const int*   ei = (const int*)d_in[1];
  const float* W1 = (const float*)d_in[2];
  const float* b1 = (const float*)d_in[3];
  const float* W2 = (const float*)d_in[4];
  const float* b2 = (const float*)d_in[5];
  int E = in_sizes[1] / 2;
  const int* src = ei;
  const int* dst = ei + E;

  char* ws = (char*)d_ws;
  size_t o = 0;
  auto alloc = [&](size_t bytes) {
    char* p = ws + o;
    o += (bytes + 255) & ~(size_t)255;
    return p;
  };
  unsigned int* gedge = (unsigned int*)alloc((size_t)NBUCK * CAP * sizeof(unsigned int));
  int*   bcur  = (int*)alloc(NBUCK * sizeof(int));
  int*   goff  = (int*)alloc((NBUCK + 1) * sizeof(int));
  int*   off   = (int*)alloc((NN + 1) * sizeof(int));
  float* dinv  = (float*)alloc(NN * sizeof(float));
  int*   esrc  = (int*)alloc((size_t)E * sizeof(int));
  unsigned short* h1b = (unsigned short*)alloc((size_t)NN * C_HID * sizeof(unsigned short));
  unsigned int*   ag1b = (unsigned int*)alloc((size_t)NN * (C_HID / 2) * sizeof(unsigned int));
  unsigned short* h2b = (unsigned short*)alloc((size_t)NN * C_OUT * sizeof(unsigned short));
  uint4* pbuf2 = (uint4*)alloc(12 * 64 * sizeof(uint4));
  uint4* pbuf1 = (uint4*)alloc(64 * 64 * sizeof(uint4));

  hipMemsetAsync(bcur, 0, NBUCK * sizeof(int), stream);
  passA_kernel<<<(E + EPB - 1) / EPB, 256, 0, stream>>>(src, dst, E, gedge, bcur);
  bscan_kernel<<<1, 128, 0, stream>>>(bcur, goff, off, E);
  passB_kernel<<<NBUCK, 512, 0, stream>>>(gedge, bcur, goff, esrc, off, dinv);
  wprep_kernel<<<19, 256, 0, stream>>>(W1, W2, pbuf1, pbuf2);

  gemm1_kernel<<<(NN + 63) / 64, 256, 0, stream>>>(x, pbuf1, h1b);
  agg1_kernel<<<(NN + 3) / 4, 256, 0, stream>>>(h1b, off, esrc, dinv, b1,
                                                (uint4*)ag1b, NN);
  gemm2_kernel<<<(NN + 63) / 64, 256, 0, stream>>>((const unsigned short*)ag1b, pbuf2, h2b);
  agg2_kernel<<<(NN + 3) / 4, 256, 0, stream>>>(h2b, off, esrc, dinv, b2,
                                                (float*)d_out, NN);
}

// Round 9
// 168.331 us; speedup vs baseline: 3.9953x; 1.0931x over previous
//
#include <hip/hip_runtime.h>
#include <cmath>

#define NN 50000
#define C_IN 256
#define C_HID 128
#define C_OUT 40

#define BSZ 512                          // nodes per bucket
#define NBUCK ((NN + BSZ - 1) / BSZ)     // 98
#define CAP 19456                        // max edges per bucket region
#define EPB 4096                         // edges per passA block

typedef __attribute__((ext_vector_type(8))) short bf16x8;
typedef __attribute__((ext_vector_type(4))) float f32x4;

__device__ __forceinline__ float bf2f(unsigned int u16) {
  unsigned int b = (u16 & 0xFFFFu) << 16;
  return __builtin_bit_cast(float, b);
}
__device__ __forceinline__ unsigned short f2bf(float f) {
  unsigned int b = __builtin_bit_cast(unsigned int, f);
  unsigned int r = (b + 0x7FFF + ((b >> 16) & 1)) >> 16;  // RNE
  return (unsigned short)r;
}

// ---------------- CSR build: pass A — LDS-binned partition into NBUCK regions ------------

__global__ __launch_bounds__(256) void passA_kernel(const int* __restrict__ src,
    const int* __restrict__ dst, int E, unsigned int* __restrict__ gedge,
    int* __restrict__ bcur) {
  __shared__ unsigned int pk[EPB];
  __shared__ unsigned char bof[EPB];
  __shared__ int bcnt[NBUCK], bstart[NBUCK], bpos[NBUCK], gbase[NBUCK];
  int tid = threadIdx.x;
  int e0 = blockIdx.x * EPB;
  int cnt = min(EPB, E - e0);
  for (int b = tid; b < NBUCK; b += 256) bcnt[b] = 0;
  int ds_[16], ss_[16];
  __syncthreads();
  #pragma unroll
  for (int k = 0; k < 16; ++k) {
    int i = tid + k * 256;
    if (i < cnt) {
      ds_[k] = dst[e0 + i];
      ss_[k] = src[e0 + i];
      atomicAdd(&bcnt[ds_[k] >> 9], 1);
    }
  }
  __syncthreads();
  if (tid == 0) {
    int acc = 0;
    for (int b = 0; b < NBUCK; ++b) { bstart[b] = acc; bpos[b] = acc; acc += bcnt[b]; }
  }
  __syncthreads();
  #pragma unroll
  for (int k = 0; k < 16; ++k) {
    int i = tid + k * 256;
    if (i < cnt) {
      int b = ds_[k] >> 9;
      int p = atomicAdd(&bpos[b], 1);
      pk[p] = ((unsigned int)ss_[k] << 9) | (unsigned int)(ds_[k] & 511);
      bof[p] = (unsigned char)b;
    }
  }
  __syncthreads();
  for (int b = tid; b < NBUCK; b += 256)
    gbase[b] = atomicAdd(&bcur[b], bcnt[b]);
  __syncthreads();
  for (int i = tid; i < cnt; i += 256) {
    int b = bof[i];
    int p = gbase[b] + (i - bstart[b]);
    gedge[(size_t)b * CAP + p] = pk[i];
  }
}

__global__ void bscan_kernel(const int* __restrict__ bcur, int* __restrict__ goff,
                             int* __restrict__ off, int E) {
  __shared__ int t[128];
  int tid = threadIdx.x;
  int v = (tid < NBUCK) ? bcur[tid] : 0;
  t[tid] = v;
  __syncthreads();
  for (int d = 1; d < 128; d <<= 1) {
    int x = (tid >= d) ? t[tid - d] : 0;
    __syncthreads();
    t[tid] += x;
    __syncthreads();
  }
  if (tid < NBUCK) goff[tid] = t[tid] - v;
  if (tid == 0) { goff[NBUCK] = E; off[NN] = E; }
}

__global__ __launch_bounds__(512) void passB_kernel(const unsigned int* __restrict__ gedge,
    const int* __restrict__ bcur, const int* __restrict__ goff,
    int* __restrict__ esrc, int* __restrict__ off, float* __restrict__ dinv) {
  __shared__ int dcnt[512];
  __shared__ int dsc[512];
  __shared__ int dcur[512];
  int b = blockIdx.x, tid = threadIdx.x;
  int nE = bcur[b];
  int base = goff[b];
  const unsigned int* reg = gedge + (size_t)b * CAP;
  dcnt[tid] = 0;
  __syncthreads();
  for (int i = tid; i < nE; i += 512)
    atomicAdd(&dcnt[reg[i] & 511], 1);
  __syncthreads();
  int own = dcnt[tid];
  dsc[tid] = own;
  __syncthreads();
  for (int d = 1; d < 512; d <<= 1) {
    int x = (tid >= d) ? dsc[tid - d] : 0;
    __syncthreads();
    dsc[tid] += x;
    __syncthreads();
  }
  int excl = dsc[tid] - own;
  dcur[tid] = excl;
  int node = b * BSZ + tid;
  if (node < NN) {
    off[node]  = base + excl;
    dinv[node] = rsqrtf((float)(own + 1));
  }
  __syncthreads();
  for (int i = tid; i < nE; i += 512) {
    unsigned int p = reg[i];
    int pos = atomicAdd(&dcur[p & 511], 1);
    esrc[base + pos] = (int)(p >> 9);
  }
}

// epack[e] = (src<<16) | bf16(dinv[src]) — one 4B word per edge for the agg kernels.
__global__ void epack_kernel(const int* __restrict__ esrc, const float* __restrict__ dinv,
                             unsigned int* __restrict__ epack, int E) {
  int e = blockIdx.x * 256 + threadIdx.x;
  if (e < E) {
    int s = esrc[e];
    epack[e] = ((unsigned int)s << 16) | (unsigned int)f2bf(dinv[s]);
  }
}

// ---------------- W prep (merged): W1 -> 64 frag-sets, W2 -> 12 frag-sets ---------------

__global__ void wprep_kernel(const float* __restrict__ W1, const float* __restrict__ W2,
                             uint4* __restrict__ pbuf1, uint4* __restrict__ pbuf2) {
  int blk = blockIdx.x;
  int tid = threadIdx.x;
  if (blk < 16) {  // W1
    int gid = blk * 256 + tid;
    int l = gid & 63, idx = gid >> 6;  // idx = t*8+ks
    int ks = idx & 7, t = idx >> 3;
    int c = t * 16 + (l & 15);
    int kbase = ks * 32 + (l >> 4) * 8;
    unsigned int u[4];
    #pragma unroll
    for (int jp = 0; jp < 4; ++jp) {
      float v0 = W1[(size_t)(kbase + 2 * jp) * C_HID + c];
      float v1 = W1[(size_t)(kbase + 2 * jp + 1) * C_HID + c];
      u[jp] = (unsigned int)f2bf(v0) | ((unsigned int)f2bf(v1) << 16);
    }
    pbuf1[idx * 64 + l] = make_uint4(u[0], u[1], u[2], u[3]);
  } else {  // W2
    int gid = (blk - 16) * 256 + tid;
    int l = gid & 63, idx = gid >> 6;  // idx = t*4+ks
    int ks = idx & 3, t = idx >> 2;
    int c = t * 16 + (l & 15);
    int kbase = ks * 32 + (l >> 4) * 8;
    unsigned int u[4];
    #pragma unroll
    for (int jp = 0; jp < 4; ++jp) {
      float v0 = (c < C_OUT) ? W2[(size_t)(kbase + 2 * jp) * C_OUT + c] : 0.f;
      float v1 = (c < C_OUT) ? W2[(size_t)(kbase + 2 * jp + 1) * C_OUT + c] : 0.f;
      u[jp] = (unsigned int)f2bf(v0) | ((unsigned int)f2bf(v1) << 16);
    }
    pbuf2[idx * 64 + l] = make_uint4(u[0], u[1], u[2], u[3]);
  }
}

// ---------------- GEMM 1 (MFMA): h1[50000,128](bf16) = x(->bf16) @ W1 -------------------

__global__ __launch_bounds__(256) void gemm1_kernel(const float* __restrict__ x,
    const uint4* __restrict__ pb, unsigned short* __restrict__ h) {
  int l = threadIdx.x & 63, w = threadIdx.x >> 6;
  int row0 = blockIdx.x * 64 + w * 16;
  int arow = min(row0 + (l & 15), NN - 1);
  const float* xp = x + (size_t)arow * C_IN + (l >> 4) * 8;
  bf16x8 a[8];
  #pragma unroll
  for (int ks = 0; ks < 8; ++ks) {
    float4 a0 = *(const float4*)(xp + ks * 32);
    float4 a1 = *(const float4*)(xp + ks * 32 + 4);
    union { bf16x8 v; unsigned short s[8]; } pa;
    pa.s[0] = f2bf(a0.x); pa.s[1] = f2bf(a0.y); pa.s[2] = f2bf(a0.z); pa.s[3] = f2bf(a0.w);
    pa.s[4] = f2bf(a1.x); pa.s[5] = f2bf(a1.y); pa.s[6] = f2bf(a1.z); pa.s[7] = f2bf(a1.w);
    a[ks] = pa.v;
  }
  f32x4 acc[8] = {};
  #pragma unroll
  for (int t = 0; t < 8; ++t) {
    #pragma unroll
    for (int ks = 0; ks < 8; ++ks) {
      bf16x8 b = __builtin_bit_cast(bf16x8, pb[(t * 8 + ks) * 64 + l]);
      acc[t] = __builtin_amdgcn_mfma_f32_16x16x32_bf16(a[ks], b, acc[t], 0, 0, 0);
    }
  }
  int c0 = l & 15, rb = (l >> 4) * 4;
  #pragma unroll
  for (int t = 0; t < 8; ++t) {
    #pragma unroll
    for (int r = 0; r < 4; ++r) {
      int row = row0 + rb + r;
      if (row < NN) h[(size_t)row * C_HID + t * 16 + c0] = f2bf(acc[t][r]);
    }
  }
}

// ---------------- GEMM 2 (MFMA): h2[50000,40](bf16) = ag1(bf16) @ W2 --------------------

__global__ __launch_bounds__(256) void gemm2_kernel(const unsigned short* __restrict__ ag1b,
    const uint4* __restrict__ pbuf, unsigned short* __restrict__ h2) {
  int l = threadIdx.x & 63, w = threadIdx.x >> 6;
  int row0 = blockIdx.x * 64 + w * 16;
  int arow = min(row0 + (l & 15), NN - 1);
  const uint4* ap = (const uint4*)(ag1b + (size_t)arow * C_HID + (l >> 4) * 8);
  bf16x8 a[4];
  #pragma unroll
  for (int ks = 0; ks < 4; ++ks) a[ks] = __builtin_bit_cast(bf16x8, ap[ks * 4]);
  f32x4 acc[3] = {};
  #pragma unroll
  for (int t = 0; t < 3; ++t) {
    #pragma unroll
    for (int ks = 0; ks < 4; ++ks) {
      bf16x8 b = __builtin_bit_cast(bf16x8, pbuf[(t * 4 + ks) * 64 + l]);
      acc[t] = __builtin_amdgcn_mfma_f32_16x16x32_bf16(a[ks], b, acc[t], 0, 0, 0);
    }
  }
  int rbase = row0 + (l >> 4) * 4;
  int c0 = l & 15;
  #pragma unroll
  for (int t = 0; t < 3; ++t) {
    int col = t * 16 + c0;
    if (col < C_OUT) {
      #pragma unroll
      for (int r = 0; r < 4; ++r) {
        int row = rbase + r;
        if (row < NN) h2[(size_t)row * C_OUT + col] = f2bf(acc[t][r]);
      }
    }
  }
}

// ---------------- Aggregation ----------------

// Layer-1 agg: wave per node, 16 lanes/edge (uint4 = 8 ch), 16 edges per iteration
// (4 gather instructions in flight), epack prefetched one iteration ahead.
__global__ void agg1_kernel(const unsigned short* __restrict__ h, const int* __restrict__ off,
                            const unsigned int* __restrict__ epack,
                            const float* __restrict__ dinv, const float* __restrict__ b,
                            uint4* __restrict__ outb, int n, int E) {
  int wv = threadIdx.x >> 6, l = threadIdx.x & 63;
  int i = blockIdx.x * 4 + wv;
  if (i >= n) return;
  int g = l >> 4, q = l & 15;
  float di = dinv[i];
  const uint4* hp = (const uint4*)h;  // row = 16 uint4 (128 ch)
  float a0 = 0.f, a1 = 0.f, a2 = 0.f, a3 = 0.f, a4 = 0.f, a5 = 0.f, a6 = 0.f, a7 = 0.f;
  int p0 = off[i], p1 = off[i + 1];
  int pb = p0;
  unsigned int e0 = epack[min(pb + g, E - 1)];
  unsigned int e1 = epack[min(pb + 4 + g, E - 1)];
  unsigned int e2 = epack[min(pb + 8 + g, E - 1)];
  unsigned int e3 = epack[min(pb + 12 + g, E - 1)];
  #define ACC_EDGE(ee)                                                        \
    {                                                                         \
      int s_ = (int)((ee) >> 16);                                             \
      float n_ = bf2f(ee) * di;                                               \
      uint4 v_ = hp[(size_t)s_ * 16 + q];                                     \
      a0 += bf2f(v_.x) * n_; a1 += bf2f(v_.x >> 16) * n_;                     \
      a2 += bf2f(v_.y) * n_; a3 += bf2f(v_.y >> 16) * n_;                     \
      a4 += bf2f(v_.z) * n_; a5 += bf2f(v_.z >> 16) * n_;                     \
      a6 += bf2f(v_.w) * n_; a7 += bf2f(v_.w >> 16) * n_;                     \
    }
  for (; pb + 15 < p1; pb += 16) {
    int np = pb + 16;
    unsigned int f0 = epack[min(np + g, E - 1)];
    unsigned int f1 = epack[min(np + 4 + g, E - 1)];
    unsigned int f2 = epack[min(np + 8 + g, E - 1)];
    unsigned int f3 = epack[min(np + 12 + g, E - 1)];
    ACC_EDGE(e0); ACC_EDGE(e1); ACC_EDGE(e2); ACC_EDGE(e3);
    e0 = f0; e1 = f1; e2 = f2; e3 = f3;
  }
  if (pb + g      < p1) ACC_EDGE(e0);
  if (pb + 4 + g  < p1) ACC_EDGE(e1);
  if (pb + 8 + g  < p1) ACC_EDGE(e2);
  if (pb + 12 + g < p1) ACC_EDGE(e3);
  #undef ACC_EDGE
  a0 += __shfl_xor(a0, 16); a1 += __shfl_xor(a1, 16);
  a2 += __shfl_xor(a2, 16); a3 += __shfl_xor(a3, 16);
  a4 += __shfl_xor(a4, 16); a5 += __shfl_xor(a5, 16);
  a6 += __shfl_xor(a6, 16); a7 += __shfl_xor(a7, 16);
  a0 += __shfl_xor(a0, 32); a1 += __shfl_xor(a1, 32);
  a2 += __shfl_xor(a2, 32); a3 += __shfl_xor(a3, 32);
  a4 += __shfl_xor(a4, 32); a5 += __shfl_xor(a5, 32);
  a6 += __shfl_xor(a6, 32); a7 += __shfl_xor(a7, 32);
  if (g == 0) {
    uint4 sv = hp[(size_t)i * 16 + q];
    float dd = di * di;
    a0 += bf2f(sv.x) * dd; a1 += bf2f(sv.x >> 16) * dd;
    a2 += bf2f(sv.y) * dd; a3 += bf2f(sv.y >> 16) * dd;
    a4 += bf2f(sv.z) * dd; a5 += bf2f(sv.z >> 16) * dd;
    a6 += bf2f(sv.w) * dd; a7 += bf2f(sv.w >> 16) * dd;
    float4 b0 = ((const float4*)b)[q * 2];
    float4 b1v = ((const float4*)b)[q * 2 + 1];
    a0 = fmaxf(a0 + b0.x, 0.f); a1 = fmaxf(a1 + b0.y, 0.f);
    a2 = fmaxf(a2 + b0.z, 0.f); a3 = fmaxf(a3 + b0.w, 0.f);
    a4 = fmaxf(a4 + b1v.x, 0.f); a5 = fmaxf(a5 + b1v.y, 0.f);
    a6 = fmaxf(a6 + b1v.z, 0.f); a7 = fmaxf(a7 + b1v.w, 0.f);
    uint4 o;
    o.x = (unsigned int)f2bf(a0) | ((unsigned int)f2bf(a1) << 16);
    o.y = (unsigned int)f2bf(a2) | ((unsigned int)f2bf(a3) << 16);
    o.z = (unsigned int)f2bf(a4) | ((unsigned int)f2bf(a5) << 16);
    o.w = (unsigned int)f2bf(a6) | ((unsigned int)f2bf(a7) << 16);
    outb[(size_t)i * 16 + q] = o;
  }
}

// Layer-2 agg + bias + log_softmax: wave per node, 12 edges/iter (2 gathers in flight),
// epack prefetched one iteration ahead.
__global__ void agg2_kernel(const unsigned short* __restrict__ h, const int* __restrict__ off,
                            const unsigned int* __restrict__ epack,
                            const float* __restrict__ dinv, const float* __restrict__ b,
                            float* __restrict__ out, int n, int E) {
  int wv = threadIdx.x >> 6, l = threadIdx.x & 63;
  int i = blockIdx.x * 4 + wv;
  if (i >= n) return;
  int g = l / 10, q = l - g * 10;
  bool lact = l < 60;
  if (!lact) g = 0;  // keep epack indices tame for lanes 60-63
  float di = dinv[i];
  const uint2* hp = (const uint2*)h;  // row = 10 uint2 (40 ch)
  float a0 = 0.f, a1 = 0.f, a2 = 0.f, a3 = 0.f;
  int p0 = off[i], p1 = off[i + 1];
  int pb = p0;
  unsigned int e0 = epack[min(pb + g, E - 1)];
  unsigned int e1 = epack[min(pb + 6 + g, E - 1)];
  #define ACC_EDGE2(ee)                                                       \
    {                                                                         \
      int s_ = (int)((ee) >> 16);                                             \
      float n_ = bf2f(ee) * di;                                               \
      uint2 v_ = hp[(size_t)s_ * 10 + q];                                     \
      a0 += bf2f(v_.x) * n_; a1 += bf2f(v_.x >> 16) * n_;                     \
      a2 += bf2f(v_.y) * n_; a3 += bf2f(v_.y >> 16) * n_;                     \
    }
  for (; pb + 11 < p1; pb += 12) {
    int np = pb + 12;
    unsigned int f0 = epack[min(np + g, E - 1)];
    unsigned int f1 = epack[min(np + 6 + g, E - 1)];
    if (lact) { ACC_EDGE2(e0); ACC_EDGE2(e1); }
    e0 = f0; e1 = f1;
  }
  if (lact && pb + g < p1) ACC_EDGE2(e0);
  if (lact && pb + 6 + g < p1) ACC_EDGE2(e1);
  #undef ACC_EDGE2
  float t0 = 0.f, t1 = 0.f, t2 = 0.f, t3 = 0.f;
  #pragma unroll
  for (int gg = 0; gg < 6; ++gg) {
    int sl = gg * 10 + q;
    t0 += __shfl(a0, sl); t1 += __shfl(a1, sl);
    t2 += __shfl(a2, sl); t3 += __shfl(a3, sl);
  }
  bool act = l < 10;
  float v0, v1, v2, v3;
  if (act) {
    uint2 sv = hp[(size_t)i * 10 + l];
    float dd = di * di;
    float4 bb = ((const float4*)b)[l];
    v0 = t0 + bf2f(sv.x) * dd + bb.x;
    v1 = t1 + bf2f(sv.x >> 16) * dd + bb.y;
    v2 = t2 + bf2f(sv.y) * dd + bb.z;
    v3 = t3 + bf2f(sv.y >> 16) * dd + bb.w;
  } else {
    v0 = v1 = v2 = v3 = -INFINITY;
  }
  float mm = fmaxf(fmaxf(v0, v1), fmaxf(v2, v3));
  #pragma unroll
  for (int d = 32; d > 0; d >>= 1) mm = fmaxf(mm, __shfl_xor(mm, d));
  float e = act ? (expf(v0 - mm) + expf(v1 - mm) + expf(v2 - mm) + expf(v3 - mm)) : 0.f;
  float ss = e;
  #pragma unroll
  for (int d = 32; d > 0; d >>= 1) ss += __shfl_xor(ss, d);
  if (act) {
    float lg = logf(ss);
    float4 o = {v0 - mm - lg, v1 - mm - lg, v2 - mm - lg, v3 - mm - lg};
    *(float4*)&out[(size_t)i * C_OUT + l * 4] = o;
  }
}

// ---------------- launch ----------------

extern "C" void kernel_launch(void* const* d_in, const int* in_sizes, int n_in,
                              void* d_out, int out_size, void* d_ws, size_t ws_size,
                              hipStream_t stream) {
  const float* x  = (const float*)d_in[0];
  const int*   ei = (const int*)d_in[1];
  const float* W1 = (const float*)d_in[2];
  const float* b1 = (const float*)d_in[3];
  const float* W2 = (const float*)d_in[4];
  const float* b2 = (const float*)d_in[5];
  int E = in_sizes[1] / 2;
  const int* src = ei;
  const int* dst = ei + E;

  char* ws = (char*)d_ws;
  size_t o = 0;
  auto alloc = [&](size_t bytes) {
    char* p = ws + o;
    o += (bytes + 255) & ~(size_t)255;
    return p;
  };
  unsigned int* gedge = (unsigned int*)alloc((size_t)NBUCK * CAP * sizeof(unsigned int));
  int*   bcur  = (int*)alloc(NBUCK * sizeof(int));
  int*   goff  = (int*)alloc((NBUCK + 1) * sizeof(int));
  int*   off   = (int*)alloc((NN + 1) * sizeof(int));
  float* dinv  = (float*)alloc(NN * sizeof(float));
  int*   esrc  = (int*)alloc((size_t)E * sizeof(int));
  unsigned int* epack = (unsigned int*)alloc((size_t)E * sizeof(unsigned int));
  unsigned short* h1b = (unsigned short*)alloc((size_t)NN * C_HID * sizeof(unsigned short));
  unsigned int*   ag1b = (unsigned int*)alloc((size_t)NN * (C_HID / 2) * sizeof(unsigned int));
  unsigned short* h2b = (unsigned short*)alloc((size_t)NN * C_OUT * sizeof(unsigned short));
  uint4* pbuf2 = (uint4*)alloc(12 * 64 * sizeof(uint4));
  uint4* pbuf1 = (uint4*)alloc(64 * 64 * sizeof(uint4));

  hipMemsetAsync(bcur, 0, NBUCK * sizeof(int), stream);
  passA_kernel<<<(E + EPB - 1) / EPB, 256, 0, stream>>>(src, dst, E, gedge, bcur);
  bscan_kernel<<<1, 128, 0, stream>>>(bcur, goff, off, E);
  passB_kernel<<<NBUCK, 512, 0, stream>>>(gedge, bcur, goff, esrc, off, dinv);
  epack_kernel<<<(E + 255) / 256, 256, 0, stream>>>(esrc, dinv, epack, E);
  wprep_kernel<<<19, 256, 0, stream>>>(W1, W2, pbuf1, pbuf2);

  gemm1_kernel<<<(NN + 63) / 64, 256, 0, stream>>>(x, pbuf1, h1b);
  agg1_kernel<<<(NN + 3) / 4, 256, 0, stream>>>(h1b, off, epack, dinv, b1,
                                                (uint4*)ag1b, NN, E);
  gemm2_kernel<<<(NN + 63) / 64, 256, 0, stream>>>((const unsigned short*)ag1b, pbuf2, h2b);
  agg2_kernel<<<(NN + 3) / 4, 256, 0, stream>>>(h2b, off, epack, dinv, b2,
                                                (float*)d_out, NN, E);
}

// Round 10
// 168.126 us; speedup vs baseline: 4.0002x; 1.0012x over previous
//
#include <hip/hip_runtime.h>
#include <cmath>

#define NN 50000
#define C_IN 256
#define C_HID 128
#define C_OUT 40

#define BSZ 512                          // nodes per bucket
#define NBUCK ((NN + BSZ - 1) / BSZ)     // 98
#define CAP 19456                        // max edges per bucket region
#define EPB 4096                         // edges per passA block

typedef __attribute__((ext_vector_type(8))) short bf16x8;
typedef __attribute__((ext_vector_type(4))) float f32x4;

__device__ __forceinline__ float bf2f(unsigned int u16) {
  unsigned int b = (u16 & 0xFFFFu) << 16;
  return __builtin_bit_cast(float, b);
}
__device__ __forceinline__ unsigned short f2bf(float f) {
  unsigned int b = __builtin_bit_cast(unsigned int, f);
  unsigned int r = (b + 0x7FFF + ((b >> 16) & 1)) >> 16;  // RNE
  return (unsigned short)r;
}

// ---------------- CSR build: pass A — LDS-binned partition into NBUCK regions ------------

__global__ __launch_bounds__(256) void passA_kernel(const int* __restrict__ src,
    const int* __restrict__ dst, int E, unsigned int* __restrict__ gedge,
    int* __restrict__ bcur) {
  __shared__ unsigned int pk[EPB];
  __shared__ unsigned char bof[EPB];
  __shared__ int bcnt[NBUCK], bstart[NBUCK], bpos[NBUCK], gbase[NBUCK];
  int tid = threadIdx.x;
  int e0 = blockIdx.x * EPB;
  int cnt = min(EPB, E - e0);
  for (int b = tid; b < NBUCK; b += 256) bcnt[b] = 0;
  int ds_[16], ss_[16];
  __syncthreads();
  #pragma unroll
  for (int k = 0; k < 16; ++k) {
    int i = tid + k * 256;
    if (i < cnt) {
      ds_[k] = dst[e0 + i];
      ss_[k] = src[e0 + i];
      atomicAdd(&bcnt[ds_[k] >> 9], 1);
    }
  }
  __syncthreads();
  if (tid == 0) {
    int acc = 0;
    for (int b = 0; b < NBUCK; ++b) { bstart[b] = acc; bpos[b] = acc; acc += bcnt[b]; }
  }
  __syncthreads();
  #pragma unroll
  for (int k = 0; k < 16; ++k) {
    int i = tid + k * 256;
    if (i < cnt) {
      int b = ds_[k] >> 9;
      int p = atomicAdd(&bpos[b], 1);
      pk[p] = ((unsigned int)ss_[k] << 9) | (unsigned int)(ds_[k] & 511);
      bof[p] = (unsigned char)b;
    }
  }
  __syncthreads();
  for (int b = tid; b < NBUCK; b += 256)
    gbase[b] = atomicAdd(&bcur[b], bcnt[b]);
  __syncthreads();
  for (int i = tid; i < cnt; i += 256) {
    int b = bof[i];
    int p = gbase[b] + (i - bstart[b]);
    gedge[(size_t)b * CAP + p] = pk[i];
  }
}

__global__ void bscan_kernel(const int* __restrict__ bcur, int* __restrict__ goff,
                             int* __restrict__ off, int E) {
  __shared__ int t[128];
  int tid = threadIdx.x;
  int v = (tid < NBUCK) ? bcur[tid] : 0;
  t[tid] = v;
  __syncthreads();
  for (int d = 1; d < 128; d <<= 1) {
    int x = (tid >= d) ? t[tid - d] : 0;
    __syncthreads();
    t[tid] += x;
    __syncthreads();
  }
  if (tid < NBUCK) goff[tid] = t[tid] - v;
  if (tid == 0) { goff[NBUCK] = E; off[NN] = E; }
}

__global__ __launch_bounds__(512) void passB_kernel(const unsigned int* __restrict__ gedge,
    const int* __restrict__ bcur, const int* __restrict__ goff,
    int* __restrict__ esrc, int* __restrict__ off, float* __restrict__ dinv) {
  __shared__ int dcnt[512];
  __shared__ int dsc[512];
  __shared__ int dcur[512];
  int b = blockIdx.x, tid = threadIdx.x;
  int nE = bcur[b];
  int base = goff[b];
  const unsigned int* reg = gedge + (size_t)b * CAP;
  dcnt[tid] = 0;
  __syncthreads();
  for (int i = tid; i < nE; i += 512)
    atomicAdd(&dcnt[reg[i] & 511], 1);
  __syncthreads();
  int own = dcnt[tid];
  dsc[tid] = own;
  __syncthreads();
  for (int d = 1; d < 512; d <<= 1) {
    int x = (tid >= d) ? dsc[tid - d] : 0;
    __syncthreads();
    dsc[tid] += x;
    __syncthreads();
  }
  int excl = dsc[tid] - own;
  dcur[tid] = excl;
  int node = b * BSZ + tid;
  if (node < NN) {
    off[node]  = base + excl;
    dinv[node] = rsqrtf((float)(own + 1));
  }
  __syncthreads();
  for (int i = tid; i < nE; i += 512) {
    unsigned int p = reg[i];
    int pos = atomicAdd(&dcur[p & 511], 1);
    esrc[base + pos] = (int)(p >> 9);
  }
}

// epack[e] = (src<<16) | bf16(dinv[src]) — one 4B word per edge for the agg kernels.
__global__ void epack_kernel(const int* __restrict__ esrc, const float* __restrict__ dinv,
                             unsigned int* __restrict__ epack, int E) {
  int e = blockIdx.x * 256 + threadIdx.x;
  if (e < E) {
    int s = esrc[e];
    epack[e] = ((unsigned int)s << 16) | (unsigned int)f2bf(dinv[s]);
  }
}

// ---------------- W prep (merged): W1 -> 64 frag-sets, W2 -> 12 frag-sets ---------------

__global__ void wprep_kernel(const float* __restrict__ W1, const float* __restrict__ W2,
                             uint4* __restrict__ pbuf1, uint4* __restrict__ pbuf2) {
  int blk = blockIdx.x;
  int tid = threadIdx.x;
  if (blk < 16) {  // W1
    int gid = blk * 256 + tid;
    int l = gid & 63, idx = gid >> 6;  // idx = t*8+ks
    int ks = idx & 7, t = idx >> 3;
    int c = t * 16 + (l & 15);
    int kbase = ks * 32 + (l >> 4) * 8;
    unsigned int u[4];
    #pragma unroll
    for (int jp = 0; jp < 4; ++jp) {
      float v0 = W1[(size_t)(kbase + 2 * jp) * C_HID + c];
      float v1 = W1[(size_t)(kbase + 2 * jp + 1) * C_HID + c];
      u[jp] = (unsigned int)f2bf(v0) | ((unsigned int)f2bf(v1) << 16);
    }
    pbuf1[idx * 64 + l] = make_uint4(u[0], u[1], u[2], u[3]);
  } else {  // W2
    int gid = (blk - 16) * 256 + tid;
    int l = gid & 63, idx = gid >> 6;  // idx = t*4+ks
    int ks = idx & 3, t = idx >> 2;
    int c = t * 16 + (l & 15);
    int kbase = ks * 32 + (l >> 4) * 8;
    unsigned int u[4];
    #pragma unroll
    for (int jp = 0; jp < 4; ++jp) {
      float v0 = (c < C_OUT) ? W2[(size_t)(kbase + 2 * jp) * C_OUT + c] : 0.f;
      float v1 = (c < C_OUT) ? W2[(size_t)(kbase + 2 * jp + 1) * C_OUT + c] : 0.f;
      u[jp] = (unsigned int)f2bf(v0) | ((unsigned int)f2bf(v1) << 16);
    }
    pbuf2[idx * 64 + l] = make_uint4(u[0], u[1], u[2], u[3]);
  }
}

// ---------------- GEMM 1 (MFMA): h1[50000,128](bf16) = x(->bf16) @ W1 -------------------

__global__ __launch_bounds__(256) void gemm1_kernel(const float* __restrict__ x,
    const uint4* __restrict__ pb, unsigned short* __restrict__ h) {
  int l = threadIdx.x & 63, w = threadIdx.x >> 6;
  int row0 = blockIdx.x * 64 + w * 16;
  int arow = min(row0 + (l & 15), NN - 1);
  const float* xp = x + (size_t)arow * C_IN + (l >> 4) * 8;
  bf16x8 a[8];
  #pragma unroll
  for (int ks = 0; ks < 8; ++ks) {
    float4 a0 = *(const float4*)(xp + ks * 32);
    float4 a1 = *(const float4*)(xp + ks * 32 + 4);
    union { bf16x8 v; unsigned short s[8]; } pa;
    pa.s[0] = f2bf(a0.x); pa.s[1] = f2bf(a0.y); pa.s[2] = f2bf(a0.z); pa.s[3] = f2bf(a0.w);
    pa.s[4] = f2bf(a1.x); pa.s[5] = f2bf(a1.y); pa.s[6] = f2bf(a1.z); pa.s[7] = f2bf(a1.w);
    a[ks] = pa.v;
  }
  f32x4 acc[8] = {};
  #pragma unroll
  for (int t = 0; t < 8; ++t) {
    #pragma unroll
    for (int ks = 0; ks < 8; ++ks) {
      bf16x8 b = __builtin_bit_cast(bf16x8, pb[(t * 8 + ks) * 64 + l]);
      acc[t] = __builtin_amdgcn_mfma_f32_16x16x32_bf16(a[ks], b, acc[t], 0, 0, 0);
    }
  }
  int c0 = l & 15, rb = (l >> 4) * 4;
  #pragma unroll
  for (int t = 0; t < 8; ++t) {
    #pragma unroll
    for (int r = 0; r < 4; ++r) {
      int row = row0 + rb + r;
      if (row < NN) h[(size_t)row * C_HID + t * 16 + c0] = f2bf(acc[t][r]);
    }
  }
}

// ---------------- GEMM 2 (MFMA): h2[50000,40](bf16) = ag1(bf16) @ W2 --------------------

__global__ __launch_bounds__(256) void gemm2_kernel(const unsigned short* __restrict__ ag1b,
    const uint4* __restrict__ pbuf, unsigned short* __restrict__ h2) {
  int l = threadIdx.x & 63, w = threadIdx.x >> 6;
  int row0 = blockIdx.x * 64 + w * 16;
  int arow = min(row0 + (l & 15), NN - 1);
  const uint4* ap = (const uint4*)(ag1b + (size_t)arow * C_HID + (l >> 4) * 8);
  bf16x8 a[4];
  #pragma unroll
  for (int ks = 0; ks < 4; ++ks) a[ks] = __builtin_bit_cast(bf16x8, ap[ks * 4]);
  f32x4 acc[3] = {};
  #pragma unroll
  for (int t = 0; t < 3; ++t) {
    #pragma unroll
    for (int ks = 0; ks < 4; ++ks) {
      bf16x8 b = __builtin_bit_cast(bf16x8, pbuf[(t * 4 + ks) * 64 + l]);
      acc[t] = __builtin_amdgcn_mfma_f32_16x16x32_bf16(a[ks], b, acc[t], 0, 0, 0);
    }
  }
  int rbase = row0 + (l >> 4) * 4;
  int c0 = l & 15;
  #pragma unroll
  for (int t = 0; t < 3; ++t) {
    int col = t * 16 + c0;
    if (col < C_OUT) {
      #pragma unroll
      for (int r = 0; r < 4; ++r) {
        int row = rbase + r;
        if (row < NN) h2[(size_t)row * C_OUT + col] = f2bf(acc[t][r]);
      }
    }
  }
}

// ---------------- Aggregation ----------------

// Layer-1 agg: wave per node, 16 lanes/edge, 16 edges/iter, 2-level software pipeline:
// steady state holds meta[t],meta[t+1],data[t]; body issues data[t+1] (addr from resident
// meta) + meta[t+2] (independent), computes on data[t]. No dependent wait in the loop.
__global__ void agg1_kernel(const unsigned short* __restrict__ h, const int* __restrict__ off,
                            const unsigned int* __restrict__ epack,
                            const float* __restrict__ dinv, const float* __restrict__ b,
                            uint4* __restrict__ outb, int n, int E) {
  int wv = threadIdx.x >> 6, l = threadIdx.x & 63;
  int i = blockIdx.x * 4 + wv;
  if (i >= n) return;
  int g = l >> 4, q = l & 15;
  float di = dinv[i];
  const uint4* hp = (const uint4*)h;  // row = 16 uint4 (128 ch)
  float a0 = 0.f, a1 = 0.f, a2 = 0.f, a3 = 0.f, a4 = 0.f, a5 = 0.f, a6 = 0.f, a7 = 0.f;
  int p0 = off[i], p1 = off[i + 1];
  int pb = p0;
  int Em1 = E - 1;
  // meta for iter t and t+1
  unsigned int e0 = epack[min(pb + g, Em1)];
  unsigned int e1 = epack[min(pb + 4 + g, Em1)];
  unsigned int e2 = epack[min(pb + 8 + g, Em1)];
  unsigned int e3 = epack[min(pb + 12 + g, Em1)];
  unsigned int f0 = epack[min(pb + 16 + g, Em1)];
  unsigned int f1 = epack[min(pb + 20 + g, Em1)];
  unsigned int f2 = epack[min(pb + 24 + g, Em1)];
  unsigned int f3 = epack[min(pb + 28 + g, Em1)];
  // data for iter t
  uint4 H0 = hp[(size_t)(e0 >> 16) * 16 + q];
  uint4 H1 = hp[(size_t)(e1 >> 16) * 16 + q];
  uint4 H2 = hp[(size_t)(e2 >> 16) * 16 + q];
  uint4 H3 = hp[(size_t)(e3 >> 16) * 16 + q];
  #define ACC_EDGE(vv, ee)                                                    \
    {                                                                         \
      float n_ = bf2f(ee) * di;                                               \
      a0 += bf2f(vv.x) * n_; a1 += bf2f(vv.x >> 16) * n_;                     \
      a2 += bf2f(vv.y) * n_; a3 += bf2f(vv.y >> 16) * n_;                     \
      a4 += bf2f(vv.z) * n_; a5 += bf2f(vv.z >> 16) * n_;                     \
      a6 += bf2f(vv.w) * n_; a7 += bf2f(vv.w >> 16) * n_;                     \
    }
  for (; pb + 31 < p1; pb += 16) {
    uint4 G0 = hp[(size_t)(f0 >> 16) * 16 + q];      // data t+1 (meta resident)
    uint4 G1 = hp[(size_t)(f1 >> 16) * 16 + q];
    uint4 G2 = hp[(size_t)(f2 >> 16) * 16 + q];
    uint4 G3 = hp[(size_t)(f3 >> 16) * 16 + q];
    unsigned int n0 = epack[min(pb + 32 + g, Em1)];  // meta t+2 (independent)
    unsigned int n1 = epack[min(pb + 36 + g, Em1)];
    unsigned int n2 = epack[min(pb + 40 + g, Em1)];
    unsigned int n3 = epack[min(pb + 44 + g, Em1)];
    ACC_EDGE(H0, e0); ACC_EDGE(H1, e1); ACC_EDGE(H2, e2); ACC_EDGE(H3, e3);
    e0 = f0; e1 = f1; e2 = f2; e3 = f3;
    f0 = n0; f1 = n1; f2 = n2; f3 = n3;
    H0 = G0; H1 = G1; H2 = G2; H3 = G3;
  }
  // tail batch 1: edges [pb, pb+16) — data already resident
  if (pb + g < p1)      ACC_EDGE(H0, e0);
  if (pb + 4 + g < p1)  ACC_EDGE(H1, e1);
  if (pb + 8 + g < p1)  ACC_EDGE(H2, e2);
  if (pb + 12 + g < p1) ACC_EDGE(H3, e3);
  // tail batch 2: edges [pb+16, p1), meta in f
  int pc = pb + 16;
  if (pc < p1) {
    uint4 G0 = hp[(size_t)(f0 >> 16) * 16 + q];
    uint4 G1 = hp[(size_t)(f1 >> 16) * 16 + q];
    uint4 G2 = hp[(size_t)(f2 >> 16) * 16 + q];
    uint4 G3 = hp[(size_t)(f3 >> 16) * 16 + q];
    if (pc + g < p1)      ACC_EDGE(G0, f0);
    if (pc + 4 + g < p1)  ACC_EDGE(G1, f1);
    if (pc + 8 + g < p1)  ACC_EDGE(G2, f2);
    if (pc + 12 + g < p1) ACC_EDGE(G3, f3);
  }
  #undef ACC_EDGE
  a0 += __shfl_xor(a0, 16); a1 += __shfl_xor(a1, 16);
  a2 += __shfl_xor(a2, 16); a3 += __shfl_xor(a3, 16);
  a4 += __shfl_xor(a4, 16); a5 += __shfl_xor(a5, 16);
  a6 += __shfl_xor(a6, 16); a7 += __shfl_xor(a7, 16);
  a0 += __shfl_xor(a0, 32); a1 += __shfl_xor(a1, 32);
  a2 += __shfl_xor(a2, 32); a3 += __shfl_xor(a3, 32);
  a4 += __shfl_xor(a4, 32); a5 += __shfl_xor(a5, 32);
  a6 += __shfl_xor(a6, 32); a7 += __shfl_xor(a7, 32);
  if (g == 0) {
    uint4 sv = hp[(size_t)i * 16 + q];
    float dd = di * di;
    a0 += bf2f(sv.x) * dd; a1 += bf2f(sv.x >> 16) * dd;
    a2 += bf2f(sv.y) * dd; a3 += bf2f(sv.y >> 16) * dd;
    a4 += bf2f(sv.z) * dd; a5 += bf2f(sv.z >> 16) * dd;
    a6 += bf2f(sv.w) * dd; a7 += bf2f(sv.w >> 16) * dd;
    float4 b0 = ((const float4*)b)[q * 2];
    float4 b1v = ((const float4*)b)[q * 2 + 1];
    a0 = fmaxf(a0 + b0.x, 0.f); a1 = fmaxf(a1 + b0.y, 0.f);
    a2 = fmaxf(a2 + b0.z, 0.f); a3 = fmaxf(a3 + b0.w, 0.f);
    a4 = fmaxf(a4 + b1v.x, 0.f); a5 = fmaxf(a5 + b1v.y, 0.f);
    a6 = fmaxf(a6 + b1v.z, 0.f); a7 = fmaxf(a7 + b1v.w, 0.f);
    uint4 o;
    o.x = (unsigned int)f2bf(a0) | ((unsigned int)f2bf(a1) << 16);
    o.y = (unsigned int)f2bf(a2) | ((unsigned int)f2bf(a3) << 16);
    o.z = (unsigned int)f2bf(a4) | ((unsigned int)f2bf(a5) << 16);
    o.w = (unsigned int)f2bf(a6) | ((unsigned int)f2bf(a7) << 16);
    outb[(size_t)i * 16 + q] = o;
  }
}

// Layer-2 agg + bias + log_softmax: wave per node, 12 edges/iter, same 2-level pipeline.
__global__ void agg2_kernel(const unsigned short* __restrict__ h, const int* __restrict__ off,
                            const unsigned int* __restrict__ epack,
                            const float* __restrict__ dinv, const float* __restrict__ b,
                            float* __restrict__ out, int n, int E) {
  int wv = threadIdx.x >> 6, l = threadIdx.x & 63;
  int i = blockIdx.x * 4 + wv;
  if (i >= n) return;
  int g = l / 10, q = l - g * 10;
  bool lact = l < 60;
  if (!lact) { g = 0; q = 0; }
  float di = dinv[i];
  const uint2* hp = (const uint2*)h;  // row = 10 uint2 (40 ch)
  float a0 = 0.f, a1 = 0.f, a2 = 0.f, a3 = 0.f;
  int p0 = off[i], p1 = off[i + 1];
  int pb = p0;
  int Em1 = E - 1;
  unsigned int e0 = epack[min(pb + g, Em1)];
  unsigned int e1 = epack[min(pb + 6 + g, Em1)];
  unsigned int f0 = epack[min(pb + 12 + g, Em1)];
  unsigned int f1 = epack[min(pb + 18 + g, Em1)];
  uint2 H0 = hp[(size_t)(e0 >> 16) * 10 + q];
  uint2 H1 = hp[(size_t)(e1 >> 16) * 10 + q];
  #define ACC_EDGE2(vv, ee)                                                   \
    {                                                                         \
      float n_ = bf2f(ee) * di;                                               \
      a0 += bf2f(vv.x) * n_; a1 += bf2f(vv.x >> 16) * n_;                     \
      a2 += bf2f(vv.y) * n_; a3 += bf2f(vv.y >> 16) * n_;                     \
    }
  for (; pb + 23 < p1; pb += 12) {
    uint2 G0 = hp[(size_t)(f0 >> 16) * 10 + q];
    uint2 G1 = hp[(size_t)(f1 >> 16) * 10 + q];
    unsigned int n0 = epack[min(pb + 24 + g, Em1)];
    unsigned int n1 = epack[min(pb + 30 + g, Em1)];
    if (lact) { ACC_EDGE2(H0, e0); ACC_EDGE2(H1, e1); }
    e0 = f0; e1 = f1;
    f0 = n0; f1 = n1;
    H0 = G0; H1 = G1;
  }
  if (lact && pb + g < p1)     ACC_EDGE2(H0, e0);
  if (lact && pb + 6 + g < p1) ACC_EDGE2(H1, e1);
  int pc = pb + 12;
  if (pc < p1) {
    uint2 G0 = hp[(size_t)(f0 >> 16) * 10 + q];
    uint2 G1 = hp[(size_t)(f1 >> 16) * 10 + q];
    if (lact && pc + g < p1)     ACC_EDGE2(G0, f0);
    if (lact && pc + 6 + g < p1) ACC_EDGE2(G1, f1);
  }
  #undef ACC_EDGE2
  float t0 = 0.f, t1 = 0.f, t2 = 0.f, t3 = 0.f;
  #pragma unroll
  for (int gg = 0; gg < 6; ++gg) {
    int sl = gg * 10 + q;
    t0 += __shfl(a0, sl); t1 += __shfl(a1, sl);
    t2 += __shfl(a2, sl); t3 += __shfl(a3, sl);
  }
  bool act = l < 10;
  float v0, v1, v2, v3;
  if (act) {
    uint2 sv = hp[(size_t)i * 10 + l];
    float dd = di * di;
    float4 bb = ((const float4*)b)[l];
    v0 = t0 + bf2f(sv.x) * dd + bb.x;
    v1 = t1 + bf2f(sv.x >> 16) * dd + bb.y;
    v2 = t2 + bf2f(sv.y) * dd + bb.z;
    v3 = t3 + bf2f(sv.y >> 16) * dd + bb.w;
  } else {
    v0 = v1 = v2 = v3 = -INFINITY;
  }
  float mm = fmaxf(fmaxf(v0, v1), fmaxf(v2, v3));
  #pragma unroll
  for (int d = 32; d > 0; d >>= 1) mm = fmaxf(mm, __shfl_xor(mm, d));
  float e = act ? (expf(v0 - mm) + expf(v1 - mm) + expf(v2 - mm) + expf(v3 - mm)) : 0.f;
  float ss = e;
  #pragma unroll
  for (int d = 32; d > 0; d >>= 1) ss += __shfl_xor(ss, d);
  if (act) {
    float lg = logf(ss);
    float4 o = {v0 - mm - lg, v1 - mm - lg, v2 - mm - lg, v3 - mm - lg};
    *(float4*)&out[(size_t)i * C_OUT + l * 4] = o;
  }
}

// ---------------- launch ----------------

extern "C" void kernel_launch(void* const* d_in, const int* in_sizes, int n_in,
                              void* d_out, int out_size, void* d_ws, size_t ws_size,
                              hipStream_t stream) {
  const float* x  = (const float*)d_in[0];
  const int*   ei = (const int*)d_in[1];
  const float* W1 = (const float*)d_in[2];
  const float* b1 = (const float*)d_in[3];
  const float* W2 = (const float*)d_in[4];
  const float* b2 = (const float*)d_in[5];
  int E = in_sizes[1] / 2;
  const int* src = ei;
  const int* dst = ei + E;

  char* ws = (char*)d_ws;
  size_t o = 0;
  auto alloc = [&](size_t bytes) {
    char* p = ws + o;
    o += (bytes + 255) & ~(size_t)255;
    return p;
  };
  unsigned int* gedge = (unsigned int*)alloc((size_t)NBUCK * CAP * sizeof(unsigned int));
  int*   bcur  = (int*)alloc(NBUCK * sizeof(int));
  int*   goff  = (int*)alloc((NBUCK + 1) * sizeof(int));
  int*   off   = (int*)alloc((NN + 1) * sizeof(int));
  float* dinv  = (float*)alloc(NN * sizeof(float));
  int*   esrc  = (int*)alloc((size_t)E * sizeof(int));
  unsigned int* epack = (unsigned int*)alloc((size_t)E * sizeof(unsigned int));
  unsigned short* h1b = (unsigned short*)alloc((size_t)NN * C_HID * sizeof(unsigned short));
  unsigned int*   ag1b = (unsigned int*)alloc((size_t)NN * (C_HID / 2) * sizeof(unsigned int));
  unsigned short* h2b = (unsigned short*)alloc((size_t)NN * C_OUT * sizeof(unsigned short));
  uint4* pbuf2 = (uint4*)alloc(12 * 64 * sizeof(uint4));
  uint4* pbuf1 = (uint4*)alloc(64 * 64 * sizeof(uint4));

  hipMemsetAsync(bcur, 0, NBUCK * sizeof(int), stream);
  passA_kernel<<<(E + EPB - 1) / EPB, 256, 0, stream>>>(src, dst, E, gedge, bcur);
  bscan_kernel<<<1, 128, 0, stream>>>(bcur, goff, off, E);
  passB_kernel<<<NBUCK, 512, 0, stream>>>(gedge, bcur, goff, esrc, off, dinv);
  epack_kernel<<<(E + 255) / 256, 256, 0, stream>>>(esrc, dinv, epack, E);
  wprep_kernel<<<19, 256, 0, stream>>>(W1, W2, pbuf1, pbuf2);

  gemm1_kernel<<<(NN + 63) / 64, 256, 0, stream>>>(x, pbuf1, h1b);
  agg1_kernel<<<(NN + 3) / 4, 256, 0, stream>>>(h1b, off, epack, dinv, b1,
                                                (uint4*)ag1b, NN, E);
  gemm2_kernel<<<(NN + 63) / 64, 256, 0, stream>>>((const unsigned short*)ag1b, pbuf2, h2b);
  agg2_kernel<<<(NN + 3) / 4, 256, 0, stream>>>(h2b, off, epack, dinv, b2,
                                                (float*)d_out, NN, E);
}

// Round 11
// 147.599 us; speedup vs baseline: 4.5565x; 1.1391x over previous
//
#include <hip/hip_runtime.h>
#include <cmath>

#define NN 50000
#define C_IN 256
#define C_HID 128
#define C_OUT 40

#define BSZ 512                          // nodes per bucket
#define NBUCK ((NN + BSZ - 1) / BSZ)     // 98
#define CAP 19456                        // max edges per bucket region
#define EPB 4096                         // edges per passA block

typedef __attribute__((ext_vector_type(8))) short bf16x8;
typedef __attribute__((ext_vector_type(4))) float f32x4;
typedef __attribute__((ext_vector_type(2))) float f32x2;

__device__ __forceinline__ float bf2f(unsigned int u16) {
  unsigned int b = (u16 & 0xFFFFu) << 16;
  return __builtin_bit_cast(float, b);
}
__device__ __forceinline__ unsigned short f2bf(float f) {
  unsigned int b = __builtin_bit_cast(unsigned int, f);
  unsigned int r = (b + 0x7FFF + ((b >> 16) & 1)) >> 16;  // RNE
  return (unsigned short)r;
}

// ---------------- CSR build: pass A — LDS-binned partition into NBUCK regions ------------

__global__ __launch_bounds__(256) void passA_kernel(const int* __restrict__ src,
    const int* __restrict__ dst, int E, unsigned int* __restrict__ gedge,
    int* __restrict__ bcur) {
  __shared__ unsigned int pk[EPB];
  __shared__ unsigned char bof[EPB];
  __shared__ int bcnt[NBUCK], bstart[NBUCK], bpos[NBUCK], gbase[NBUCK];
  int tid = threadIdx.x;
  int e0 = blockIdx.x * EPB;
  int cnt = min(EPB, E - e0);
  for (int b = tid; b < NBUCK; b += 256) bcnt[b] = 0;
  int ds_[16], ss_[16];
  __syncthreads();
  #pragma unroll
  for (int k = 0; k < 16; ++k) {
    int i = tid + k * 256;
    if (i < cnt) {
      ds_[k] = dst[e0 + i];
      ss_[k] = src[e0 + i];
      atomicAdd(&bcnt[ds_[k] >> 9], 1);
    }
  }
  __syncthreads();
  if (tid == 0) {
    int acc = 0;
    for (int b = 0; b < NBUCK; ++b) { bstart[b] = acc; bpos[b] = acc; acc += bcnt[b]; }
  }
  __syncthreads();
  #pragma unroll
  for (int k = 0; k < 16; ++k) {
    int i = tid + k * 256;
    if (i < cnt) {
      int b = ds_[k] >> 9;
      int p = atomicAdd(&bpos[b], 1);
      pk[p] = ((unsigned int)ss_[k] << 9) | (unsigned int)(ds_[k] & 511);
      bof[p] = (unsigned char)b;
    }
  }
  __syncthreads();
  for (int b = tid; b < NBUCK; b += 256)
    gbase[b] = atomicAdd(&bcur[b], bcnt[b]);
  __syncthreads();
  for (int i = tid; i < cnt; i += 256) {
    int b = bof[i];
    int p = gbase[b] + (i - bstart[b]);
    gedge[(size_t)b * CAP + p] = pk[i];
  }
}

__global__ void bscan_kernel(const int* __restrict__ bcur, int* __restrict__ goff,
                             int* __restrict__ off, int E) {
  __shared__ int t[128];
  int tid = threadIdx.x;
  int v = (tid < NBUCK) ? bcur[tid] : 0;
  t[tid] = v;
  __syncthreads();
  for (int d = 1; d < 128; d <<= 1) {
    int x = (tid >= d) ? t[tid - d] : 0;
    __syncthreads();
    t[tid] += x;
    __syncthreads();
  }
  if (tid < NBUCK) goff[tid] = t[tid] - v;
  if (tid == 0) { goff[NBUCK] = E; off[NN] = E; }
}

__global__ __launch_bounds__(512) void passB_kernel(const unsigned int* __restrict__ gedge,
    const int* __restrict__ bcur, const int* __restrict__ goff,
    int* __restrict__ esrc, int* __restrict__ off, float* __restrict__ dinv) {
  __shared__ int dcnt[512];
  __shared__ int dsc[512];
  __shared__ int dcur[512];
  int b = blockIdx.x, tid = threadIdx.x;
  int nE = bcur[b];
  int base = goff[b];
  const unsigned int* reg = gedge + (size_t)b * CAP;
  dcnt[tid] = 0;
  __syncthreads();
  for (int i = tid; i < nE; i += 512)
    atomicAdd(&dcnt[reg[i] & 511], 1);
  __syncthreads();
  int own = dcnt[tid];
  dsc[tid] = own;
  __syncthreads();
  for (int d = 1; d < 512; d <<= 1) {
    int x = (tid >= d) ? dsc[tid - d] : 0;
    __syncthreads();
    dsc[tid] += x;
    __syncthreads();
  }
  int excl = dsc[tid] - own;
  dcur[tid] = excl;
  int node = b * BSZ + tid;
  if (node < NN) {
    off[node]  = base + excl;
    dinv[node] = rsqrtf((float)(own + 1));
  }
  __syncthreads();
  for (int i = tid; i < nE; i += 512) {
    unsigned int p = reg[i];
    int pos = atomicAdd(&dcur[p & 511], 1);
    esrc[base + pos] = (int)(p >> 9);
  }
}

// epack[e] = (src<<16) | bf16(dinv[src])
__global__ void epack_kernel(const int* __restrict__ esrc, const float* __restrict__ dinv,
                             unsigned int* __restrict__ epack, int E) {
  int e = blockIdx.x * 256 + threadIdx.x;
  if (e < E) {
    int s = esrc[e];
    epack[e] = ((unsigned int)s << 16) | (unsigned int)f2bf(dinv[s]);
  }
}

// ---------------- W prep: W1 frags, W2 frags (k-permuted), permuted b1 -------------------
// h1 stored layout: row pos p = c0*8 + t holds channel chan(p) = (p&7)*16 + (p>>3).
// pbuf2 compensates: B-frag row k reads W2[chan(k)][c].

__global__ void wprep_kernel(const float* __restrict__ W1, const float* __restrict__ W2,
                             const float* __restrict__ b1, uint4* __restrict__ pbuf1,
                             uint4* __restrict__ pbuf2, float* __restrict__ bperm) {
  int blk = blockIdx.x;
  int tid = threadIdx.x;
  if (blk < 16) {  // W1
    int gid = blk * 256 + tid;
    int l = gid & 63, idx = gid >> 6;  // idx = t*8+ks
    int ks = idx & 7, t = idx >> 3;
    int c = t * 16 + (l & 15);
    int kbase = ks * 32 + (l >> 4) * 8;
    unsigned int u[4];
    #pragma unroll
    for (int jp = 0; jp < 4; ++jp) {
      float v0 = W1[(size_t)(kbase + 2 * jp) * C_HID + c];
      float v1 = W1[(size_t)(kbase + 2 * jp + 1) * C_HID + c];
      u[jp] = (unsigned int)f2bf(v0) | ((unsigned int)f2bf(v1) << 16);
    }
    pbuf1[idx * 64 + l] = make_uint4(u[0], u[1], u[2], u[3]);
  } else if (blk < 19) {  // W2, k-permuted
    int gid = (blk - 16) * 256 + tid;
    int l = gid & 63, idx = gid >> 6;  // idx = t*4+ks
    int ks = idx & 3, t = idx >> 2;
    int c = t * 16 + (l & 15);
    int kbase = ks * 32 + (l >> 4) * 8;
    unsigned int u[4];
    #pragma unroll
    for (int jp = 0; jp < 4; ++jp) {
      int k0 = kbase + 2 * jp, k1 = k0 + 1;
      int ch0 = ((k0 & 7) << 4) + (k0 >> 3);
      int ch1 = ((k1 & 7) << 4) + (k1 >> 3);
      float v0 = (c < C_OUT) ? W2[(size_t)ch0 * C_OUT + c] : 0.f;
      float v1 = (c < C_OUT) ? W2[(size_t)ch1 * C_OUT + c] : 0.f;
      u[jp] = (unsigned int)f2bf(v0) | ((unsigned int)f2bf(v1) << 16);
    }
    pbuf2[idx * 64 + l] = make_uint4(u[0], u[1], u[2], u[3]);
  } else {  // permuted bias for agg1
    if (tid < C_HID) bperm[tid] = b1[((tid & 7) << 4) + (tid >> 3)];
  }
}

// ---------------- GEMM 1 (MFMA): h1[50000,128](fp8, permuted rows) = x(->bf16) @ W1 ------

__global__ __launch_bounds__(256) void gemm1_kernel(const float* __restrict__ x,
    const uint4* __restrict__ pb, uint2* __restrict__ h) {
  int l = threadIdx.x & 63, w = threadIdx.x >> 6;
  int row0 = blockIdx.x * 64 + w * 16;
  int arow = min(row0 + (l & 15), NN - 1);
  const float* xp = x + (size_t)arow * C_IN + (l >> 4) * 8;
  bf16x8 a[8];
  #pragma unroll
  for (int ks = 0; ks < 8; ++ks) {
    float4 a0 = *(const float4*)(xp + ks * 32);
    float4 a1 = *(const float4*)(xp + ks * 32 + 4);
    union { bf16x8 v; unsigned short s[8]; } pa;
    pa.s[0] = f2bf(a0.x); pa.s[1] = f2bf(a0.y); pa.s[2] = f2bf(a0.z); pa.s[3] = f2bf(a0.w);
    pa.s[4] = f2bf(a1.x); pa.s[5] = f2bf(a1.y); pa.s[6] = f2bf(a1.z); pa.s[7] = f2bf(a1.w);
    a[ks] = pa.v;
  }
  f32x4 acc[8] = {};
  #pragma unroll
  for (int t = 0; t < 8; ++t) {
    #pragma unroll
    for (int ks = 0; ks < 8; ++ks) {
      bf16x8 b = __builtin_bit_cast(bf16x8, pb[(t * 8 + ks) * 64 + l]);
      acc[t] = __builtin_amdgcn_mfma_f32_16x16x32_bf16(a[ks], b, acc[t], 0, 0, 0);
    }
  }
  int c0 = l & 15, rb = (l >> 4) * 4;
  #pragma unroll
  for (int r = 0; r < 4; ++r) {
    int row = row0 + rb + r;
    if (row < NN) {
      int w0 = __builtin_amdgcn_cvt_pk_fp8_f32(acc[0][r], acc[1][r], 0, false);
      w0     = __builtin_amdgcn_cvt_pk_fp8_f32(acc[2][r], acc[3][r], w0, true);
      int w1 = __builtin_amdgcn_cvt_pk_fp8_f32(acc[4][r], acc[5][r], 0, false);
      w1     = __builtin_amdgcn_cvt_pk_fp8_f32(acc[6][r], acc[7][r], w1, true);
      h[(size_t)row * 16 + c0] = make_uint2((unsigned int)w0, (unsigned int)w1);
    }
  }
}

// ---------------- GEMM 2 (MFMA): h2[50000,40](bf16) = ag1(bf16, stored order) @ W2 -------

__global__ __launch_bounds__(256) void gemm2_kernel(const unsigned short* __restrict__ ag1b,
    const uint4* __restrict__ pbuf, unsigned short* __restrict__ h2) {
  int l = threadIdx.x & 63, w = threadIdx.x >> 6;
  int row0 = blockIdx.x * 64 + w * 16;
  int arow = min(row0 + (l & 15), NN - 1);
  const uint4* ap = (const uint4*)(ag1b + (size_t)arow * C_HID + (l >> 4) * 8);
  bf16x8 a[4];
  #pragma unroll
  for (int ks = 0; ks < 4; ++ks) a[ks] = __builtin_bit_cast(bf16x8, ap[ks * 4]);
  f32x4 acc[3] = {};
  #pragma unroll
  for (int t = 0; t < 3; ++t) {
    #pragma unroll
    for (int ks = 0; ks < 4; ++ks) {
      bf16x8 b = __builtin_bit_cast(bf16x8, pbuf[(t * 4 + ks) * 64 + l]);
      acc[t] = __builtin_amdgcn_mfma_f32_16x16x32_bf16(a[ks], b, acc[t], 0, 0, 0);
    }
  }
  int rbase = row0 + (l >> 4) * 4;
  int c0 = l & 15;
  #pragma unroll
  for (int t = 0; t < 3; ++t) {
    int col = t * 16 + c0;
    if (col < C_OUT) {
      #pragma unroll
      for (int r = 0; r < 4; ++r) {
        int row = rbase + r;
        if (row < NN) h2[(size_t)row * C_OUT + col] = f2bf(acc[t][r]);
      }
    }
  }
}

// ---------------- Aggregation ----------------

// Layer-1 agg: wave per node, 16 lanes/edge (uint2 = 8 fp8 ch), 16 edges/iter,
// 2-level pipeline. Output bf16 in same stored order.
__global__ void agg1_kernel(const uint2* __restrict__ h, const int* __restrict__ off,
                            const unsigned int* __restrict__ epack,
                            const float* __restrict__ dinv, const float* __restrict__ bperm,
                            uint4* __restrict__ outb, int n, int E) {
  int wv = threadIdx.x >> 6, l = threadIdx.x & 63;
  int i = blockIdx.x * 4 + wv;
  if (i >= n) return;
  int g = l >> 4, q = l & 15;
  float di = dinv[i];
  float a0 = 0.f, a1 = 0.f, a2 = 0.f, a3 = 0.f, a4 = 0.f, a5 = 0.f, a6 = 0.f, a7 = 0.f;
  int p0 = off[i], p1 = off[i + 1];
  int pb = p0;
  int Em1 = E - 1;
  unsigned int e0 = epack[min(pb + g, Em1)];
  unsigned int e1 = epack[min(pb + 4 + g, Em1)];
  unsigned int e2 = epack[min(pb + 8 + g, Em1)];
  unsigned int e3 = epack[min(pb + 12 + g, Em1)];
  unsigned int f0 = epack[min(pb + 16 + g, Em1)];
  unsigned int f1 = epack[min(pb + 20 + g, Em1)];
  unsigned int f2 = epack[min(pb + 24 + g, Em1)];
  unsigned int f3 = epack[min(pb + 28 + g, Em1)];
  uint2 H0 = h[(size_t)(e0 >> 16) * 16 + q];
  uint2 H1 = h[(size_t)(e1 >> 16) * 16 + q];
  uint2 H2 = h[(size_t)(e2 >> 16) * 16 + q];
  uint2 H3 = h[(size_t)(e3 >> 16) * 16 + q];
  #define ACC_EDGE(vv, ee)                                                    \
    {                                                                         \
      float n_ = bf2f(ee) * di;                                               \
      f32x2 c0_ = __builtin_amdgcn_cvt_pk_f32_fp8((int)vv.x, false);          \
      f32x2 c1_ = __builtin_amdgcn_cvt_pk_f32_fp8((int)vv.x, true);           \
      f32x2 c2_ = __builtin_amdgcn_cvt_pk_f32_fp8((int)vv.y, false);          \
      f32x2 c3_ = __builtin_amdgcn_cvt_pk_f32_fp8((int)vv.y, true);           \
      a0 += c0_[0] * n_; a1 += c0_[1] * n_;                                   \
      a2 += c1_[0] * n_; a3 += c1_[1] * n_;                                   \
      a4 += c2_[0] * n_; a5 += c2_[1] * n_;                                   \
      a6 += c3_[0] * n_; a7 += c3_[1] * n_;                                   \
    }
  for (; pb + 31 < p1; pb += 16) {
    uint2 G0 = h[(size_t)(f0 >> 16) * 16 + q];
    uint2 G1 = h[(size_t)(f1 >> 16) * 16 + q];
    uint2 G2 = h[(size_t)(f2 >> 16) * 16 + q];
    uint2 G3 = h[(size_t)(f3 >> 16) * 16 + q];
    unsigned int n0 = epack[min(pb + 32 + g, Em1)];
    unsigned int n1 = epack[min(pb + 36 + g, Em1)];
    unsigned int n2 = epack[min(pb + 40 + g, Em1)];
    unsigned int n3 = epack[min(pb + 44 + g, Em1)];
    ACC_EDGE(H0, e0); ACC_EDGE(H1, e1); ACC_EDGE(H2, e2); ACC_EDGE(H3, e3);
    e0 = f0; e1 = f1; e2 = f2; e3 = f3;
    f0 = n0; f1 = n1; f2 = n2; f3 = n3;
    H0 = G0; H1 = G1; H2 = G2; H3 = G3;
  }
  if (pb + g < p1)      ACC_EDGE(H0, e0);
  if (pb + 4 + g < p1)  ACC_EDGE(H1, e1);
  if (pb + 8 + g < p1)  ACC_EDGE(H2, e2);
  if (pb + 12 + g < p1) ACC_EDGE(H3, e3);
  int pc = pb + 16;
  if (pc < p1) {
    uint2 G0 = h[(size_t)(f0 >> 16) * 16 + q];
    uint2 G1 = h[(size_t)(f1 >> 16) * 16 + q];
    uint2 G2 = h[(size_t)(f2 >> 16) * 16 + q];
    uint2 G3 = h[(size_t)(f3 >> 16) * 16 + q];
    if (pc + g < p1)      ACC_EDGE(G0, f0);
    if (pc + 4 + g < p1)  ACC_EDGE(G1, f1);
    if (pc + 8 + g < p1)  ACC_EDGE(G2, f2);
    if (pc + 12 + g < p1) ACC_EDGE(G3, f3);
  }
  #undef ACC_EDGE
  a0 += __shfl_xor(a0, 16); a1 += __shfl_xor(a1, 16);
  a2 += __shfl_xor(a2, 16); a3 += __shfl_xor(a3, 16);
  a4 += __shfl_xor(a4, 16); a5 += __shfl_xor(a5, 16);
  a6 += __shfl_xor(a6, 16); a7 += __shfl_xor(a7, 16);
  a0 += __shfl_xor(a0, 32); a1 += __shfl_xor(a1, 32);
  a2 += __shfl_xor(a2, 32); a3 += __shfl_xor(a3, 32);
  a4 += __shfl_xor(a4, 32); a5 += __shfl_xor(a5, 32);
  a6 += __shfl_xor(a6, 32); a7 += __shfl_xor(a7, 32);
  if (g == 0) {
    uint2 sv = h[(size_t)i * 16 + q];
    float dd = di * di;
    f32x2 s0 = __builtin_amdgcn_cvt_pk_f32_fp8((int)sv.x, false);
    f32x2 s1 = __builtin_amdgcn_cvt_pk_f32_fp8((int)sv.x, true);
    f32x2 s2 = __builtin_amdgcn_cvt_pk_f32_fp8((int)sv.y, false);
    f32x2 s3 = __builtin_amdgcn_cvt_pk_f32_fp8((int)sv.y, true);
    a0 += s0[0] * dd; a1 += s0[1] * dd;
    a2 += s1[0] * dd; a3 += s1[1] * dd;
    a4 += s2[0] * dd; a5 += s2[1] * dd;
    a6 += s3[0] * dd; a7 += s3[1] * dd;
    float4 b0 = ((const float4*)bperm)[q * 2];
    float4 b1v = ((const float4*)bperm)[q * 2 + 1];
    a0 = fmaxf(a0 + b0.x, 0.f); a1 = fmaxf(a1 + b0.y, 0.f);
    a2 = fmaxf(a2 + b0.z, 0.f); a3 = fmaxf(a3 + b0.w, 0.f);
    a4 = fmaxf(a4 + b1v.x, 0.f); a5 = fmaxf(a5 + b1v.y, 0.f);
    a6 = fmaxf(a6 + b1v.z, 0.f); a7 = fmaxf(a7 + b1v.w, 0.f);
    uint4 o;
    o.x = (unsigned int)f2bf(a0) | ((unsigned int)f2bf(a1) << 16);
    o.y = (unsigned int)f2bf(a2) | ((unsigned int)f2bf(a3) << 16);
    o.z = (unsigned int)f2bf(a4) | ((unsigned int)f2bf(a5) << 16);
    o.w = (unsigned int)f2bf(a6) | ((unsigned int)f2bf(a7) << 16);
    outb[(size_t)i * 16 + q] = o;
  }
}

// Layer-2 agg + bias + log_softmax: wave per node, 12 edges/iter, 2-level pipeline (bf16 h2).
__global__ void agg2_kernel(const unsigned short* __restrict__ h, const int* __restrict__ off,
                            const unsigned int* __restrict__ epack,
                            const float* __restrict__ dinv, const float* __restrict__ b,
                            float* __restrict__ out, int n, int E) {
  int wv = threadIdx.x >> 6, l = threadIdx.x & 63;
  int i = blockIdx.x * 4 + wv;
  if (i >= n) return;
  int g = l / 10, q = l - g * 10;
  bool lact = l < 60;
  if (!lact) { g = 0; q = 0; }
  float di = dinv[i];
  const uint2* hp = (const uint2*)h;  // row = 10 uint2 (40 ch)
  float a0 = 0.f, a1 = 0.f, a2 = 0.f, a3 = 0.f;
  int p0 = off[i], p1 = off[i + 1];
  int pb = p0;
  int Em1 = E - 1;
  unsigned int e0 = epack[min(pb + g, Em1)];
  unsigned int e1 = epack[min(pb + 6 + g, Em1)];
  unsigned int f0 = epack[min(pb + 12 + g, Em1)];
  unsigned int f1 = epack[min(pb + 18 + g, Em1)];
  uint2 H0 = hp[(size_t)(e0 >> 16) * 10 + q];
  uint2 H1 = hp[(size_t)(e1 >> 16) * 10 + q];
  #define ACC_EDGE2(vv, ee)                                                   \
    {                                                                         \
      float n_ = bf2f(ee) * di;                                               \
      a0 += bf2f(vv.x) * n_; a1 += bf2f(vv.x >> 16) * n_;                     \
      a2 += bf2f(vv.y) * n_; a3 += bf2f(vv.y >> 16) * n_;                     \
    }
  for (; pb + 23 < p1; pb += 12) {
    uint2 G0 = hp[(size_t)(f0 >> 16) * 10 + q];
    uint2 G1 = hp[(size_t)(f1 >> 16) * 10 + q];
    unsigned int n0 = epack[min(pb + 24 + g, Em1)];
    unsigned int n1 = epack[min(pb + 30 + g, Em1)];
    if (lact) { ACC_EDGE2(H0, e0); ACC_EDGE2(H1, e1); }
    e0 = f0; e1 = f1;
    f0 = n0; f1 = n1;
    H0 = G0; H1 = G1;
  }
  if (lact && pb + g < p1)     ACC_EDGE2(H0, e0);
  if (lact && pb + 6 + g < p1) ACC_EDGE2(H1, e1);
  int pc = pb + 12;
  if (pc < p1) {
    uint2 G0 = hp[(size_t)(f0 >> 16) * 10 + q];
    uint2 G1 = hp[(size_t)(f1 >> 16) * 10 + q];
    if (lact && pc + g < p1)     ACC_EDGE2(G0, f0);
    if (lact && pc + 6 + g < p1) ACC_EDGE2(G1, f1);
  }
  #undef ACC_EDGE2
  float t0 = 0.f, t1 = 0.f, t2 = 0.f, t3 = 0.f;
  #pragma unroll
  for (int gg = 0; gg < 6; ++gg) {
    int sl = gg * 10 + q;
    t0 += __shfl(a0, sl); t1 += __shfl(a1, sl);
    t2 += __shfl(a2, sl); t3 += __shfl(a3, sl);
  }
  bool act = l < 10;
  float v0, v1, v2, v3;
  if (act) {
    uint2 sv = hp[(size_t)i * 10 + l];
    float dd = di * di;
    float4 bb = ((const float4*)b)[l];
    v0 = t0 + bf2f(sv.x) * dd + bb.x;
    v1 = t1 + bf2f(sv.x >> 16) * dd + bb.y;
    v2 = t2 + bf2f(sv.y) * dd + bb.z;
    v3 = t3 + bf2f(sv.y >> 16) * dd + bb.w;
  } else {
    v0 = v1 = v2 = v3 = -INFINITY;
  }
  float mm = fmaxf(fmaxf(v0, v1), fmaxf(v2, v3));
  #pragma unroll
  for (int d = 32; d > 0; d >>= 1) mm = fmaxf(mm, __shfl_xor(mm, d));
  float e = act ? (expf(v0 - mm) + expf(v1 - mm) + expf(v2 - mm) + expf(v3 - mm)) : 0.f;
  float ss = e;
  #pragma unroll
  for (int d = 32; d > 0; d >>= 1) ss += __shfl_xor(ss, d);
  if (act) {
    float lg = logf(ss);
    float4 o = {v0 - mm - lg, v1 - mm - lg, v2 - mm - lg, v3 - mm - lg};
    *(float4*)&out[(size_t)i * C_OUT + l * 4] = o;
  }
}

// ---------------- launch ----------------

extern "C" void kernel_launch(void* const* d_in, const int* in_sizes, int n_in,
                              void* d_out, int out_size, void* d_ws, size_t ws_size,
                              hipStream_t stream) {
  const float* x  = (const float*)d_in[0];
  const int*   ei = (const int*)d_in[1];
  const float* W1 = (const float*)d_in[2];
  const float* b1 = (const float*)d_in[3];
  const float* W2 = (const float*)d_in[4];
  const float* b2 = (const float*)d_in[5];
  int E = in_sizes[1] / 2;
  const int* src = ei;
  const int* dst = ei + E;

  char* ws = (char*)d_ws;
  size_t o = 0;
  auto alloc = [&](size_t bytes) {
    char* p = ws + o;
    o += (bytes + 255) & ~(size_t)255;
    return p;
  };
  unsigned int* gedge = (unsigned int*)alloc((size_t)NBUCK * CAP * sizeof(unsigned int));
  int*   bcur  = (int*)alloc(NBUCK * sizeof(int));
  int*   goff  = (int*)alloc((NBUCK + 1) * sizeof(int));
  int*   off   = (int*)alloc((NN + 1) * sizeof(int));
  float* dinv  = (float*)alloc(NN * sizeof(float));
  int*   esrc  = (int*)alloc((size_t)E * sizeof(int));
  unsigned int* epack = (unsigned int*)alloc((size_t)E * sizeof(unsigned int));
  uint2* h1f8  = (uint2*)alloc((size_t)NN * C_HID);  // fp8, 128 B/row
  unsigned int*   ag1b = (unsigned int*)alloc((size_t)NN * (C_HID / 2) * sizeof(unsigned int));
  unsigned short* h2b = (unsigned short*)alloc((size_t)NN * C_OUT * sizeof(unsigned short));
  uint4* pbuf2 = (uint4*)alloc(12 * 64 * sizeof(uint4));
  uint4* pbuf1 = (uint4*)alloc(64 * 64 * sizeof(uint4));
  float* bperm = (float*)alloc(C_HID * sizeof(float));

  hipMemsetAsync(bcur, 0, NBUCK * sizeof(int), stream);
  passA_kernel<<<(E + EPB - 1) / EPB, 256, 0, stream>>>(src, dst, E, gedge, bcur);
  bscan_kernel<<<1, 128, 0, stream>>>(bcur, goff, off, E);
  passB_kernel<<<NBUCK, 512, 0, stream>>>(gedge, bcur, goff, esrc, off, dinv);
  epack_kernel<<<(E + 255) / 256, 256, 0, stream>>>(esrc, dinv, epack, E);
  wprep_kernel<<<20, 256, 0, stream>>>(W1, W2, b1, pbuf1, pbuf2, bperm);

  gemm1_kernel<<<(NN + 63) / 64, 256, 0, stream>>>(x, pbuf1, h1f8);
  agg1_kernel<<<(NN + 3) / 4, 256, 0, stream>>>(h1f8, off, epack, dinv, bperm,
                                                (uint4*)ag1b, NN, E);
  gemm2_kernel<<<(NN + 63) / 64, 256, 0, stream>>>((const unsigned short*)ag1b, pbuf2, h2b);
  agg2_kernel<<<(NN + 3) / 4, 256, 0, stream>>>(h2b, off, epack, dinv, b2,
                                                (float*)d_out, NN, E);
}

// Round 12
// 135.067 us; speedup vs baseline: 4.9793x; 1.0928x over previous
//
#include <hip/hip_runtime.h>
#include <cmath>

#define NN 50000
#define C_IN 256
#define C_HID 128
#define C_OUT 40

#define BSZ 512                          // nodes per bucket
#define NBUCK ((NN + BSZ - 1) / BSZ)     // 98
#define CAP 19456                        // max edges per bucket region
#define EPB 4096                         // edges per passA block

typedef __attribute__((ext_vector_type(8))) short bf16x8;
typedef __attribute__((ext_vector_type(4))) float f32x4;
typedef __attribute__((ext_vector_type(2))) float f32x2;

__device__ __forceinline__ float bf2f(unsigned int u16) {
  unsigned int b = (u16 & 0xFFFFu) << 16;
  return __builtin_bit_cast(float, b);
}
__device__ __forceinline__ unsigned short f2bf(float f) {
  unsigned int b = __builtin_bit_cast(unsigned int, f);
  unsigned int r = (b + 0x7FFF + ((b >> 16) & 1)) >> 16;  // RNE
  return (unsigned short)r;
}

// ---------------- CSR build: pass A — LDS-binned partition into NBUCK regions ------------

__global__ __launch_bounds__(256) void passA_kernel(const int* __restrict__ src,
    const int* __restrict__ dst, int E, unsigned int* __restrict__ gedge,
    int* __restrict__ bcur) {
  __shared__ unsigned int pk[EPB];
  __shared__ unsigned char bof[EPB];
  __shared__ int bcnt[NBUCK], bstart[NBUCK], bpos[NBUCK], gbase[NBUCK];
  int tid = threadIdx.x;
  int e0 = blockIdx.x * EPB;
  int cnt = min(EPB, E - e0);
  for (int b = tid; b < NBUCK; b += 256) bcnt[b] = 0;
  int ds_[16], ss_[16];
  __syncthreads();
  #pragma unroll
  for (int k = 0; k < 16; ++k) {
    int i = tid + k * 256;
    if (i < cnt) {
      ds_[k] = dst[e0 + i];
      ss_[k] = src[e0 + i];
      atomicAdd(&bcnt[ds_[k] >> 9], 1);
    }
  }
  __syncthreads();
  if (tid == 0) {
    int acc = 0;
    for (int b = 0; b < NBUCK; ++b) { bstart[b] = acc; bpos[b] = acc; acc += bcnt[b]; }
  }
  __syncthreads();
  #pragma unroll
  for (int k = 0; k < 16; ++k) {
    int i = tid + k * 256;
    if (i < cnt) {
      int b = ds_[k] >> 9;
      int p = atomicAdd(&bpos[b], 1);
      pk[p] = ((unsigned int)ss_[k] << 9) | (unsigned int)(ds_[k] & 511);
      bof[p] = (unsigned char)b;
    }
  }
  __syncthreads();
  for (int b = tid; b < NBUCK; b += 256)
    gbase[b] = atomicAdd(&bcur[b], bcnt[b]);
  __syncthreads();
  for (int i = tid; i < cnt; i += 256) {
    int b = bof[i];
    int p = gbase[b] + (i - bstart[b]);
    gedge[(size_t)b * CAP + p] = pk[i];
  }
}

// pass B — per-bucket counting sort; computes its own prefix base from bcur (no bscan).
__global__ __launch_bounds__(512) void passB_kernel(const unsigned int* __restrict__ gedge,
    const int* __restrict__ bcur, int* __restrict__ esrc, int* __restrict__ off,
    float* __restrict__ dinv, int E) {
  __shared__ int dcnt[512];
  __shared__ int dsc[512];
  __shared__ int dcur[512];
  __shared__ int bc[128];
  int b = blockIdx.x, tid = threadIdx.x;
  int nE = bcur[b];
  if (tid < 128) bc[tid] = (tid < b) ? bcur[tid] : 0;  // tid<b<=97 keeps reads in-range
  dcnt[tid] = 0;
  __syncthreads();
  const unsigned int* reg = gedge + (size_t)b * CAP;
  for (int i = tid; i < nE; i += 512)
    atomicAdd(&dcnt[reg[i] & 511], 1);
  __syncthreads();
  for (int d = 64; d > 0; d >>= 1) {  // tree-reduce bc -> base
    if (tid < d) bc[tid] += bc[tid + d];
    __syncthreads();
  }
  int base = bc[0];
  int own = dcnt[tid];
  dsc[tid] = own;
  __syncthreads();
  for (int d = 1; d < 512; d <<= 1) {
    int x = (tid >= d) ? dsc[tid - d] : 0;
    __syncthreads();
    dsc[tid] += x;
    __syncthreads();
  }
  int excl = dsc[tid] - own;
  dcur[tid] = excl;
  int node = b * BSZ + tid;
  if (node < NN) {
    off[node]  = base + excl;
    dinv[node] = rsqrtf((float)(own + 1));
  }
  if (b == 0 && tid == 0) off[NN] = E;
  __syncthreads();
  for (int i = tid; i < nE; i += 512) {
    unsigned int p = reg[i];
    int pos = atomicAdd(&dcur[p & 511], 1);
    esrc[base + pos] = (int)(p >> 9);
  }
}

// ---------------- W prep + bcur zero + permuted b1 ---------------------------------------
// h1 stored layout: row pos p = c0*8 + t holds channel chan(p) = (p&7)*16 + (p>>3).

__global__ void wprep_kernel(const float* __restrict__ W1, const float* __restrict__ W2,
                             const float* __restrict__ b1, uint4* __restrict__ pbuf1,
                             uint4* __restrict__ pbuf2, float* __restrict__ bperm,
                             int* __restrict__ bcur) {
  int blk = blockIdx.x;
  int tid = threadIdx.x;
  if (blk < 16) {  // W1
    int gid = blk * 256 + tid;
    int l = gid & 63, idx = gid >> 6;  // idx = t*8+ks
    int ks = idx & 7, t = idx >> 3;
    int c = t * 16 + (l & 15);
    int kbase = ks * 32 + (l >> 4) * 8;
    unsigned int u[4];
    #pragma unroll
    for (int jp = 0; jp < 4; ++jp) {
      float v0 = W1[(size_t)(kbase + 2 * jp) * C_HID + c];
      float v1 = W1[(size_t)(kbase + 2 * jp + 1) * C_HID + c];
      u[jp] = (unsigned int)f2bf(v0) | ((unsigned int)f2bf(v1) << 16);
    }
    pbuf1[idx * 64 + l] = make_uint4(u[0], u[1], u[2], u[3]);
  } else if (blk < 19) {  // W2, k-permuted to match h1/ag1 stored order
    int gid = (blk - 16) * 256 + tid;
    int l = gid & 63, idx = gid >> 6;  // idx = t*4+ks
    int ks = idx & 3, t = idx >> 2;
    int c = t * 16 + (l & 15);
    int kbase = ks * 32 + (l >> 4) * 8;
    unsigned int u[4];
    #pragma unroll
    for (int jp = 0; jp < 4; ++jp) {
      int k0 = kbase + 2 * jp, k1 = k0 + 1;
      int ch0 = ((k0 & 7) << 4) + (k0 >> 3);
      int ch1 = ((k1 & 7) << 4) + (k1 >> 3);
      float v0 = (c < C_OUT) ? W2[(size_t)ch0 * C_OUT + c] : 0.f;
      float v1 = (c < C_OUT) ? W2[(size_t)ch1 * C_OUT + c] : 0.f;
      u[jp] = (unsigned int)f2bf(v0) | ((unsigned int)f2bf(v1) << 16);
    }
    pbuf2[idx * 64 + l] = make_uint4(u[0], u[1], u[2], u[3]);
  } else {  // housekeeping: zero bcur, permuted bias for agg1
    if (tid < NBUCK) bcur[tid] = 0;
    if (tid >= 128 && tid < 128 + C_HID) {
      int p = tid - 128;
      bperm[p] = b1[((p & 7) << 4) + (p >> 3)];
    }
  }
}

// ---------------- GEMM 1 (MFMA) + epack side-blocks --------------------------------------
// blocks < ngemm: h1[50000,128](fp8, permuted rows) = x(->bf16) @ W1
// blocks >= ngemm: epack[e] = (esrc[e]<<16) | bf16(dinv[esrc[e]])  (grid-stride)

__global__ __launch_bounds__(256) void gemm1_epack_kernel(const float* __restrict__ x,
    const uint4* __restrict__ pb, uint2* __restrict__ h,
    const int* __restrict__ esrc, const float* __restrict__ dinv,
    unsigned int* __restrict__ epack, int E, int ngemm) {
  if ((int)blockIdx.x >= ngemm) {
    int nb = gridDim.x - ngemm;
    for (int e = (blockIdx.x - ngemm) * 256 + threadIdx.x; e < E; e += nb * 256) {
      int s = esrc[e];
      epack[e] = ((unsigned int)s << 16) | (unsigned int)f2bf(dinv[s]);
    }
    return;
  }
  int l = threadIdx.x & 63, w = threadIdx.x >> 6;
  int row0 = blockIdx.x * 64 + w * 16;
  int arow = min(row0 + (l & 15), NN - 1);
  const float* xp = x + (size_t)arow * C_IN + (l >> 4) * 8;
  bf16x8 a[8];
  #pragma unroll
  for (int ks = 0; ks < 8; ++ks) {
    float4 a0 = *(const float4*)(xp + ks * 32);
    float4 a1 = *(const float4*)(xp + ks * 32 + 4);
    union { bf16x8 v; unsigned short s[8]; } pa;
    pa.s[0] = f2bf(a0.x); pa.s[1] = f2bf(a0.y); pa.s[2] = f2bf(a0.z); pa.s[3] = f2bf(a0.w);
    pa.s[4] = f2bf(a1.x); pa.s[5] = f2bf(a1.y); pa.s[6] = f2bf(a1.z); pa.s[7] = f2bf(a1.w);
    a[ks] = pa.v;
  }
  f32x4 acc[8] = {};
  #pragma unroll
  for (int t = 0; t < 8; ++t) {
    #pragma unroll
    for (int ks = 0; ks < 8; ++ks) {
      bf16x8 b = __builtin_bit_cast(bf16x8, pb[(t * 8 + ks) * 64 + l]);
      acc[t] = __builtin_amdgcn_mfma_f32_16x16x32_bf16(a[ks], b, acc[t], 0, 0, 0);
    }
  }
  int c0 = l & 15, rb = (l >> 4) * 4;
  #pragma unroll
  for (int r = 0; r < 4; ++r) {
    int row = row0 + rb + r;
    if (row < NN) {
      int w0 = __builtin_amdgcn_cvt_pk_fp8_f32(acc[0][r], acc[1][r], 0, false);
      w0     = __builtin_amdgcn_cvt_pk_fp8_f32(acc[2][r], acc[3][r], w0, true);
      int w1 = __builtin_amdgcn_cvt_pk_fp8_f32(acc[4][r], acc[5][r], 0, false);
      w1     = __builtin_amdgcn_cvt_pk_fp8_f32(acc[6][r], acc[7][r], w1, true);
      h[(size_t)row * 16 + c0] = make_uint2((unsigned int)w0, (unsigned int)w1);
    }
  }
}

// ---------------- GEMM 2 (MFMA): h2[50000,40](fp8) = ag1(bf16, stored order) @ W2 --------

__global__ __launch_bounds__(256) void gemm2_kernel(const unsigned short* __restrict__ ag1b,
    const uint4* __restrict__ pbuf, unsigned char* __restrict__ h2) {
  int l = threadIdx.x & 63, w = threadIdx.x >> 6;
  int row0 = blockIdx.x * 64 + w * 16;
  int arow = min(row0 + (l & 15), NN - 1);
  const uint4* ap = (const uint4*)(ag1b + (size_t)arow * C_HID + (l >> 4) * 8);
  bf16x8 a[4];
  #pragma unroll
  for (int ks = 0; ks < 4; ++ks) a[ks] = __builtin_bit_cast(bf16x8, ap[ks * 4]);
  f32x4 acc[3] = {};
  #pragma unroll
  for (int t = 0; t < 3; ++t) {
    #pragma unroll
    for (int ks = 0; ks < 4; ++ks) {
      bf16x8 b = __builtin_bit_cast(bf16x8, pbuf[(t * 4 + ks) * 64 + l]);
      acc[t] = __builtin_amdgcn_mfma_f32_16x16x32_bf16(a[ks], b, acc[t], 0, 0, 0);
    }
  }
  int rbase = row0 + (l >> 4) * 4;
  int c0 = l & 15;
  #pragma unroll
  for (int t = 0; t < 3; ++t) {
    int col = t * 16 + c0;
    if (col < C_OUT) {
      #pragma unroll
      for (int r = 0; r < 4; ++r) {
        int row = rbase + r;
        if (row < NN) {
          int pk = __builtin_amdgcn_cvt_pk_fp8_f32(acc[t][r], 0.f, 0, false);
          h2[(size_t)row * C_OUT + col] = (unsigned char)(pk & 0xFF);
        }
      }
    }
  }
}

// ---------------- Aggregation ----------------

// Layer-1 agg: wave per node, 16 lanes/edge (uint2 = 8 fp8 ch), 16 edges/iter,
// 2-level pipeline. Output bf16 in same stored order.
__global__ void agg1_kernel(const uint2* __restrict__ h, const int* __restrict__ off,
                            const unsigned int* __restrict__ epack,
                            const float* __restrict__ dinv, const float* __restrict__ bperm,
                            uint4* __restrict__ outb, int n, int E) {
  int wv = threadIdx.x >> 6, l = threadIdx.x & 63;
  int i = blockIdx.x * 4 + wv;
  if (i >= n) return;
  int g = l >> 4, q = l & 15;
  float di = dinv[i];
  float a0 = 0.f, a1 = 0.f, a2 = 0.f, a3 = 0.f, a4 = 0.f, a5 = 0.f, a6 = 0.f, a7 = 0.f;
  int p0 = off[i], p1 = off[i + 1];
  int pb = p0;
  int Em1 = E - 1;
  unsigned int e0 = epack[min(pb + g, Em1)];
  unsigned int e1 = epack[min(pb + 4 + g, Em1)];
  unsigned int e2 = epack[min(pb + 8 + g, Em1)];
  unsigned int e3 = epack[min(pb + 12 + g, Em1)];
  unsigned int f0 = epack[min(pb + 16 + g, Em1)];
  unsigned int f1 = epack[min(pb + 20 + g, Em1)];
  unsigned int f2 = epack[min(pb + 24 + g, Em1)];
  unsigned int f3 = epack[min(pb + 28 + g, Em1)];
  uint2 H0 = h[(size_t)(e0 >> 16) * 16 + q];
  uint2 H1 = h[(size_t)(e1 >> 16) * 16 + q];
  uint2 H2 = h[(size_t)(e2 >> 16) * 16 + q];
  uint2 H3 = h[(size_t)(e3 >> 16) * 16 + q];
  #define ACC_EDGE(vv, ee)                                                    \
    {                                                                         \
      float n_ = bf2f(ee) * di;                                               \
      f32x2 c0_ = __builtin_amdgcn_cvt_pk_f32_fp8((int)vv.x, false);          \
      f32x2 c1_ = __builtin_amdgcn_cvt_pk_f32_fp8((int)vv.x, true);           \
      f32x2 c2_ = __builtin_amdgcn_cvt_pk_f32_fp8((int)vv.y, false);          \
      f32x2 c3_ = __builtin_amdgcn_cvt_pk_f32_fp8((int)vv.y, true);           \
      a0 += c0_[0] * n_; a1 += c0_[1] * n_;                                   \
      a2 += c1_[0] * n_; a3 += c1_[1] * n_;                                   \
      a4 += c2_[0] * n_; a5 += c2_[1] * n_;                                   \
      a6 += c3_[0] * n_; a7 += c3_[1] * n_;                                   \
    }
  for (; pb + 31 < p1; pb += 16) {
    uint2 G0 = h[(size_t)(f0 >> 16) * 16 + q];
    uint2 G1 = h[(size_t)(f1 >> 16) * 16 + q];
    uint2 G2 = h[(size_t)(f2 >> 16) * 16 + q];
    uint2 G3 = h[(size_t)(f3 >> 16) * 16 + q];
    unsigned int n0 = epack[min(pb + 32 + g, Em1)];
    unsigned int n1 = epack[min(pb + 36 + g, Em1)];
    unsigned int n2 = epack[min(pb + 40 + g, Em1)];
    unsigned int n3 = epack[min(pb + 44 + g, Em1)];
    ACC_EDGE(H0, e0); ACC_EDGE(H1, e1); ACC_EDGE(H2, e2); ACC_EDGE(H3, e3);
    e0 = f0; e1 = f1; e2 = f2; e3 = f3;
    f0 = n0; f1 = n1; f2 = n2; f3 = n3;
    H0 = G0; H1 = G1; H2 = G2; H3 = G3;
  }
  if (pb + g < p1)      ACC_EDGE(H0, e0);
  if (pb + 4 + g < p1)  ACC_EDGE(H1, e1);
  if (pb + 8 + g < p1)  ACC_EDGE(H2, e2);
  if (pb + 12 + g < p1) ACC_EDGE(H3, e3);
  int pc = pb + 16;
  if (pc < p1) {
    uint2 G0 = h[(size_t)(f0 >> 16) * 16 + q];
    uint2 G1 = h[(size_t)(f1 >> 16) * 16 + q];
    uint2 G2 = h[(size_t)(f2 >> 16) * 16 + q];
    uint2 G3 = h[(size_t)(f3 >> 16) * 16 + q];
    if (pc + g < p1)      ACC_EDGE(G0, f0);
    if (pc + 4 + g < p1)  ACC_EDGE(G1, f1);
    if (pc + 8 + g < p1)  ACC_EDGE(G2, f2);
    if (pc + 12 + g < p1) ACC_EDGE(G3, f3);
  }
  #undef ACC_EDGE
  a0 += __shfl_xor(a0, 16); a1 += __shfl_xor(a1, 16);
  a2 += __shfl_xor(a2, 16); a3 += __shfl_xor(a3, 16);
  a4 += __shfl_xor(a4, 16); a5 += __shfl_xor(a5, 16);
  a6 += __shfl_xor(a6, 16); a7 += __shfl_xor(a7, 16);
  a0 += __shfl_xor(a0, 32); a1 += __shfl_xor(a1, 32);
  a2 += __shfl_xor(a2, 32); a3 += __shfl_xor(a3, 32);
  a4 += __shfl_xor(a4, 32); a5 += __shfl_xor(a5, 32);
  a6 += __shfl_xor(a6, 32); a7 += __shfl_xor(a7, 32);
  if (g == 0) {
    uint2 sv = h[(size_t)i * 16 + q];
    float dd = di * di;
    f32x2 s0 = __builtin_amdgcn_cvt_pk_f32_fp8((int)sv.x, false);
    f32x2 s1 = __builtin_amdgcn_cvt_pk_f32_fp8((int)sv.x, true);
    f32x2 s2 = __builtin_amdgcn_cvt_pk_f32_fp8((int)sv.y, false);
    f32x2 s3 = __builtin_amdgcn_cvt_pk_f32_fp8((int)sv.y, true);
    a0 += s0[0] * dd; a1 += s0[1] * dd;
    a2 += s1[0] * dd; a3 += s1[1] * dd;
    a4 += s2[0] * dd; a5 += s2[1] * dd;
    a6 += s3[0] * dd; a7 += s3[1] * dd;
    float4 b0 = ((const float4*)bperm)[q * 2];
    float4 b1v = ((const float4*)bperm)[q * 2 + 1];
    a0 = fmaxf(a0 + b0.x, 0.f); a1 = fmaxf(a1 + b0.y, 0.f);
    a2 = fmaxf(a2 + b0.z, 0.f); a3 = fmaxf(a3 + b0.w, 0.f);
    a4 = fmaxf(a4 + b1v.x, 0.f); a5 = fmaxf(a5 + b1v.y, 0.f);
    a6 = fmaxf(a6 + b1v.z, 0.f); a7 = fmaxf(a7 + b1v.w, 0.f);
    uint4 o;
    o.x = (unsigned int)f2bf(a0) | ((unsigned int)f2bf(a1) << 16);
    o.y = (unsigned int)f2bf(a2) | ((unsigned int)f2bf(a3) << 16);
    o.z = (unsigned int)f2bf(a4) | ((unsigned int)f2bf(a5) << 16);
    o.w = (unsigned int)f2bf(a6) | ((unsigned int)f2bf(a7) << 16);
    outb[(size_t)i * 16 + q] = o;
  }
}

// Layer-2 agg + bias + log_softmax: wave per node, fp8 h2 (uint = 4 ch/lane, 10 lanes/edge),
// 12 edges/iter via 2 gathers, 2-level pipeline.
__global__ void agg2_kernel(const unsigned char* __restrict__ h2, const int* __restrict__ off,
                            const unsigned int* __restrict__ epack,
                            const float* __restrict__ dinv, const float* __restrict__ b,
                            float* __restrict__ out, int n, int E) {
  int wv = threadIdx.x >> 6, l = threadIdx.x & 63;
  int i = blockIdx.x * 4 + wv;
  if (i >= n) return;
  int g = l / 10, q = l - g * 10;
  bool lact = l < 60;
  if (!lact) { g = 0; q = 0; }
  float di = dinv[i];
  float a0 = 0.f, a1 = 0.f, a2 = 0.f, a3 = 0.f;
  int p0 = off[i], p1 = off[i + 1];
  int pb = p0;
  int Em1 = E - 1;
  unsigned int e0 = epack[min(pb + g, Em1)];
  unsigned int e1 = epack[min(pb + 6 + g, Em1)];
  unsigned int f0 = epack[min(pb + 12 + g, Em1)];
  unsigned int f1 = epack[min(pb + 18 + g, Em1)];
  unsigned int H0 = *(const unsigned int*)(h2 + (size_t)(e0 >> 16) * C_OUT + q * 4);
  unsigned int H1 = *(const unsigned int*)(h2 + (size_t)(e1 >> 16) * C_OUT + q * 4);
  #define ACC_EDGE2(vv, ee)                                                   \
    {                                                                         \
      float n_ = bf2f(ee) * di;                                               \
      f32x2 lo_ = __builtin_amdgcn_cvt_pk_f32_fp8((int)(vv), false);          \
      f32x2 hi_ = __builtin_amdgcn_cvt_pk_f32_fp8((int)(vv), true);           \
      a0 += lo_[0] * n_; a1 += lo_[1] * n_;                                   \
      a2 += hi_[0] * n_; a3 += hi_[1] * n_;                                   \
    }
  for (; pb + 23 < p1; pb += 12) {
    unsigned int G0 = *(const unsigned int*)(h2 + (size_t)(f0 >> 16) * C_OUT + q * 4);
    unsigned int G1 = *(const unsigned int*)(h2 + (size_t)(f1 >> 16) * C_OUT + q * 4);
    unsigned int n0 = epack[min(pb + 24 + g, Em1)];
    unsigned int n1 = epack[min(pb + 30 + g, Em1)];
    if (lact) { ACC_EDGE2(H0, e0); ACC_EDGE2(H1, e1); }
    e0 = f0; e1 = f1;
    f0 = n0; f1 = n1;
    H0 = G0; H1 = G1;
  }
  if (lact && pb + g < p1)     ACC_EDGE2(H0, e0);
  if (lact && pb + 6 + g < p1) ACC_EDGE2(H1, e1);
  int pc = pb + 12;
  if (pc < p1) {
    unsigned int G0 = *(const unsigned int*)(h2 + (size_t)(f0 >> 16) * C_OUT + q * 4);
    unsigned int G1 = *(const unsigned int*)(h2 + (size_t)(f1 >> 16) * C_OUT + q * 4);
    if (lact && pc + g < p1)     ACC_EDGE2(G0, f0);
    if (lact && pc + 6 + g < p1) ACC_EDGE2(G1, f1);
  }
  #undef ACC_EDGE2
  float t0 = 0.f, t1 = 0.f, t2 = 0.f, t3 = 0.f;
  #pragma unroll
  for (int gg = 0; gg < 6; ++gg) {
    int sl = gg * 10 + q;
    t0 += __shfl(a0, sl); t1 += __shfl(a1, sl);
    t2 += __shfl(a2, sl); t3 += __shfl(a3, sl);
  }
  bool act = l < 10;
  float v0, v1, v2, v3;
  if (act) {
    unsigned int sv = *(const unsigned int*)(h2 + (size_t)i * C_OUT + l * 4);
    f32x2 slo = __builtin_amdgcn_cvt_pk_f32_fp8((int)sv, false);
    f32x2 shi = __builtin_amdgcn_cvt_pk_f32_fp8((int)sv, true);
    float dd = di * di;
    float4 bb = ((const float4*)b)[l];
    v0 = t0 + slo[0] * dd + bb.x;
    v1 = t1 + slo[1] * dd + bb.y;
    v2 = t2 + shi[0] * dd + bb.z;
    v3 = t3 + shi[1] * dd + bb.w;
  } else {
    v0 = v1 = v2 = v3 = -INFINITY;
  }
  float mm = fmaxf(fmaxf(v0, v1), fmaxf(v2, v3));
  #pragma unroll
  for (int d = 32; d > 0; d >>= 1) mm = fmaxf(mm, __shfl_xor(mm, d));
  float e = act ? (expf(v0 - mm) + expf(v1 - mm) + expf(v2 - mm) + expf(v3 - mm)) : 0.f;
  float ss = e;
  #pragma unroll
  for (int d = 32; d > 0; d >>= 1) ss += __shfl_xor(ss, d);
  if (act) {
    float lg = logf(ss);
    float4 o = {v0 - mm - lg, v1 - mm - lg, v2 - mm - lg, v3 - mm - lg};
    *(float4*)&out[(size_t)i * C_OUT + l * 4] = o;
  }
}

// ---------------- launch ----------------

extern "C" void kernel_launch(void* const* d_in, const int* in_sizes, int n_in,
                              void* d_out, int out_size, void* d_ws, size_t ws_size,
                              hipStream_t stream) {
  const float* x  = (const float*)d_in[0];
  const int*   ei = (const int*)d_in[1];
  const float* W1 = (const float*)d_in[2];
  const float* b1 = (const float*)d_in[3];
  const float* W2 = (const float*)d_in[4];
  const float* b2 = (const float*)d_in[5];
  int E = in_sizes[1] / 2;
  const int* src = ei;
  const int* dst = ei + E;

  char* ws = (char*)d_ws;
  size_t o = 0;
  auto alloc = [&](size_t bytes) {
    char* p = ws + o;
    o += (bytes + 255) & ~(size_t)255;
    return p;
  };
  unsigned int* gedge = (unsigned int*)alloc((size_t)NBUCK * CAP * sizeof(unsigned int));
  int*   bcur  = (int*)alloc(NBUCK * sizeof(int));
  int*   off   = (int*)alloc((NN + 1) * sizeof(int));
  float* dinv  = (float*)alloc(NN * sizeof(float));
  int*   esrc  = (int*)alloc((size_t)E * sizeof(int));
  unsigned int* epack = (unsigned int*)alloc((size_t)E * sizeof(unsigned int));
  uint2* h1f8  = (uint2*)alloc((size_t)NN * C_HID);      // fp8, 128 B/row
  unsigned int*   ag1b = (unsigned int*)alloc((size_t)NN * (C_HID / 2) * sizeof(unsigned int));
  unsigned char*  h2f8 = (unsigned char*)alloc((size_t)NN * C_OUT);  // fp8, 40 B/row
  uint4* pbuf2 = (uint4*)alloc(12 * 64 * sizeof(uint4));
  uint4* pbuf1 = (uint4*)alloc(64 * 64 * sizeof(uint4));
  float* bperm = (float*)alloc(C_HID * sizeof(float));

  int ngemm = (NN + 63) / 64;  // 782

  wprep_kernel<<<20, 256, 0, stream>>>(W1, W2, b1, pbuf1, pbuf2, bperm, bcur);
  passA_kernel<<<(E + EPB - 1) / EPB, 256, 0, stream>>>(src, dst, E, gedge, bcur);
  passB_kernel<<<NBUCK, 512, 0, stream>>>(gedge, bcur, esrc, off, dinv, E);
  gemm1_epack_kernel<<<ngemm + 512, 256, 0, stream>>>(x, pbuf1, h1f8, esrc, dinv,
                                                      epack, E, ngemm);
  agg1_kernel<<<(NN + 3) / 4, 256, 0, stream>>>(h1f8, off, epack, dinv, bperm,
                                                (uint4*)ag1b, NN, E);
  gemm2_kernel<<<ngemm, 256, 0, stream>>>((const unsigned short*)ag1b, pbuf2, h2f8);
  agg2_kernel<<<(NN + 3) / 4, 256, 0, stream>>>(h2f8, off, epack, dinv, b2,
                                                (float*)d_out, NN, E);
}